// Round 7
// baseline (386.476 us; speedup 1.0000x reference)
//
#include <hip/hip_runtime.h>
#include <hip/hip_bf16.h>
#include <math.h>

#define TSEQ 2048
#define BATCH 2
#define CDIM 1024
#define NH 16
#define HD 64
#define DFF 4096
#define ROWS (BATCH*TSEQ)   // 4096

typedef __attribute__((ext_vector_type(4))) float f32x4;
typedef __attribute__((ext_vector_type(8))) short bf16x8;   // 8 bf16 in 4 VGPRs
typedef __attribute__((ext_vector_type(4))) unsigned short u16x4;

__device__ __forceinline__ void gload_lds16(const void* g, void* l) {
    void* gv = const_cast<void*>(g);
    __builtin_amdgcn_global_load_lds((__attribute__((address_space(1))) void*)gv,
                                     (__attribute__((address_space(3))) void*)l, 16, 0, 0);
}

__device__ __forceinline__ unsigned short f2bf(float f) {
    unsigned int u = __float_as_uint(f);
    return (unsigned short)((u + 0x7FFFu + ((u >> 16) & 1u)) >> 16);
}
__device__ __forceinline__ float bf2f(unsigned short u) {
    return __uint_as_float((unsigned int)u << 16);
}

// ------------------------------- LayerNorm -> bf16 --------------------------------
__global__ __launch_bounds__(256) void ln_kernel(const float* __restrict__ x,
                                                 const float* __restrict__ g,
                                                 const float* __restrict__ b,
                                                 unsigned short* __restrict__ out) {
    int row = blockIdx.x;
    int tid = threadIdx.x;
    const float* xr = x + (size_t)row * CDIM;
    float4 v = *(const float4*)(xr + tid * 4);
    float s  = v.x + v.y + v.z + v.w;
    float s2 = v.x*v.x + v.y*v.y + v.z*v.z + v.w*v.w;
    #pragma unroll
    for (int off = 32; off >= 1; off >>= 1) {
        s  += __shfl_down(s, off);
        s2 += __shfl_down(s2, off);
    }
    __shared__ float red[8];
    int wid = tid >> 6, lane = tid & 63;
    if (lane == 0) { red[wid] = s; red[wid + 4] = s2; }
    __syncthreads();
    float ts  = red[0] + red[1] + red[2] + red[3];
    float ts2 = red[4] + red[5] + red[6] + red[7];
    float mu  = ts * (1.0f / CDIM);
    float var = ts2 * (1.0f / CDIM) - mu * mu;
    float rstd = rsqrtf(var + 1e-5f);
    float4 gv = *(const float4*)(g + tid * 4);
    float4 bv = *(const float4*)(b + tid * 4);
    unsigned short o4[4];
    o4[0] = f2bf((v.x - mu) * rstd * gv.x + bv.x);
    o4[1] = f2bf((v.y - mu) * rstd * gv.y + bv.y);
    o4[2] = f2bf((v.z - mu) * rstd * gv.z + bv.z);
    o4[3] = f2bf((v.w - mu) * rstd * gv.w + bv.w);
    *(u16x4*)(out + (size_t)row * CDIM + tid * 4) = *(u16x4*)o4;
}

// --------------------- transpose + cast: W[K][N] f32 -> Wt[N][K] bf16 ---------------
__global__ __launch_bounds__(256) void transpose_cast_kernel(const float* __restrict__ W,
                                                             unsigned short* __restrict__ Wt,
                                                             int K, int N) {
    __shared__ float T[64][65];
    int tid = threadIdx.x;
    int n0 = blockIdx.x * 64, k0 = blockIdx.y * 64;
    int kr = tid >> 4;
    int nc = (tid & 15) * 4;
    #pragma unroll
    for (int i = 0; i < 4; ++i) {
        float4 v = *(const float4*)&W[(size_t)(k0 + kr + i*16) * N + (n0 + nc)];
        T[kr + i*16][nc + 0] = v.x;
        T[kr + i*16][nc + 1] = v.y;
        T[kr + i*16][nc + 2] = v.z;
        T[kr + i*16][nc + 3] = v.w;
    }
    __syncthreads();
    int n  = tid >> 2;
    int kb = (tid & 3) * 16;
    unsigned short tmp[16];
    #pragma unroll
    for (int i = 0; i < 16; ++i) tmp[i] = f2bf(T[kb + i][n]);
    unsigned short* dst = Wt + (size_t)(n0 + n) * K + (k0 + kb);
    *(int4*)dst       = *(int4*)&tmp[0];
    *(int4*)(dst + 8) = *(int4*)&tmp[8];
}

// ------------- V transpose: qkv V-part -> VtG[b][h][d][s] (bf16) -------------------
__global__ __launch_bounds__(256) void vtrans_kernel(const unsigned short* __restrict__ qkv,
                                                     unsigned short* __restrict__ vtg) {
    __shared__ unsigned short T[64][72];
    const int tid = threadIdx.x;
    const int st  = blockIdx.x;            // s-tile
    const int bh  = blockIdx.y;
    const int b   = bh >> 4, h = bh & 15;
    {
        const int sl = tid >> 2;           // 0..63
        const int dc = (tid & 3) * 16;
        const unsigned short* src = qkv + ((size_t)(b * TSEQ + st * 64 + sl)) * 3072 + 2048 + h * 64 + dc;
        bf16x8 v0 = *(const bf16x8*)src;
        bf16x8 v1 = *(const bf16x8*)(src + 8);
        #pragma unroll
        for (int i = 0; i < 8; ++i) {
            T[sl][dc + i]     = (unsigned short)v0[i];
            T[sl][dc + 8 + i] = (unsigned short)v1[i];
        }
    }
    __syncthreads();
    {
        const int d  = tid >> 2;           // 0..63
        const int sc = (tid & 3) * 16;
        unsigned short tmp[16];
        #pragma unroll
        for (int i = 0; i < 16; ++i) tmp[i] = T[sc + i][d];
        unsigned short* dst = vtg + (((size_t)(b * NH + h) * 64 + d) * TSEQ) + st * 64 + sc;
        *(int4*)dst       = *(int4*)&tmp[0];
        *(int4*)(dst + 8) = *(int4*)&tmp[8];
    }
}

// ---------------- MFMA GEMM (TN): C[M,N] = A[M,K](bf16) @ Bt[N,K](bf16)^T ----------
// EPI: 0 = bias -> bf16 out; 1 = bias + f32 residual -> f32 out; 2 = bias+GELU -> bf16 out
template<int EPI>
__global__ __launch_bounds__(256) void gemm_kernel(const unsigned short* __restrict__ A,
                                                   const unsigned short* __restrict__ Bt,
                                                   const float* __restrict__ bias,
                                                   const float* __restrict__ res,
                                                   void* __restrict__ Cout,
                                                   int M, int N, int K) {
    __shared__ __align__(16) unsigned short As[128 * 32];
    __shared__ __align__(16) unsigned short Bs[128 * 32];
    const int tid = threadIdx.x;
    const int l   = tid & 63;
    const int w   = tid >> 6;
    const int wr  = (w >> 1) * 64;
    const int wc  = (w & 1) * 64;
    const long brow = (long)blockIdx.y * 128;
    const long bcol = (long)blockIdx.x * 128;

    const unsigned short* gA0 = A  + (size_t)(brow + (tid >> 2)) * K + (tid & 3) * 8;
    const unsigned short* gA1 = gA0 + (size_t)64 * K;
    const unsigned short* gB0 = Bt + (size_t)(bcol + (tid >> 2)) * K + (tid & 3) * 8;
    const unsigned short* gB1 = gB0 + (size_t)64 * K;
    unsigned short* lA0 = As + tid * 8;
    unsigned short* lA1 = As + 2048 + tid * 8;
    unsigned short* lB0 = Bs + tid * 8;
    unsigned short* lB1 = Bs + 2048 + tid * 8;

    f32x4 acc[4][4];
    #pragma unroll
    for (int m = 0; m < 4; ++m)
        #pragma unroll
        for (int n = 0; n < 4; ++n) acc[m][n] = (f32x4){0.f, 0.f, 0.f, 0.f};

    const int aoff = (wr + (l & 15)) * 32 + (l >> 4) * 8;
    const int boff = (wc + (l & 15)) * 32 + (l >> 4) * 8;

    for (int k0 = 0; k0 < K; k0 += 32) {
        gload_lds16(gA0 + k0, lA0);
        gload_lds16(gA1 + k0, lA1);
        gload_lds16(gB0 + k0, lB0);
        gload_lds16(gB1 + k0, lB1);
        __syncthreads();
        bf16x8 af[4], bf[4];
        #pragma unroll
        for (int m = 0; m < 4; ++m) af[m] = *(const bf16x8*)&As[aoff + m * 512];
        #pragma unroll
        for (int n = 0; n < 4; ++n) bf[n] = *(const bf16x8*)&Bs[boff + n * 512];
        #pragma unroll
        for (int m = 0; m < 4; ++m)
            #pragma unroll
            for (int n = 0; n < 4; ++n)
                acc[m][n] = __builtin_amdgcn_mfma_f32_16x16x32_bf16(af[m], bf[n], acc[m][n], 0, 0, 0);
        __syncthreads();
    }

    #pragma unroll
    for (int m = 0; m < 4; ++m) {
        const int rown = wr + m * 16 + (l >> 4) * 4;
        #pragma unroll
        for (int n = 0; n < 4; ++n) {
            const long col = bcol + wc + n * 16 + (l & 15);
            const float bb = bias[col];
            #pragma unroll
            for (int r = 0; r < 4; ++r) {
                const long row = brow + rown + r;
                float v = acc[m][n][r] + bb;
                if (EPI == 1) {
                    v += res[row * N + col];
                    ((float*)Cout)[row * N + col] = v;
                } else if (EPI == 2) {
                    v = 0.5f * v * (1.0f + erff(v * 0.70710678118f));
                    ((unsigned short*)Cout)[row * N + col] = f2bf(v);
                } else {
                    ((unsigned short*)Cout)[row * N + col] = f2bf(v);
                }
            }
        }
    }
}

// ------------------- MFMA causal flash attention (single-wave blocks) ---------------
// One 64-lane wave per block; each wave owns a 16-row q-strip and iterates K-tiles in
// PAIRS (128 s-cols per softmax pass). K frags direct from qkv (L2-resident per head);
// V frags from VtG[b][h][d][s]. Ps wave-private LDS (4 KB), XOR-chunk swizzled.
// Q pre-scaled by 0.125*log2e; softmax in exp2 domain.
// Grid 4096 = 8 xcd x (2 h x 2 b x 128 strips), longest strip first (LPT backfill).
#define QSCALE 0.18033688011112042f   // 0.125 * log2(e)
__global__ __launch_bounds__(64) void attn_kernel(const unsigned short* __restrict__ qkv,
                                                  const unsigned short* __restrict__ vtg,
                                                  unsigned short* __restrict__ out) {
    __shared__ __align__(16) unsigned short Ps[16 * 128];   // [row][col], chunk-XOR swizzled

    const int l    = threadIdx.x;              // 0..63
    const int lin  = blockIdx.x;
    const int xcd  = lin & 7;
    const int rest = lin >> 3;                 // 0..511
    const int h    = xcd + 8 * (rest & 1);     // heads {x, x+8} pinned to XCD x
    const int b    = (rest >> 1) & 1;
    const int strip = 127 - (rest >> 2);       // longest first
    const int jmax  = strip >> 2;              // last K-tile index
    const size_t rowbase = (size_t)b * TSEQ;

    const unsigned short* kbase = qkv + rowbase * 3072 + 1024 + h * 64;     // + s*3072 + d
    const unsigned short* vbase = vtg + ((size_t)(b * NH + h) * 64) * TSEQ; // + d*TSEQ + s

    // Q fragments (A operand: row l&15, k-slice (l>>4)*8), pre-scaled
    bf16x8 aq0, aq1;
    {
        const int qrow = strip * 16 + (l & 15);
        const unsigned short* qp = qkv + (rowbase + qrow) * 3072 + h * 64 + (l >> 4) * 8;
        bf16x8 t0 = *(const bf16x8*)qp;
        bf16x8 t1 = *(const bf16x8*)(qp + 32);
        #pragma unroll
        for (int i = 0; i < 8; ++i) {
            aq0[i] = (short)f2bf(bf2f((unsigned short)t0[i]) * QSCALE);
            aq1[i] = (short)f2bf(bf2f((unsigned short)t1[i]) * QSCALE);
        }
    }

    float mrow[4], lrow[4];
    #pragma unroll
    for (int r = 0; r < 4; ++r) { mrow[r] = -INFINITY; lrow[r] = 0.f; }
    f32x4 o[4];
    #pragma unroll
    for (int d = 0; d < 4; ++d) o[d] = (f32x4){0.f, 0.f, 0.f, 0.f};

    const int qg = strip * 16 + (l >> 4) * 4;   // this lane's base q row (global)

    // ---------------- pair steps: tiles j, j+1 (128 cols per softmax) ----------------
    for (int j = 0; j + 1 <= jmax; j += 2) {
        const bool diag2 = (j + 1 == jmax);

        bf16x8 kf[16];
        #pragma unroll
        for (int t = 0; t < 2; ++t)
            #pragma unroll
            for (int sb = 0; sb < 4; ++sb) {
                const unsigned short* kp = kbase + (size_t)((j + t) * 64 + sb * 16 + (l & 15)) * 3072 + (l >> 4) * 8;
                kf[t * 8 + sb * 2]     = *(const bf16x8*)kp;
                kf[t * 8 + sb * 2 + 1] = *(const bf16x8*)(kp + 32);
            }

        f32x4 sf[8];
        __builtin_amdgcn_s_setprio(1);
        #pragma unroll
        for (int t = 0; t < 2; ++t)
            #pragma unroll
            for (int sb = 0; sb < 4; ++sb) {
                f32x4 acc = (f32x4){0.f, 0.f, 0.f, 0.f};
                acc = __builtin_amdgcn_mfma_f32_16x16x32_bf16(aq0, kf[t*8 + sb*2],     acc, 0, 0, 0);
                acc = __builtin_amdgcn_mfma_f32_16x16x32_bf16(aq1, kf[t*8 + sb*2 + 1], acc, 0, 0, 0);
                sf[t*4 + sb] = acc;
            }
        __builtin_amdgcn_s_setprio(0);

        // V fragments for both tiles (kf dead; flat index kb' = t*2+kb over 128 cols)
        bf16x8 vf[16];
        #pragma unroll
        for (int kb = 0; kb < 4; ++kb)
            #pragma unroll
            for (int db = 0; db < 4; ++db)
                vf[kb * 4 + db] = *(const bf16x8*)(vbase + (size_t)(db * 16 + (l & 15)) * TSEQ
                                                   + j * 64 + kb * 32 + (l >> 4) * 8);

        // causal mask on the second tile if it is the diagonal
        if (diag2) {
            #pragma unroll
            for (int sb = 0; sb < 4; ++sb) {
                const int cg = (j + 1) * 64 + sb * 16 + (l & 15);
                #pragma unroll
                for (int r = 0; r < 4; ++r)
                    if (cg > qg + r) sf[4 + sb][r] = -INFINITY;
            }
        }

        // online softmax (exp2 domain) over 128 cols
        float mnew[4], alpha[4], psum[4];
        #pragma unroll
        for (int r = 0; r < 4; ++r) {
            float mx = fmaxf(fmaxf(fmaxf(sf[0][r], sf[1][r]), fmaxf(sf[2][r], sf[3][r])),
                             fmaxf(fmaxf(sf[4][r], sf[5][r]), fmaxf(sf[6][r], sf[7][r])));
            mx = fmaxf(mx, __shfl_xor(mx, 1));
            mx = fmaxf(mx, __shfl_xor(mx, 2));
            mx = fmaxf(mx, __shfl_xor(mx, 4));
            mx = fmaxf(mx, __shfl_xor(mx, 8));
            float mn = fmaxf(mrow[r], mx);
            mnew[r]  = mn;
            alpha[r] = exp2f(mrow[r] - mn);
            mrow[r]  = mn;
            psum[r]  = 0.f;
        }
        #pragma unroll
        for (int t = 0; t < 2; ++t)
            #pragma unroll
            for (int sb = 0; sb < 4; ++sb) {
                const int col = t * 64 + sb * 16 + (l & 15);
                #pragma unroll
                for (int r = 0; r < 4; ++r) {
                    float p = exp2f(sf[t*4 + sb][r] - mnew[r]);
                    psum[r] += p;
                    const int row = (l >> 4) * 4 + r;
                    Ps[row * 128 + (((col >> 3) ^ (row & 7)) << 3) + (col & 7)] = f2bf(p);
                }
            }
        #pragma unroll
        for (int r = 0; r < 4; ++r) {
            float ps = psum[r];
            ps += __shfl_xor(ps, 1);
            ps += __shfl_xor(ps, 2);
            ps += __shfl_xor(ps, 4);
            ps += __shfl_xor(ps, 8);
            lrow[r] = lrow[r] * alpha[r] + ps;
            #pragma unroll
            for (int d = 0; d < 4; ++d) o[d][r] *= alpha[r];
        }

        // O += P V over 128 cols (Ps wave-private; lgkmcnt orders write->read)
        __builtin_amdgcn_s_setprio(1);
        #pragma unroll
        for (int kb = 0; kb < 4; ++kb) {
            const int row = l & 15;
            bf16x8 pa = *(const bf16x8*)&Ps[row * 128 + (((kb * 4 + (l >> 4)) ^ (row & 7)) << 3)];
            #pragma unroll
            for (int db = 0; db < 4; ++db)
                o[db] = __builtin_amdgcn_mfma_f32_16x16x32_bf16(pa, vf[kb * 4 + db], o[db], 0, 0, 0);
        }
        __builtin_amdgcn_s_setprio(0);
    }

    // ---------------- tail single tile (j = jmax) when tile count is odd -------------
    if ((jmax & 1) == 0) {
        const int j = jmax;
        bf16x8 kf[8];
        #pragma unroll
        for (int sb = 0; sb < 4; ++sb) {
            const unsigned short* kp = kbase + (size_t)(j * 64 + sb * 16 + (l & 15)) * 3072 + (l >> 4) * 8;
            kf[sb * 2]     = *(const bf16x8*)kp;
            kf[sb * 2 + 1] = *(const bf16x8*)(kp + 32);
        }
        f32x4 sf[4];
        __builtin_amdgcn_s_setprio(1);
        #pragma unroll
        for (int sb = 0; sb < 4; ++sb) {
            f32x4 acc = (f32x4){0.f, 0.f, 0.f, 0.f};
            acc = __builtin_amdgcn_mfma_f32_16x16x32_bf16(aq0, kf[sb*2],     acc, 0, 0, 0);
            acc = __builtin_amdgcn_mfma_f32_16x16x32_bf16(aq1, kf[sb*2 + 1], acc, 0, 0, 0);
            sf[sb] = acc;
        }
        __builtin_amdgcn_s_setprio(0);

        bf16x8 vf[8];
        #pragma unroll
        for (int kb = 0; kb < 2; ++kb)
            #pragma unroll
            for (int db = 0; db < 4; ++db)
                vf[kb * 4 + db] = *(const bf16x8*)(vbase + (size_t)(db * 16 + (l & 15)) * TSEQ
                                                   + j * 64 + kb * 32 + (l >> 4) * 8);
        #pragma unroll
        for (int sb = 0; sb < 4; ++sb) {
            const int cg = j * 64 + sb * 16 + (l & 15);
            #pragma unroll
            for (int r = 0; r < 4; ++r)
                if (cg > qg + r) sf[sb][r] = -INFINITY;
        }

        float mnew[4], alpha[4], psum[4];
        #pragma unroll
        for (int r = 0; r < 4; ++r) {
            float mx = fmaxf(fmaxf(sf[0][r], sf[1][r]), fmaxf(sf[2][r], sf[3][r]));
            mx = fmaxf(mx, __shfl_xor(mx, 1));
            mx = fmaxf(mx, __shfl_xor(mx, 2));
            mx = fmaxf(mx, __shfl_xor(mx, 4));
            mx = fmaxf(mx, __shfl_xor(mx, 8));
            float mn = fmaxf(mrow[r], mx);
            mnew[r]  = mn;
            alpha[r] = exp2f(mrow[r] - mn);
            mrow[r]  = mn;
            psum[r]  = 0.f;
        }
        #pragma unroll
        for (int sb = 0; sb < 4; ++sb) {
            const int col = sb * 16 + (l & 15);
            #pragma unroll
            for (int r = 0; r < 4; ++r) {
                float p = exp2f(sf[sb][r] - mnew[r]);
                psum[r] += p;
                const int row = (l >> 4) * 4 + r;
                Ps[row * 128 + (((col >> 3) ^ (row & 7)) << 3) + (col & 7)] = f2bf(p);
            }
        }
        #pragma unroll
        for (int r = 0; r < 4; ++r) {
            float ps = psum[r];
            ps += __shfl_xor(ps, 1);
            ps += __shfl_xor(ps, 2);
            ps += __shfl_xor(ps, 4);
            ps += __shfl_xor(ps, 8);
            lrow[r] = lrow[r] * alpha[r] + ps;
            #pragma unroll
            for (int d = 0; d < 4; ++d) o[d][r] *= alpha[r];
        }
        __builtin_amdgcn_s_setprio(1);
        #pragma unroll
        for (int kb = 0; kb < 2; ++kb) {
            const int row = l & 15;
            bf16x8 pa = *(const bf16x8*)&Ps[row * 128 + (((kb * 4 + (l >> 4)) ^ (row & 7)) << 3)];
            #pragma unroll
            for (int db = 0; db < 4; ++db)
                o[db] = __builtin_amdgcn_mfma_f32_16x16x32_bf16(pa, vf[kb * 4 + db], o[db], 0, 0, 0);
        }
        __builtin_amdgcn_s_setprio(0);
    }

    // epilogue: O / l -> bf16
    #pragma unroll
    for (int r = 0; r < 4; ++r) {
        const float inv = 1.0f / lrow[r];
        const size_t rb = (rowbase + strip * 16 + (l >> 4) * 4 + r) * (size_t)CDIM + h * 64 + (l & 15);
        #pragma unroll
        for (int d = 0; d < 4; ++d)
            out[rb + d * 16] = f2bf(o[d][r] * inv);
    }
}

extern "C" void kernel_launch(void* const* d_in, const int* in_sizes, int n_in,
                              void* d_out, int out_size, void* d_ws, size_t ws_size,
                              hipStream_t stream) {
    const float* x     = (const float*)d_in[0];
    const float* ln1_g = (const float*)d_in[1];
    const float* ln1_b = (const float*)d_in[2];
    const float* w_qkv = (const float*)d_in[3];
    const float* b_qkv = (const float*)d_in[4];
    const float* w_out = (const float*)d_in[5];
    const float* b_out = (const float*)d_in[6];
    const float* ln2_g = (const float*)d_in[7];
    const float* ln2_b = (const float*)d_in[8];
    const float* w_ff1 = (const float*)d_in[9];
    const float* b_ff1 = (const float*)d_in[10];
    const float* w_ff2 = (const float*)d_in[11];
    const float* b_ff2 = (const float*)d_in[12];
    float* out = (float*)d_out;

    char* wsb = (char*)d_ws;
    unsigned short* h_bf    = (unsigned short*)(wsb);                          // 8 MB
    unsigned short* qkv_bf  = (unsigned short*)(wsb + 8ll  * 1024 * 1024);     // 24 MB
    unsigned short* attn_bf = (unsigned short*)(wsb + 32ll * 1024 * 1024);     // 8 MB
    float*          x1      = (float*)         (wsb + 40ll * 1024 * 1024);     // 16 MB
    unsigned short* vtg     = (unsigned short*)(wsb + 40ll * 1024 * 1024);     // 8 MB, overlays x1 (dead until step 4)
    unsigned short* wqkvT   = (unsigned short*)(wsb + 56ll * 1024 * 1024);     // 6 MB
    unsigned short* woutT   = (unsigned short*)(wsb + 62ll * 1024 * 1024);     // 2 MB
    unsigned short* wff1T   = (unsigned short*)(wsb + 64ll * 1024 * 1024);     // 8 MB
    unsigned short* wff2T   = (unsigned short*)(wsb + 72ll * 1024 * 1024);     // 8 MB
    unsigned short* ff1_bf  = (unsigned short*)(wsb + 8ll  * 1024 * 1024);     // 32 MB, overlays dead qkv+attn

    transpose_cast_kernel<<<dim3(48, 16), 256, 0, stream>>>(w_qkv, wqkvT, 1024, 3072);
    transpose_cast_kernel<<<dim3(16, 16), 256, 0, stream>>>(w_out, woutT, 1024, 1024);
    transpose_cast_kernel<<<dim3(64, 16), 256, 0, stream>>>(w_ff1, wff1T, 1024, 4096);
    transpose_cast_kernel<<<dim3(16, 64), 256, 0, stream>>>(w_ff2, wff2T, 4096, 1024);

    // 1. LN1 -> bf16
    ln_kernel<<<ROWS, 256, 0, stream>>>(x, ln1_g, ln1_b, h_bf);
    // 2. qkv = h @ w_qkv + b  -> bf16
    gemm_kernel<0><<<dim3(24, 32), 256, 0, stream>>>(h_bf, wqkvT, b_qkv, nullptr, qkv_bf, ROWS, 3072, 1024);
    // 2b. V transpose -> VtG[b][h][d][s]
    vtrans_kernel<<<dim3(32, 32), 256, 0, stream>>>(qkv_bf, vtg);
    // 3. causal flash attention -> bf16 (4096 single-wave blocks, 16-row q-strips)
    attn_kernel<<<4096, 64, 0, stream>>>(qkv_bf, vtg, attn_bf);
    // 4. x1 = x + attn @ w_out + b  -> f32   (overwrites vtg region; vtg is dead)
    gemm_kernel<1><<<dim3(8, 32), 256, 0, stream>>>(attn_bf, woutT, b_out, x, x1, ROWS, 1024, 1024);
    // 5. LN2 -> bf16
    ln_kernel<<<ROWS, 256, 0, stream>>>(x1, ln2_g, ln2_b, h_bf);
    // 6. ff1 = gelu(h @ w_ff1 + b)  -> bf16
    gemm_kernel<2><<<dim3(32, 32), 256, 0, stream>>>(h_bf, wff1T, b_ff1, nullptr, ff1_bf, ROWS, 4096, 1024);
    // 7. out = x1 + ff1 @ w_ff2 + b  -> f32
    gemm_kernel<1><<<dim3(8, 32), 256, 0, stream>>>(ff1_bf, wff2T, b_ff2, x1, (float*)out, ROWS, 1024, 4096);
}

// Round 8
// 324.988 us; speedup vs baseline: 1.1892x; 1.1892x over previous
//
#include <hip/hip_runtime.h>
#include <hip/hip_bf16.h>
#include <math.h>

#define TSEQ 2048
#define BATCH 2
#define CDIM 1024
#define NH 16
#define HD 64
#define DFF 4096
#define ROWS (BATCH*TSEQ)   // 4096

typedef __attribute__((ext_vector_type(4))) float f32x4;
typedef __attribute__((ext_vector_type(8))) short bf16x8;   // 8 bf16 in 4 VGPRs
typedef __attribute__((ext_vector_type(4))) unsigned short u16x4;

__device__ __forceinline__ void gload_lds16(const void* g, void* l) {
    void* gv = const_cast<void*>(g);
    __builtin_amdgcn_global_load_lds((__attribute__((address_space(1))) void*)gv,
                                     (__attribute__((address_space(3))) void*)l, 16, 0, 0);
}

__device__ __forceinline__ unsigned short f2bf(float f) {
    unsigned int u = __float_as_uint(f);
    return (unsigned short)((u + 0x7FFFu + ((u >> 16) & 1u)) >> 16);
}
__device__ __forceinline__ float bf2f(unsigned short u) {
    return __uint_as_float((unsigned int)u << 16);
}

// ------------------------------- LayerNorm -> bf16 --------------------------------
__global__ __launch_bounds__(256) void ln_kernel(const float* __restrict__ x,
                                                 const float* __restrict__ g,
                                                 const float* __restrict__ b,
                                                 unsigned short* __restrict__ out) {
    int row = blockIdx.x;
    int tid = threadIdx.x;
    const float* xr = x + (size_t)row * CDIM;
    float4 v = *(const float4*)(xr + tid * 4);
    float s  = v.x + v.y + v.z + v.w;
    float s2 = v.x*v.x + v.y*v.y + v.z*v.z + v.w*v.w;
    #pragma unroll
    for (int off = 32; off >= 1; off >>= 1) {
        s  += __shfl_down(s, off);
        s2 += __shfl_down(s2, off);
    }
    __shared__ float red[8];
    int wid = tid >> 6, lane = tid & 63;
    if (lane == 0) { red[wid] = s; red[wid + 4] = s2; }
    __syncthreads();
    float ts  = red[0] + red[1] + red[2] + red[3];
    float ts2 = red[4] + red[5] + red[6] + red[7];
    float mu  = ts * (1.0f / CDIM);
    float var = ts2 * (1.0f / CDIM) - mu * mu;
    float rstd = rsqrtf(var + 1e-5f);
    float4 gv = *(const float4*)(g + tid * 4);
    float4 bv = *(const float4*)(b + tid * 4);
    unsigned short o4[4];
    o4[0] = f2bf((v.x - mu) * rstd * gv.x + bv.x);
    o4[1] = f2bf((v.y - mu) * rstd * gv.y + bv.y);
    o4[2] = f2bf((v.z - mu) * rstd * gv.z + bv.z);
    o4[3] = f2bf((v.w - mu) * rstd * gv.w + bv.w);
    *(u16x4*)(out + (size_t)row * CDIM + tid * 4) = *(u16x4*)o4;
}

// --------------------- transpose + cast: W[K][N] f32 -> Wt[N][K] bf16 ---------------
__global__ __launch_bounds__(256) void transpose_cast_kernel(const float* __restrict__ W,
                                                             unsigned short* __restrict__ Wt,
                                                             int K, int N) {
    __shared__ float T[64][65];
    int tid = threadIdx.x;
    int n0 = blockIdx.x * 64, k0 = blockIdx.y * 64;
    int kr = tid >> 4;
    int nc = (tid & 15) * 4;
    #pragma unroll
    for (int i = 0; i < 4; ++i) {
        float4 v = *(const float4*)&W[(size_t)(k0 + kr + i*16) * N + (n0 + nc)];
        T[kr + i*16][nc + 0] = v.x;
        T[kr + i*16][nc + 1] = v.y;
        T[kr + i*16][nc + 2] = v.z;
        T[kr + i*16][nc + 3] = v.w;
    }
    __syncthreads();
    int n  = tid >> 2;
    int kb = (tid & 3) * 16;
    unsigned short tmp[16];
    #pragma unroll
    for (int i = 0; i < 16; ++i) tmp[i] = f2bf(T[kb + i][n]);
    unsigned short* dst = Wt + (size_t)(n0 + n) * K + (k0 + kb);
    *(int4*)dst       = *(int4*)&tmp[0];
    *(int4*)(dst + 8) = *(int4*)&tmp[8];
}

// ---- K/V fragment-major pre-pass --------------------------------------------------
// For each (b,h) and 64-row tile J: 8 K-chunks (sb 0..3, g 0..1) and 8 V-chunks
// (kb 0..1, db 0..3), each 64 lanes x 16B, laid out so attn's fragment load is one
// fully-coalesced 1KB wave-load:
//   kfrag[((bh*32+J)*8 + sb*2+g)*512 + l*8 + i] = K[J*64+sb*16+(l&15)][g*32+(l>>4)*8+i]
//   vfrag[((bh*32+J)*8 + kb*4+db)*512 + l*8 + i] = V[J*64+kb*32+(l>>4)*8+i][db*16+(l&15)]
// grid (32 tiles, 32 bh), 256 threads.
__global__ __launch_bounds__(256) void kvfrag_kernel(const unsigned short* __restrict__ qkv,
                                                     unsigned short* __restrict__ kfrag,
                                                     unsigned short* __restrict__ vfrag) {
    __shared__ unsigned short Kt[64][72];
    __shared__ unsigned short Vt[64][72];
    const int tid = threadIdx.x;
    const int j  = blockIdx.x;
    const int bh = blockIdx.y;
    const int b = bh >> 4, h = bh & 15;
    {
        const int r  = tid >> 2;
        const int c0 = (tid & 3) * 16;
        const unsigned short* src = qkv + ((size_t)(b * TSEQ + j * 64 + r)) * 3072 + 1024 + h * 64 + c0;
        bf16x8 k0 = *(const bf16x8*)src;
        bf16x8 k1 = *(const bf16x8*)(src + 8);
        bf16x8 v0 = *(const bf16x8*)(src + 1024);       // V part = +2048 total offset
        bf16x8 v1 = *(const bf16x8*)(src + 1032);
        *(bf16x8*)&Kt[r][c0]     = k0;
        *(bf16x8*)&Kt[r][c0 + 8] = k1;
        *(bf16x8*)&Vt[r][c0]     = v0;
        *(bf16x8*)&Vt[r][c0 + 8] = v1;
    }
    __syncthreads();
    const int l  = tid & 63;
    const int qd = tid >> 6;                            // 0..3
    const size_t tbase = ((size_t)(bh * 32 + j)) * 8 * 512;
    #pragma unroll
    for (int pass = 0; pass < 2; ++pass) {
        const int kc = qd + pass * 4;                   // K chunk 0..7
        const int sb = kc >> 1, g = kc & 1;
        bf16x8 kv = *(const bf16x8*)&Kt[sb * 16 + (l & 15)][g * 32 + (l >> 4) * 8];
        *(bf16x8*)(kfrag + tbase + kc * 512 + l * 8) = kv;

        const int vc = qd + pass * 4;                   // V chunk 0..7
        const int kb = vc >> 2, db = vc & 3;
        unsigned short tmp[8];
        #pragma unroll
        for (int i = 0; i < 8; ++i)
            tmp[i] = Vt[kb * 32 + (l >> 4) * 8 + i][db * 16 + (l & 15)];
        *(bf16x8*)(vfrag + tbase + vc * 512 + l * 8) = *(bf16x8*)tmp;
    }
}

// ---------------- MFMA GEMM (TN): C[M,N] = A[M,K](bf16) @ Bt[N,K](bf16)^T ----------
// EPI: 0 = bias -> bf16 out; 1 = bias + f32 residual -> f32 out; 2 = bias+GELU -> bf16 out
template<int EPI>
__global__ __launch_bounds__(256) void gemm_kernel(const unsigned short* __restrict__ A,
                                                   const unsigned short* __restrict__ Bt,
                                                   const float* __restrict__ bias,
                                                   const float* __restrict__ res,
                                                   void* __restrict__ Cout,
                                                   int M, int N, int K) {
    __shared__ __align__(16) unsigned short As[128 * 32];
    __shared__ __align__(16) unsigned short Bs[128 * 32];
    const int tid = threadIdx.x;
    const int l   = tid & 63;
    const int w   = tid >> 6;
    const int wr  = (w >> 1) * 64;
    const int wc  = (w & 1) * 64;
    const long brow = (long)blockIdx.y * 128;
    const long bcol = (long)blockIdx.x * 128;

    const unsigned short* gA0 = A  + (size_t)(brow + (tid >> 2)) * K + (tid & 3) * 8;
    const unsigned short* gA1 = gA0 + (size_t)64 * K;
    const unsigned short* gB0 = Bt + (size_t)(bcol + (tid >> 2)) * K + (tid & 3) * 8;
    const unsigned short* gB1 = gB0 + (size_t)64 * K;
    unsigned short* lA0 = As + tid * 8;
    unsigned short* lA1 = As + 2048 + tid * 8;
    unsigned short* lB0 = Bs + tid * 8;
    unsigned short* lB1 = Bs + 2048 + tid * 8;

    f32x4 acc[4][4];
    #pragma unroll
    for (int m = 0; m < 4; ++m)
        #pragma unroll
        for (int n = 0; n < 4; ++n) acc[m][n] = (f32x4){0.f, 0.f, 0.f, 0.f};

    const int aoff = (wr + (l & 15)) * 32 + (l >> 4) * 8;
    const int boff = (wc + (l & 15)) * 32 + (l >> 4) * 8;

    for (int k0 = 0; k0 < K; k0 += 32) {
        gload_lds16(gA0 + k0, lA0);
        gload_lds16(gA1 + k0, lA1);
        gload_lds16(gB0 + k0, lB0);
        gload_lds16(gB1 + k0, lB1);
        __syncthreads();
        bf16x8 af[4], bf[4];
        #pragma unroll
        for (int m = 0; m < 4; ++m) af[m] = *(const bf16x8*)&As[aoff + m * 512];
        #pragma unroll
        for (int n = 0; n < 4; ++n) bf[n] = *(const bf16x8*)&Bs[boff + n * 512];
        #pragma unroll
        for (int m = 0; m < 4; ++m)
            #pragma unroll
            for (int n = 0; n < 4; ++n)
                acc[m][n] = __builtin_amdgcn_mfma_f32_16x16x32_bf16(af[m], bf[n], acc[m][n], 0, 0, 0);
        __syncthreads();
    }

    #pragma unroll
    for (int m = 0; m < 4; ++m) {
        const int rown = wr + m * 16 + (l >> 4) * 4;
        #pragma unroll
        for (int n = 0; n < 4; ++n) {
            const long col = bcol + wc + n * 16 + (l & 15);
            const float bb = bias[col];
            #pragma unroll
            for (int r = 0; r < 4; ++r) {
                const long row = brow + rown + r;
                float v = acc[m][n][r] + bb;
                if (EPI == 1) {
                    v += res[row * N + col];
                    ((float*)Cout)[row * N + col] = v;
                } else if (EPI == 2) {
                    v = 0.5f * v * (1.0f + erff(v * 0.70710678118f));
                    ((unsigned short*)Cout)[row * N + col] = f2bf(v);
                } else {
                    ((unsigned short*)Cout)[row * N + col] = f2bf(v);
                }
            }
        }
    }
}

// ------------------- MFMA causal flash attention (single-wave blocks) ---------------
// One 64-lane wave per block; 16-row q-strip; K-tiles in PAIRS (128 cols per softmax
// pass). ALL K/V fragment loads are fully-coalesced 1KB chunk loads from the
// fragment-major kfrag/vfrag buffers (no gathers). Ps wave-private LDS (4 KB).
// Q pre-scaled by 0.125*log2e; softmax in exp2 domain.
// Grid 4096 = 8 xcd x (2 h x 2 b x 128 strips), longest strip first.
#define QSCALE 0.18033688011112042f   // 0.125 * log2(e)
__global__ __launch_bounds__(64) void attn_kernel(const unsigned short* __restrict__ qkv,
                                                  const unsigned short* __restrict__ kfrag,
                                                  const unsigned short* __restrict__ vfrag,
                                                  unsigned short* __restrict__ out) {
    __shared__ __align__(16) unsigned short Ps[16 * 128];   // [row][col], chunk-XOR swizzled

    const int l    = threadIdx.x;              // 0..63
    const int lin  = blockIdx.x;
    const int xcd  = lin & 7;
    const int rest = lin >> 3;                 // 0..511
    const int h    = xcd + 8 * (rest & 1);     // heads {x, x+8} pinned to XCD x
    const int b    = (rest >> 1) & 1;
    const int strip = 127 - (rest >> 2);       // longest first
    const int jmax  = strip >> 2;              // last K-tile index
    const size_t rowbase = (size_t)b * TSEQ;
    const int bh = b * NH + h;

    const unsigned short* kfb = kfrag + (size_t)bh * 32 * 8 * 512;  // + (J*8 + sb*2+g)*512 + l*8
    const unsigned short* vfb = vfrag + (size_t)bh * 32 * 8 * 512;  // + (J*8 + kb*4+db)*512 + l*8

    // Q fragments (A operand: row l&15, k-slice (l>>4)*8), pre-scaled
    bf16x8 aq0, aq1;
    {
        const int qrow = strip * 16 + (l & 15);
        const unsigned short* qp = qkv + (rowbase + qrow) * 3072 + h * 64 + (l >> 4) * 8;
        bf16x8 t0 = *(const bf16x8*)qp;
        bf16x8 t1 = *(const bf16x8*)(qp + 32);
        #pragma unroll
        for (int i = 0; i < 8; ++i) {
            aq0[i] = (short)f2bf(bf2f((unsigned short)t0[i]) * QSCALE);
            aq1[i] = (short)f2bf(bf2f((unsigned short)t1[i]) * QSCALE);
        }
    }

    float mrow[4], lrow[4];
    #pragma unroll
    for (int r = 0; r < 4; ++r) { mrow[r] = -INFINITY; lrow[r] = 0.f; }
    f32x4 o[4];
    #pragma unroll
    for (int d = 0; d < 4; ++d) o[d] = (f32x4){0.f, 0.f, 0.f, 0.f};

    const int qg = strip * 16 + (l >> 4) * 4;   // this lane's base q row (global)

    // ---------------- pair steps: tiles j, j+1 (128 cols per softmax) ----------------
    for (int j = 0; j + 1 <= jmax; j += 2) {
        const bool diag2 = (j + 1 == jmax);

        bf16x8 kf[16];
        #pragma unroll
        for (int t = 0; t < 2; ++t)
            #pragma unroll
            for (int sb = 0; sb < 4; ++sb) {
                const unsigned short* kp = kfb + (size_t)((j + t) * 8 + sb * 2) * 512 + l * 8;
                kf[t * 8 + sb * 2]     = *(const bf16x8*)kp;
                kf[t * 8 + sb * 2 + 1] = *(const bf16x8*)(kp + 512);
            }

        f32x4 sf[8];
        __builtin_amdgcn_s_setprio(1);
        #pragma unroll
        for (int t = 0; t < 2; ++t)
            #pragma unroll
            for (int sb = 0; sb < 4; ++sb) {
                f32x4 acc = (f32x4){0.f, 0.f, 0.f, 0.f};
                acc = __builtin_amdgcn_mfma_f32_16x16x32_bf16(aq0, kf[t*8 + sb*2],     acc, 0, 0, 0);
                acc = __builtin_amdgcn_mfma_f32_16x16x32_bf16(aq1, kf[t*8 + sb*2 + 1], acc, 0, 0, 0);
                sf[t*4 + sb] = acc;
            }
        __builtin_amdgcn_s_setprio(0);

        // V fragments for both tiles (kf regs dead; flat kb' = t*2+kb over 128 cols)
        bf16x8 vf[16];
        #pragma unroll
        for (int kb = 0; kb < 4; ++kb)
            #pragma unroll
            for (int db = 0; db < 4; ++db)
                vf[kb * 4 + db] = *(const bf16x8*)(vfb + (size_t)((j + (kb >> 1)) * 8 + (kb & 1) * 4 + db) * 512 + l * 8);

        // causal mask on the second tile if it is the diagonal
        if (diag2) {
            #pragma unroll
            for (int sb = 0; sb < 4; ++sb) {
                const int cg = (j + 1) * 64 + sb * 16 + (l & 15);
                #pragma unroll
                for (int r = 0; r < 4; ++r)
                    if (cg > qg + r) sf[4 + sb][r] = -INFINITY;
            }
        }

        // online softmax (exp2 domain) over 128 cols
        float mnew[4], alpha[4], psum[4];
        #pragma unroll
        for (int r = 0; r < 4; ++r) {
            float mx = fmaxf(fmaxf(fmaxf(sf[0][r], sf[1][r]), fmaxf(sf[2][r], sf[3][r])),
                             fmaxf(fmaxf(sf[4][r], sf[5][r]), fmaxf(sf[6][r], sf[7][r])));
            mx = fmaxf(mx, __shfl_xor(mx, 1));
            mx = fmaxf(mx, __shfl_xor(mx, 2));
            mx = fmaxf(mx, __shfl_xor(mx, 4));
            mx = fmaxf(mx, __shfl_xor(mx, 8));
            float mn = fmaxf(mrow[r], mx);
            mnew[r]  = mn;
            alpha[r] = exp2f(mrow[r] - mn);
            mrow[r]  = mn;
            psum[r]  = 0.f;
        }
        #pragma unroll
        for (int t = 0; t < 2; ++t)
            #pragma unroll
            for (int sb = 0; sb < 4; ++sb) {
                const int col = t * 64 + sb * 16 + (l & 15);
                #pragma unroll
                for (int r = 0; r < 4; ++r) {
                    float p = exp2f(sf[t*4 + sb][r] - mnew[r]);
                    psum[r] += p;
                    const int row = (l >> 4) * 4 + r;
                    Ps[row * 128 + (((col >> 3) ^ (row & 7)) << 3) + (col & 7)] = f2bf(p);
                }
            }
        #pragma unroll
        for (int r = 0; r < 4; ++r) {
            float ps = psum[r];
            ps += __shfl_xor(ps, 1);
            ps += __shfl_xor(ps, 2);
            ps += __shfl_xor(ps, 4);
            ps += __shfl_xor(ps, 8);
            lrow[r] = lrow[r] * alpha[r] + ps;
            #pragma unroll
            for (int d = 0; d < 4; ++d) o[d][r] *= alpha[r];
        }

        // O += P V over 128 cols (Ps wave-private; lgkmcnt orders write->read)
        __builtin_amdgcn_s_setprio(1);
        #pragma unroll
        for (int kb = 0; kb < 4; ++kb) {
            const int row = l & 15;
            bf16x8 pa = *(const bf16x8*)&Ps[row * 128 + (((kb * 4 + (l >> 4)) ^ (row & 7)) << 3)];
            #pragma unroll
            for (int db = 0; db < 4; ++db)
                o[db] = __builtin_amdgcn_mfma_f32_16x16x32_bf16(pa, vf[kb * 4 + db], o[db], 0, 0, 0);
        }
        __builtin_amdgcn_s_setprio(0);
    }

    // ---------------- tail single tile (j = jmax) when tile count is odd -------------
    if ((jmax & 1) == 0) {
        const int j = jmax;
        bf16x8 kf[8];
        #pragma unroll
        for (int sb = 0; sb < 4; ++sb) {
            const unsigned short* kp = kfb + (size_t)(j * 8 + sb * 2) * 512 + l * 8;
            kf[sb * 2]     = *(const bf16x8*)kp;
            kf[sb * 2 + 1] = *(const bf16x8*)(kp + 512);
        }
        f32x4 sf[4];
        __builtin_amdgcn_s_setprio(1);
        #pragma unroll
        for (int sb = 0; sb < 4; ++sb) {
            f32x4 acc = (f32x4){0.f, 0.f, 0.f, 0.f};
            acc = __builtin_amdgcn_mfma_f32_16x16x32_bf16(aq0, kf[sb*2],     acc, 0, 0, 0);
            acc = __builtin_amdgcn_mfma_f32_16x16x32_bf16(aq1, kf[sb*2 + 1], acc, 0, 0, 0);
            sf[sb] = acc;
        }
        __builtin_amdgcn_s_setprio(0);

        bf16x8 vf[8];
        #pragma unroll
        for (int kb = 0; kb < 2; ++kb)
            #pragma unroll
            for (int db = 0; db < 4; ++db)
                vf[kb * 4 + db] = *(const bf16x8*)(vfb + (size_t)(j * 8 + kb * 4 + db) * 512 + l * 8);
        #pragma unroll
        for (int sb = 0; sb < 4; ++sb) {
            const int cg = j * 64 + sb * 16 + (l & 15);
            #pragma unroll
            for (int r = 0; r < 4; ++r)
                if (cg > qg + r) sf[sb][r] = -INFINITY;
        }

        float mnew[4], alpha[4], psum[4];
        #pragma unroll
        for (int r = 0; r < 4; ++r) {
            float mx = fmaxf(fmaxf(sf[0][r], sf[1][r]), fmaxf(sf[2][r], sf[3][r]));
            mx = fmaxf(mx, __shfl_xor(mx, 1));
            mx = fmaxf(mx, __shfl_xor(mx, 2));
            mx = fmaxf(mx, __shfl_xor(mx, 4));
            mx = fmaxf(mx, __shfl_xor(mx, 8));
            float mn = fmaxf(mrow[r], mx);
            mnew[r]  = mn;
            alpha[r] = exp2f(mrow[r] - mn);
            mrow[r]  = mn;
            psum[r]  = 0.f;
        }
        #pragma unroll
        for (int sb = 0; sb < 4; ++sb) {
            const int col = sb * 16 + (l & 15);
            #pragma unroll
            for (int r = 0; r < 4; ++r) {
                float p = exp2f(sf[sb][r] - mnew[r]);
                psum[r] += p;
                const int row = (l >> 4) * 4 + r;
                Ps[row * 128 + (((col >> 3) ^ (row & 7)) << 3) + (col & 7)] = f2bf(p);
            }
        }
        #pragma unroll
        for (int r = 0; r < 4; ++r) {
            float ps = psum[r];
            ps += __shfl_xor(ps, 1);
            ps += __shfl_xor(ps, 2);
            ps += __shfl_xor(ps, 4);
            ps += __shfl_xor(ps, 8);
            lrow[r] = lrow[r] * alpha[r] + ps;
            #pragma unroll
            for (int d = 0; d < 4; ++d) o[d][r] *= alpha[r];
        }
        __builtin_amdgcn_s_setprio(1);
        #pragma unroll
        for (int kb = 0; kb < 2; ++kb) {
            const int row = l & 15;
            bf16x8 pa = *(const bf16x8*)&Ps[row * 128 + (((kb * 4 + (l >> 4)) ^ (row & 7)) << 3)];
            #pragma unroll
            for (int db = 0; db < 4; ++db)
                o[db] = __builtin_amdgcn_mfma_f32_16x16x32_bf16(pa, vf[kb * 4 + db], o[db], 0, 0, 0);
        }
        __builtin_amdgcn_s_setprio(0);
    }

    // epilogue: O / l -> bf16
    #pragma unroll
    for (int r = 0; r < 4; ++r) {
        const float inv = 1.0f / lrow[r];
        const size_t rb = (rowbase + strip * 16 + (l >> 4) * 4 + r) * (size_t)CDIM + h * 64 + (l & 15);
        #pragma unroll
        for (int d = 0; d < 4; ++d)
            out[rb + d * 16] = f2bf(o[d][r] * inv);
    }
}

extern "C" void kernel_launch(void* const* d_in, const int* in_sizes, int n_in,
                              void* d_out, int out_size, void* d_ws, size_t ws_size,
                              hipStream_t stream) {
    const float* x     = (const float*)d_in[0];
    const float* ln1_g = (const float*)d_in[1];
    const float* ln1_b = (const float*)d_in[2];
    const float* w_qkv = (const float*)d_in[3];
    const float* b_qkv = (const float*)d_in[4];
    const float* w_out = (const float*)d_in[5];
    const float* b_out = (const float*)d_in[6];
    const float* ln2_g = (const float*)d_in[7];
    const float* ln2_b = (const float*)d_in[8];
    const float* w_ff1 = (const float*)d_in[9];
    const float* b_ff1 = (const float*)d_in[10];
    const float* w_ff2 = (const float*)d_in[11];
    const float* b_ff2 = (const float*)d_in[12];
    float* out = (float*)d_out;

    char* wsb = (char*)d_ws;
    unsigned short* h_bf    = (unsigned short*)(wsb);                          // 8 MB
    unsigned short* qkv_bf  = (unsigned short*)(wsb + 8ll  * 1024 * 1024);     // 24 MB
    unsigned short* attn_bf = (unsigned short*)(wsb + 32ll * 1024 * 1024);     // 8 MB
    float*          x1      = (float*)         (wsb + 40ll * 1024 * 1024);     // 16 MB
    unsigned short* kfrag   = (unsigned short*)(wsb + 40ll * 1024 * 1024);     // 8 MB (overlays x1, dead until step 4)
    unsigned short* vfrag   = (unsigned short*)(wsb + 48ll * 1024 * 1024);     // 8 MB (overlays x1, dead until step 4)
    unsigned short* wqkvT   = (unsigned short*)(wsb + 56ll * 1024 * 1024);     // 6 MB
    unsigned short* woutT   = (unsigned short*)(wsb + 62ll * 1024 * 1024);     // 2 MB
    unsigned short* wff1T   = (unsigned short*)(wsb + 64ll * 1024 * 1024);     // 8 MB
    unsigned short* wff2T   = (unsigned short*)(wsb + 72ll * 1024 * 1024);     // 8 MB
    unsigned short* ff1_bf  = (unsigned short*)(wsb + 8ll  * 1024 * 1024);     // 32 MB, overlays dead qkv+attn

    transpose_cast_kernel<<<dim3(48, 16), 256, 0, stream>>>(w_qkv, wqkvT, 1024, 3072);
    transpose_cast_kernel<<<dim3(16, 16), 256, 0, stream>>>(w_out, woutT, 1024, 1024);
    transpose_cast_kernel<<<dim3(64, 16), 256, 0, stream>>>(w_ff1, wff1T, 1024, 4096);
    transpose_cast_kernel<<<dim3(16, 64), 256, 0, stream>>>(w_ff2, wff2T, 4096, 1024);

    // 1. LN1 -> bf16
    ln_kernel<<<ROWS, 256, 0, stream>>>(x, ln1_g, ln1_b, h_bf);
    // 2. qkv = h @ w_qkv + b  -> bf16
    gemm_kernel<0><<<dim3(24, 32), 256, 0, stream>>>(h_bf, wqkvT, b_qkv, nullptr, qkv_bf, ROWS, 3072, 1024);
    // 2b. K/V fragment-major pre-pass
    kvfrag_kernel<<<dim3(32, 32), 256, 0, stream>>>(qkv_bf, kfrag, vfrag);
    // 3. causal flash attention -> bf16 (4096 single-wave blocks, coalesced frag loads)
    attn_kernel<<<4096, 64, 0, stream>>>(qkv_bf, kfrag, vfrag, attn_bf);
    // 4. x1 = x + attn @ w_out + b  -> f32   (overwrites kfrag/vfrag region; dead now)
    gemm_kernel<1><<<dim3(8, 32), 256, 0, stream>>>(attn_bf, woutT, b_out, x, x1, ROWS, 1024, 1024);
    // 5. LN2 -> bf16
    ln_kernel<<<ROWS, 256, 0, stream>>>(x1, ln2_g, ln2_b, h_bf);
    // 6. ff1 = gelu(h @ w_ff1 + b)  -> bf16
    gemm_kernel<2><<<dim3(32, 32), 256, 0, stream>>>(h_bf, wff1T, b_ff1, nullptr, ff1_bf, ROWS, 4096, 1024);
    // 7. out = x1 + ff1 @ w_ff2 + b  -> f32
    gemm_kernel<1><<<dim3(8, 32), 256, 0, stream>>>(ff1_bf, wff2T, b_ff2, x1, (float*)out, ROWS, 1024, 4096);
}

// Round 9
// 291.541 us; speedup vs baseline: 1.3256x; 1.1147x over previous
//
#include <hip/hip_runtime.h>
#include <hip/hip_bf16.h>
#include <math.h>

#define TSEQ 2048
#define BATCH 2
#define CDIM 1024
#define NH 16
#define HD 64
#define DFF 4096
#define ROWS (BATCH*TSEQ)   // 4096

typedef __attribute__((ext_vector_type(4))) float f32x4;
typedef __attribute__((ext_vector_type(8))) short bf16x8;   // 8 bf16 in 4 VGPRs
typedef __attribute__((ext_vector_type(4))) unsigned short u16x4;

__device__ __forceinline__ void gload_lds16(const void* g, void* l) {
    void* gv = const_cast<void*>(g);
    __builtin_amdgcn_global_load_lds((__attribute__((address_space(1))) void*)gv,
                                     (__attribute__((address_space(3))) void*)l, 16, 0, 0);
}

__device__ __forceinline__ unsigned short f2bf(float f) {
    unsigned int u = __float_as_uint(f);
    return (unsigned short)((u + 0x7FFFu + ((u >> 16) & 1u)) >> 16);
}
__device__ __forceinline__ float bf2f(unsigned short u) {
    return __uint_as_float((unsigned int)u << 16);
}

// ------------------------------- LayerNorm -> bf16 --------------------------------
__global__ __launch_bounds__(256) void ln_kernel(const float* __restrict__ x,
                                                 const float* __restrict__ g,
                                                 const float* __restrict__ b,
                                                 unsigned short* __restrict__ out) {
    int row = blockIdx.x;
    int tid = threadIdx.x;
    const float* xr = x + (size_t)row * CDIM;
    float4 v = *(const float4*)(xr + tid * 4);
    float s  = v.x + v.y + v.z + v.w;
    float s2 = v.x*v.x + v.y*v.y + v.z*v.z + v.w*v.w;
    #pragma unroll
    for (int off = 32; off >= 1; off >>= 1) {
        s  += __shfl_down(s, off);
        s2 += __shfl_down(s2, off);
    }
    __shared__ float red[8];
    int wid = tid >> 6, lane = tid & 63;
    if (lane == 0) { red[wid] = s; red[wid + 4] = s2; }
    __syncthreads();
    float ts  = red[0] + red[1] + red[2] + red[3];
    float ts2 = red[4] + red[5] + red[6] + red[7];
    float mu  = ts * (1.0f / CDIM);
    float var = ts2 * (1.0f / CDIM) - mu * mu;
    float rstd = rsqrtf(var + 1e-5f);
    float4 gv = *(const float4*)(g + tid * 4);
    float4 bv = *(const float4*)(b + tid * 4);
    unsigned short o4[4];
    o4[0] = f2bf((v.x - mu) * rstd * gv.x + bv.x);
    o4[1] = f2bf((v.y - mu) * rstd * gv.y + bv.y);
    o4[2] = f2bf((v.z - mu) * rstd * gv.z + bv.z);
    o4[3] = f2bf((v.w - mu) * rstd * gv.w + bv.w);
    *(u16x4*)(out + (size_t)row * CDIM + tid * 4) = *(u16x4*)o4;
}

// --------------------- transpose + cast: W[K][N] f32 -> Wt[N][K] bf16 ---------------
__global__ __launch_bounds__(256) void transpose_cast_kernel(const float* __restrict__ W,
                                                             unsigned short* __restrict__ Wt,
                                                             int K, int N) {
    __shared__ float T[64][65];
    int tid = threadIdx.x;
    int n0 = blockIdx.x * 64, k0 = blockIdx.y * 64;
    int kr = tid >> 4;
    int nc = (tid & 15) * 4;
    #pragma unroll
    for (int i = 0; i < 4; ++i) {
        float4 v = *(const float4*)&W[(size_t)(k0 + kr + i*16) * N + (n0 + nc)];
        T[kr + i*16][nc + 0] = v.x;
        T[kr + i*16][nc + 1] = v.y;
        T[kr + i*16][nc + 2] = v.z;
        T[kr + i*16][nc + 3] = v.w;
    }
    __syncthreads();
    int n  = tid >> 2;
    int kb = (tid & 3) * 16;
    unsigned short tmp[16];
    #pragma unroll
    for (int i = 0; i < 16; ++i) tmp[i] = f2bf(T[kb + i][n]);
    unsigned short* dst = Wt + (size_t)(n0 + n) * K + (k0 + kb);
    *(int4*)dst       = *(int4*)&tmp[0];
    *(int4*)(dst + 8) = *(int4*)&tmp[8];
}

// ---- K/V fragment-major pre-pass (see R8 notes) -----------------------------------
__global__ __launch_bounds__(256) void kvfrag_kernel(const unsigned short* __restrict__ qkv,
                                                     unsigned short* __restrict__ kfrag,
                                                     unsigned short* __restrict__ vfrag) {
    __shared__ unsigned short Kt[64][72];
    __shared__ unsigned short Vt[64][72];
    const int tid = threadIdx.x;
    const int j  = blockIdx.x;
    const int bh = blockIdx.y;
    const int b = bh >> 4, h = bh & 15;
    {
        const int r  = tid >> 2;
        const int c0 = (tid & 3) * 16;
        const unsigned short* src = qkv + ((size_t)(b * TSEQ + j * 64 + r)) * 3072 + 1024 + h * 64 + c0;
        bf16x8 k0 = *(const bf16x8*)src;
        bf16x8 k1 = *(const bf16x8*)(src + 8);
        bf16x8 v0 = *(const bf16x8*)(src + 1024);
        bf16x8 v1 = *(const bf16x8*)(src + 1032);
        *(bf16x8*)&Kt[r][c0]     = k0;
        *(bf16x8*)&Kt[r][c0 + 8] = k1;
        *(bf16x8*)&Vt[r][c0]     = v0;
        *(bf16x8*)&Vt[r][c0 + 8] = v1;
    }
    __syncthreads();
    const int l  = tid & 63;
    const int qd = tid >> 6;
    const size_t tbase = ((size_t)(bh * 32 + j)) * 8 * 512;
    #pragma unroll
    for (int pass = 0; pass < 2; ++pass) {
        const int kc = qd + pass * 4;
        const int sb = kc >> 1, g = kc & 1;
        bf16x8 kv = *(const bf16x8*)&Kt[sb * 16 + (l & 15)][g * 32 + (l >> 4) * 8];
        *(bf16x8*)(kfrag + tbase + kc * 512 + l * 8) = kv;

        const int vc = qd + pass * 4;
        const int kb = vc >> 2, db = vc & 3;
        unsigned short tmp[8];
        #pragma unroll
        for (int i = 0; i < 8; ++i)
            tmp[i] = Vt[kb * 32 + (l >> 4) * 8 + i][db * 16 + (l & 15)];
        *(bf16x8*)(vfrag + tbase + vc * 512 + l * 8) = *(bf16x8*)tmp;
    }
}

// ---------------- MFMA GEMM (TN) 128x128 tile: C = A @ Bt^T + bias (+epi) ----------
template<int EPI>
__global__ __launch_bounds__(256) void gemm_kernel(const unsigned short* __restrict__ A,
                                                   const unsigned short* __restrict__ Bt,
                                                   const float* __restrict__ bias,
                                                   const float* __restrict__ res,
                                                   void* __restrict__ Cout,
                                                   int M, int N, int K) {
    __shared__ __align__(16) unsigned short As[128 * 32];
    __shared__ __align__(16) unsigned short Bs[128 * 32];
    const int tid = threadIdx.x;
    const int l   = tid & 63;
    const int w   = tid >> 6;
    const int wr  = (w >> 1) * 64;
    const int wc  = (w & 1) * 64;
    const long brow = (long)blockIdx.y * 128;
    const long bcol = (long)blockIdx.x * 128;

    const unsigned short* gA0 = A  + (size_t)(brow + (tid >> 2)) * K + (tid & 3) * 8;
    const unsigned short* gA1 = gA0 + (size_t)64 * K;
    const unsigned short* gB0 = Bt + (size_t)(bcol + (tid >> 2)) * K + (tid & 3) * 8;
    const unsigned short* gB1 = gB0 + (size_t)64 * K;
    unsigned short* lA0 = As + tid * 8;
    unsigned short* lA1 = As + 2048 + tid * 8;
    unsigned short* lB0 = Bs + tid * 8;
    unsigned short* lB1 = Bs + 2048 + tid * 8;

    f32x4 acc[4][4];
    #pragma unroll
    for (int m = 0; m < 4; ++m)
        #pragma unroll
        for (int n = 0; n < 4; ++n) acc[m][n] = (f32x4){0.f, 0.f, 0.f, 0.f};

    const int aoff = (wr + (l & 15)) * 32 + (l >> 4) * 8;
    const int boff = (wc + (l & 15)) * 32 + (l >> 4) * 8;

    for (int k0 = 0; k0 < K; k0 += 32) {
        gload_lds16(gA0 + k0, lA0);
        gload_lds16(gA1 + k0, lA1);
        gload_lds16(gB0 + k0, lB0);
        gload_lds16(gB1 + k0, lB1);
        __syncthreads();
        bf16x8 af[4], bf[4];
        #pragma unroll
        for (int m = 0; m < 4; ++m) af[m] = *(const bf16x8*)&As[aoff + m * 512];
        #pragma unroll
        for (int n = 0; n < 4; ++n) bf[n] = *(const bf16x8*)&Bs[boff + n * 512];
        #pragma unroll
        for (int m = 0; m < 4; ++m)
            #pragma unroll
            for (int n = 0; n < 4; ++n)
                acc[m][n] = __builtin_amdgcn_mfma_f32_16x16x32_bf16(af[m], bf[n], acc[m][n], 0, 0, 0);
        __syncthreads();
    }

    #pragma unroll
    for (int m = 0; m < 4; ++m) {
        const int rown = wr + m * 16 + (l >> 4) * 4;
        #pragma unroll
        for (int n = 0; n < 4; ++n) {
            const long col = bcol + wc + n * 16 + (l & 15);
            const float bb = bias[col];
            #pragma unroll
            for (int r = 0; r < 4; ++r) {
                const long row = brow + rown + r;
                float v = acc[m][n][r] + bb;
                if (EPI == 1) {
                    v += res[row * N + col];
                    ((float*)Cout)[row * N + col] = v;
                } else if (EPI == 2) {
                    v = 0.5f * v * (1.0f + erff(v * 0.70710678118f));
                    ((unsigned short*)Cout)[row * N + col] = f2bf(v);
                } else {
                    ((unsigned short*)Cout)[row * N + col] = f2bf(v);
                }
            }
        }
    }
}

// ---------------- MFMA GEMM (TN) 64x128 tile: for N=1024 GEMMs (2 blocks/CU) -------
// 4 waves as 2x2 (each 32 rows x 64 cols, acc[2][4]); LDS 12 KB; 3 gload_lds/thread.
template<int EPI>
__global__ __launch_bounds__(256) void gemm64_kernel(const unsigned short* __restrict__ A,
                                                     const unsigned short* __restrict__ Bt,
                                                     const float* __restrict__ bias,
                                                     const float* __restrict__ res,
                                                     void* __restrict__ Cout,
                                                     int M, int N, int K) {
    __shared__ __align__(16) unsigned short As[64 * 32];
    __shared__ __align__(16) unsigned short Bs[128 * 32];
    const int tid = threadIdx.x;
    const int l   = tid & 63;
    const int w   = tid >> 6;
    const int wr  = (w >> 1) * 32;
    const int wc  = (w & 1) * 64;
    const long brow = (long)blockIdx.y * 64;
    const long bcol = (long)blockIdx.x * 128;

    const unsigned short* gA0 = A  + (size_t)(brow + (tid >> 2)) * K + (tid & 3) * 8;   // 64 rows
    const unsigned short* gB0 = Bt + (size_t)(bcol + (tid >> 2)) * K + (tid & 3) * 8;   // cols 0-63
    const unsigned short* gB1 = gB0 + (size_t)64 * K;                                   // cols 64-127
    unsigned short* lA0 = As + tid * 8;
    unsigned short* lB0 = Bs + tid * 8;
    unsigned short* lB1 = Bs + 2048 + tid * 8;

    f32x4 acc[2][4];
    #pragma unroll
    for (int m = 0; m < 2; ++m)
        #pragma unroll
        for (int n = 0; n < 4; ++n) acc[m][n] = (f32x4){0.f, 0.f, 0.f, 0.f};

    const int aoff = (wr + (l & 15)) * 32 + (l >> 4) * 8;   // + m*512
    const int boff = (wc + (l & 15)) * 32 + (l >> 4) * 8;   // + n*512

    for (int k0 = 0; k0 < K; k0 += 32) {
        gload_lds16(gA0 + k0, lA0);
        gload_lds16(gB0 + k0, lB0);
        gload_lds16(gB1 + k0, lB1);
        __syncthreads();
        bf16x8 af[2], bf[4];
        #pragma unroll
        for (int m = 0; m < 2; ++m) af[m] = *(const bf16x8*)&As[aoff + m * 512];
        #pragma unroll
        for (int n = 0; n < 4; ++n) bf[n] = *(const bf16x8*)&Bs[boff + n * 512];
        #pragma unroll
        for (int m = 0; m < 2; ++m)
            #pragma unroll
            for (int n = 0; n < 4; ++n)
                acc[m][n] = __builtin_amdgcn_mfma_f32_16x16x32_bf16(af[m], bf[n], acc[m][n], 0, 0, 0);
        __syncthreads();
    }

    #pragma unroll
    for (int m = 0; m < 2; ++m) {
        const int rown = wr + m * 16 + (l >> 4) * 4;
        #pragma unroll
        for (int n = 0; n < 4; ++n) {
            const long col = bcol + wc + n * 16 + (l & 15);
            const float bb = bias[col];
            #pragma unroll
            for (int r = 0; r < 4; ++r) {
                const long row = brow + rown + r;
                float v = acc[m][n][r] + bb;
                if (EPI == 1) {
                    v += res[row * N + col];
                    ((float*)Cout)[row * N + col] = v;
                } else if (EPI == 2) {
                    v = 0.5f * v * (1.0f + erff(v * 0.70710678118f));
                    ((unsigned short*)Cout)[row * N + col] = f2bf(v);
                } else {
                    ((unsigned short*)Cout)[row * N + col] = f2bf(v);
                }
            }
        }
    }
}

// ------------------- MFMA causal flash attention (single-wave blocks) ---------------
#define QSCALE 0.18033688011112042f   // 0.125 * log2(e)
__global__ __launch_bounds__(64) void attn_kernel(const unsigned short* __restrict__ qkv,
                                                  const unsigned short* __restrict__ kfrag,
                                                  const unsigned short* __restrict__ vfrag,
                                                  unsigned short* __restrict__ out) {
    __shared__ __align__(16) unsigned short Ps[16 * 128];   // [row][col], chunk-XOR swizzled

    const int l    = threadIdx.x;
    const int lin  = blockIdx.x;
    const int xcd  = lin & 7;
    const int rest = lin >> 3;
    const int h    = xcd + 8 * (rest & 1);
    const int b    = (rest >> 1) & 1;
    const int strip = 127 - (rest >> 2);
    const int jmax  = strip >> 2;
    const size_t rowbase = (size_t)b * TSEQ;
    const int bh = b * NH + h;

    const unsigned short* kfb = kfrag + (size_t)bh * 32 * 8 * 512;
    const unsigned short* vfb = vfrag + (size_t)bh * 32 * 8 * 512;

    bf16x8 aq0, aq1;
    {
        const int qrow = strip * 16 + (l & 15);
        const unsigned short* qp = qkv + (rowbase + qrow) * 3072 + h * 64 + (l >> 4) * 8;
        bf16x8 t0 = *(const bf16x8*)qp;
        bf16x8 t1 = *(const bf16x8*)(qp + 32);
        #pragma unroll
        for (int i = 0; i < 8; ++i) {
            aq0[i] = (short)f2bf(bf2f((unsigned short)t0[i]) * QSCALE);
            aq1[i] = (short)f2bf(bf2f((unsigned short)t1[i]) * QSCALE);
        }
    }

    float mrow[4], lrow[4];
    #pragma unroll
    for (int r = 0; r < 4; ++r) { mrow[r] = -INFINITY; lrow[r] = 0.f; }
    f32x4 o[4];
    #pragma unroll
    for (int d = 0; d < 4; ++d) o[d] = (f32x4){0.f, 0.f, 0.f, 0.f};

    const int qg = strip * 16 + (l >> 4) * 4;

    for (int j = 0; j + 1 <= jmax; j += 2) {
        const bool diag2 = (j + 1 == jmax);

        bf16x8 kf[16];
        #pragma unroll
        for (int t = 0; t < 2; ++t)
            #pragma unroll
            for (int sb = 0; sb < 4; ++sb) {
                const unsigned short* kp = kfb + (size_t)((j + t) * 8 + sb * 2) * 512 + l * 8;
                kf[t * 8 + sb * 2]     = *(const bf16x8*)kp;
                kf[t * 8 + sb * 2 + 1] = *(const bf16x8*)(kp + 512);
            }

        f32x4 sf[8];
        __builtin_amdgcn_s_setprio(1);
        #pragma unroll
        for (int t = 0; t < 2; ++t)
            #pragma unroll
            for (int sb = 0; sb < 4; ++sb) {
                f32x4 acc = (f32x4){0.f, 0.f, 0.f, 0.f};
                acc = __builtin_amdgcn_mfma_f32_16x16x32_bf16(aq0, kf[t*8 + sb*2],     acc, 0, 0, 0);
                acc = __builtin_amdgcn_mfma_f32_16x16x32_bf16(aq1, kf[t*8 + sb*2 + 1], acc, 0, 0, 0);
                sf[t*4 + sb] = acc;
            }
        __builtin_amdgcn_s_setprio(0);

        bf16x8 vf[16];
        #pragma unroll
        for (int kb = 0; kb < 4; ++kb)
            #pragma unroll
            for (int db = 0; db < 4; ++db)
                vf[kb * 4 + db] = *(const bf16x8*)(vfb + (size_t)((j + (kb >> 1)) * 8 + (kb & 1) * 4 + db) * 512 + l * 8);

        if (diag2) {
            #pragma unroll
            for (int sb = 0; sb < 4; ++sb) {
                const int cg = (j + 1) * 64 + sb * 16 + (l & 15);
                #pragma unroll
                for (int r = 0; r < 4; ++r)
                    if (cg > qg + r) sf[4 + sb][r] = -INFINITY;
            }
        }

        float mnew[4], alpha[4], psum[4];
        #pragma unroll
        for (int r = 0; r < 4; ++r) {
            float mx = fmaxf(fmaxf(fmaxf(sf[0][r], sf[1][r]), fmaxf(sf[2][r], sf[3][r])),
                             fmaxf(fmaxf(sf[4][r], sf[5][r]), fmaxf(sf[6][r], sf[7][r])));
            mx = fmaxf(mx, __shfl_xor(mx, 1));
            mx = fmaxf(mx, __shfl_xor(mx, 2));
            mx = fmaxf(mx, __shfl_xor(mx, 4));
            mx = fmaxf(mx, __shfl_xor(mx, 8));
            float mn = fmaxf(mrow[r], mx);
            mnew[r]  = mn;
            alpha[r] = exp2f(mrow[r] - mn);
            mrow[r]  = mn;
            psum[r]  = 0.f;
        }
        #pragma unroll
        for (int t = 0; t < 2; ++t)
            #pragma unroll
            for (int sb = 0; sb < 4; ++sb) {
                const int col = t * 64 + sb * 16 + (l & 15);
                #pragma unroll
                for (int r = 0; r < 4; ++r) {
                    float p = exp2f(sf[t*4 + sb][r] - mnew[r]);
                    psum[r] += p;
                    const int row = (l >> 4) * 4 + r;
                    Ps[row * 128 + (((col >> 3) ^ (row & 7)) << 3) + (col & 7)] = f2bf(p);
                }
            }
        #pragma unroll
        for (int r = 0; r < 4; ++r) {
            float ps = psum[r];
            ps += __shfl_xor(ps, 1);
            ps += __shfl_xor(ps, 2);
            ps += __shfl_xor(ps, 4);
            ps += __shfl_xor(ps, 8);
            lrow[r] = lrow[r] * alpha[r] + ps;
            #pragma unroll
            for (int d = 0; d < 4; ++d) o[d][r] *= alpha[r];
        }

        __builtin_amdgcn_s_setprio(1);
        #pragma unroll
        for (int kb = 0; kb < 4; ++kb) {
            const int row = l & 15;
            bf16x8 pa = *(const bf16x8*)&Ps[row * 128 + (((kb * 4 + (l >> 4)) ^ (row & 7)) << 3)];
            #pragma unroll
            for (int db = 0; db < 4; ++db)
                o[db] = __builtin_amdgcn_mfma_f32_16x16x32_bf16(pa, vf[kb * 4 + db], o[db], 0, 0, 0);
        }
        __builtin_amdgcn_s_setprio(0);
    }

    if ((jmax & 1) == 0) {
        const int j = jmax;
        bf16x8 kf[8];
        #pragma unroll
        for (int sb = 0; sb < 4; ++sb) {
            const unsigned short* kp = kfb + (size_t)(j * 8 + sb * 2) * 512 + l * 8;
            kf[sb * 2]     = *(const bf16x8*)kp;
            kf[sb * 2 + 1] = *(const bf16x8*)(kp + 512);
        }
        f32x4 sf[4];
        __builtin_amdgcn_s_setprio(1);
        #pragma unroll
        for (int sb = 0; sb < 4; ++sb) {
            f32x4 acc = (f32x4){0.f, 0.f, 0.f, 0.f};
            acc = __builtin_amdgcn_mfma_f32_16x16x32_bf16(aq0, kf[sb*2],     acc, 0, 0, 0);
            acc = __builtin_amdgcn_mfma_f32_16x16x32_bf16(aq1, kf[sb*2 + 1], acc, 0, 0, 0);
            sf[sb] = acc;
        }
        __builtin_amdgcn_s_setprio(0);

        bf16x8 vf[8];
        #pragma unroll
        for (int kb = 0; kb < 2; ++kb)
            #pragma unroll
            for (int db = 0; db < 4; ++db)
                vf[kb * 4 + db] = *(const bf16x8*)(vfb + (size_t)(j * 8 + kb * 4 + db) * 512 + l * 8);
        #pragma unroll
        for (int sb = 0; sb < 4; ++sb) {
            const int cg = j * 64 + sb * 16 + (l & 15);
            #pragma unroll
            for (int r = 0; r < 4; ++r)
                if (cg > qg + r) sf[sb][r] = -INFINITY;
        }

        float mnew[4], alpha[4], psum[4];
        #pragma unroll
        for (int r = 0; r < 4; ++r) {
            float mx = fmaxf(fmaxf(sf[0][r], sf[1][r]), fmaxf(sf[2][r], sf[3][r]));
            mx = fmaxf(mx, __shfl_xor(mx, 1));
            mx = fmaxf(mx, __shfl_xor(mx, 2));
            mx = fmaxf(mx, __shfl_xor(mx, 4));
            mx = fmaxf(mx, __shfl_xor(mx, 8));
            float mn = fmaxf(mrow[r], mx);
            mnew[r]  = mn;
            alpha[r] = exp2f(mrow[r] - mn);
            mrow[r]  = mn;
            psum[r]  = 0.f;
        }
        #pragma unroll
        for (int sb = 0; sb < 4; ++sb) {
            const int col = sb * 16 + (l & 15);
            #pragma unroll
            for (int r = 0; r < 4; ++r) {
                float p = exp2f(sf[sb][r] - mnew[r]);
                psum[r] += p;
                const int row = (l >> 4) * 4 + r;
                Ps[row * 128 + (((col >> 3) ^ (row & 7)) << 3) + (col & 7)] = f2bf(p);
            }
        }
        #pragma unroll
        for (int r = 0; r < 4; ++r) {
            float ps = psum[r];
            ps += __shfl_xor(ps, 1);
            ps += __shfl_xor(ps, 2);
            ps += __shfl_xor(ps, 4);
            ps += __shfl_xor(ps, 8);
            lrow[r] = lrow[r] * alpha[r] + ps;
            #pragma unroll
            for (int d = 0; d < 4; ++d) o[d][r] *= alpha[r];
        }
        __builtin_amdgcn_s_setprio(1);
        #pragma unroll
        for (int kb = 0; kb < 2; ++kb) {
            const int row = l & 15;
            bf16x8 pa = *(const bf16x8*)&Ps[row * 128 + (((kb * 4 + (l >> 4)) ^ (row & 7)) << 3)];
            #pragma unroll
            for (int db = 0; db < 4; ++db)
                o[db] = __builtin_amdgcn_mfma_f32_16x16x32_bf16(pa, vf[kb * 4 + db], o[db], 0, 0, 0);
        }
        __builtin_amdgcn_s_setprio(0);
    }

    #pragma unroll
    for (int r = 0; r < 4; ++r) {
        const float inv = 1.0f / lrow[r];
        const size_t rb = (rowbase + strip * 16 + (l >> 4) * 4 + r) * (size_t)CDIM + h * 64 + (l & 15);
        #pragma unroll
        for (int d = 0; d < 4; ++d)
            out[rb + d * 16] = f2bf(o[d][r] * inv);
    }
}

extern "C" void kernel_launch(void* const* d_in, const int* in_sizes, int n_in,
                              void* d_out, int out_size, void* d_ws, size_t ws_size,
                              hipStream_t stream) {
    const float* x     = (const float*)d_in[0];
    const float* ln1_g = (const float*)d_in[1];
    const float* ln1_b = (const float*)d_in[2];
    const float* w_qkv = (const float*)d_in[3];
    const float* b_qkv = (const float*)d_in[4];
    const float* w_out = (const float*)d_in[5];
    const float* b_out = (const float*)d_in[6];
    const float* ln2_g = (const float*)d_in[7];
    const float* ln2_b = (const float*)d_in[8];
    const float* w_ff1 = (const float*)d_in[9];
    const float* b_ff1 = (const float*)d_in[10];
    const float* w_ff2 = (const float*)d_in[11];
    const float* b_ff2 = (const float*)d_in[12];
    float* out = (float*)d_out;

    char* wsb = (char*)d_ws;
    unsigned short* h_bf    = (unsigned short*)(wsb);                          // 8 MB
    unsigned short* qkv_bf  = (unsigned short*)(wsb + 8ll  * 1024 * 1024);     // 24 MB
    unsigned short* attn_bf = (unsigned short*)(wsb + 32ll * 1024 * 1024);     // 8 MB
    float*          x1      = (float*)         (wsb + 40ll * 1024 * 1024);     // 16 MB
    unsigned short* kfrag   = (unsigned short*)(wsb + 40ll * 1024 * 1024);     // 8 MB (overlays x1, dead until step 4)
    unsigned short* vfrag   = (unsigned short*)(wsb + 48ll * 1024 * 1024);     // 8 MB (overlays x1, dead until step 4)
    unsigned short* wqkvT   = (unsigned short*)(wsb + 56ll * 1024 * 1024);     // 6 MB
    unsigned short* woutT   = (unsigned short*)(wsb + 62ll * 1024 * 1024);     // 2 MB
    unsigned short* wff1T   = (unsigned short*)(wsb + 64ll * 1024 * 1024);     // 8 MB
    unsigned short* wff2T   = (unsigned short*)(wsb + 72ll * 1024 * 1024);     // 8 MB
    unsigned short* ff1_bf  = (unsigned short*)(wsb + 8ll  * 1024 * 1024);     // 32 MB, overlays dead qkv+attn

    transpose_cast_kernel<<<dim3(48, 16), 256, 0, stream>>>(w_qkv, wqkvT, 1024, 3072);
    transpose_cast_kernel<<<dim3(16, 16), 256, 0, stream>>>(w_out, woutT, 1024, 1024);
    transpose_cast_kernel<<<dim3(64, 16), 256, 0, stream>>>(w_ff1, wff1T, 1024, 4096);
    transpose_cast_kernel<<<dim3(16, 64), 256, 0, stream>>>(w_ff2, wff2T, 4096, 1024);

    // 1. LN1 -> bf16
    ln_kernel<<<ROWS, 256, 0, stream>>>(x, ln1_g, ln1_b, h_bf);
    // 2. qkv = h @ w_qkv + b  -> bf16
    gemm_kernel<0><<<dim3(24, 32), 256, 0, stream>>>(h_bf, wqkvT, b_qkv, nullptr, qkv_bf, ROWS, 3072, 1024);
    // 2b. K/V fragment-major pre-pass
    kvfrag_kernel<<<dim3(32, 32), 256, 0, stream>>>(qkv_bf, kfrag, vfrag);
    // 3. causal flash attention -> bf16
    attn_kernel<<<4096, 64, 0, stream>>>(qkv_bf, kfrag, vfrag, attn_bf);
    // 4. x1 = x + attn @ w_out + b  -> f32  (64x128 tile, 512 blocks = 2/CU)
    gemm64_kernel<1><<<dim3(8, 64), 256, 0, stream>>>(attn_bf, woutT, b_out, x, x1, ROWS, 1024, 1024);
    // 5. LN2 -> bf16
    ln_kernel<<<ROWS, 256, 0, stream>>>(x1, ln2_g, ln2_b, h_bf);
    // 6. ff1 = gelu(h @ w_ff1 + b)  -> bf16
    gemm_kernel<2><<<dim3(32, 32), 256, 0, stream>>>(h_bf, wff1T, b_ff1, nullptr, ff1_bf, ROWS, 4096, 1024);
    // 7. out = x1 + ff1 @ w_ff2 + b  -> f32  (64x128 tile, 512 blocks = 2/CU)
    gemm64_kernel<1><<<dim3(8, 64), 256, 0, stream>>>(ff1_bf, wff2T, b_ff2, x1, (float*)out, ROWS, 1024, 4096);
}

// Round 10
// 280.478 us; speedup vs baseline: 1.3779x; 1.0394x over previous
//
#include <hip/hip_runtime.h>
#include <hip/hip_bf16.h>
#include <math.h>

#define TSEQ 2048
#define BATCH 2
#define CDIM 1024
#define NH 16
#define HD 64
#define DFF 4096
#define ROWS (BATCH*TSEQ)   // 4096

typedef __attribute__((ext_vector_type(4))) float f32x4;
typedef __attribute__((ext_vector_type(8))) short bf16x8;   // 8 bf16 in 4 VGPRs
typedef __attribute__((ext_vector_type(4))) unsigned short u16x4;

__device__ __forceinline__ void gload_lds16(const void* g, void* l) {
    void* gv = const_cast<void*>(g);
    __builtin_amdgcn_global_load_lds((__attribute__((address_space(1))) void*)gv,
                                     (__attribute__((address_space(3))) void*)l, 16, 0, 0);
}

__device__ __forceinline__ unsigned short f2bf(float f) {
    unsigned int u = __float_as_uint(f);
    return (unsigned short)((u + 0x7FFFu + ((u >> 16) & 1u)) >> 16);
}
__device__ __forceinline__ float bf2f(unsigned short u) {
    return __uint_as_float((unsigned int)u << 16);
}
// tanh-form GELU: v * sigmoid(1.59577*(v + 0.044715 v^3)); |err vs exact| < ~3e-4
__device__ __forceinline__ float fast_gelu(float v) {
    float u = fmaf(0.044715f * v * v, v, v);
    float e = __expf(-1.5957691216057308f * u);
    return v * __builtin_amdgcn_rcpf(1.0f + e);
}

// ------------------------------- LayerNorm -> bf16 --------------------------------
__global__ __launch_bounds__(256) void ln_kernel(const float* __restrict__ x,
                                                 const float* __restrict__ g,
                                                 const float* __restrict__ b,
                                                 unsigned short* __restrict__ out) {
    int row = blockIdx.x;
    int tid = threadIdx.x;
    const float* xr = x + (size_t)row * CDIM;
    float4 v = *(const float4*)(xr + tid * 4);
    float s  = v.x + v.y + v.z + v.w;
    float s2 = v.x*v.x + v.y*v.y + v.z*v.z + v.w*v.w;
    #pragma unroll
    for (int off = 32; off >= 1; off >>= 1) {
        s  += __shfl_down(s, off);
        s2 += __shfl_down(s2, off);
    }
    __shared__ float red[8];
    int wid = tid >> 6, lane = tid & 63;
    if (lane == 0) { red[wid] = s; red[wid + 4] = s2; }
    __syncthreads();
    float ts  = red[0] + red[1] + red[2] + red[3];
    float ts2 = red[4] + red[5] + red[6] + red[7];
    float mu  = ts * (1.0f / CDIM);
    float var = ts2 * (1.0f / CDIM) - mu * mu;
    float rstd = rsqrtf(var + 1e-5f);
    float4 gv = *(const float4*)(g + tid * 4);
    float4 bv = *(const float4*)(b + tid * 4);
    unsigned short o4[4];
    o4[0] = f2bf((v.x - mu) * rstd * gv.x + bv.x);
    o4[1] = f2bf((v.y - mu) * rstd * gv.y + bv.y);
    o4[2] = f2bf((v.z - mu) * rstd * gv.z + bv.z);
    o4[3] = f2bf((v.w - mu) * rstd * gv.w + bv.w);
    *(u16x4*)(out + (size_t)row * CDIM + tid * 4) = *(u16x4*)o4;
}

// --------------------- transpose + cast: W[K][N] f32 -> Wt[N][K] bf16 ---------------
__global__ __launch_bounds__(256) void transpose_cast_kernel(const float* __restrict__ W,
                                                             unsigned short* __restrict__ Wt,
                                                             int K, int N) {
    __shared__ float T[64][65];
    int tid = threadIdx.x;
    int n0 = blockIdx.x * 64, k0 = blockIdx.y * 64;
    int kr = tid >> 4;
    int nc = (tid & 15) * 4;
    #pragma unroll
    for (int i = 0; i < 4; ++i) {
        float4 v = *(const float4*)&W[(size_t)(k0 + kr + i*16) * N + (n0 + nc)];
        T[kr + i*16][nc + 0] = v.x;
        T[kr + i*16][nc + 1] = v.y;
        T[kr + i*16][nc + 2] = v.z;
        T[kr + i*16][nc + 3] = v.w;
    }
    __syncthreads();
    int n  = tid >> 2;
    int kb = (tid & 3) * 16;
    unsigned short tmp[16];
    #pragma unroll
    for (int i = 0; i < 16; ++i) tmp[i] = f2bf(T[kb + i][n]);
    unsigned short* dst = Wt + (size_t)(n0 + n) * K + (k0 + kb);
    *(int4*)dst       = *(int4*)&tmp[0];
    *(int4*)(dst + 8) = *(int4*)&tmp[8];
}

// ---- K/V fragment-major pre-pass (see R8 notes) -----------------------------------
__global__ __launch_bounds__(256) void kvfrag_kernel(const unsigned short* __restrict__ qkv,
                                                     unsigned short* __restrict__ kfrag,
                                                     unsigned short* __restrict__ vfrag) {
    __shared__ unsigned short Kt[64][72];
    __shared__ unsigned short Vt[64][72];
    const int tid = threadIdx.x;
    const int j  = blockIdx.x;
    const int bh = blockIdx.y;
    const int b = bh >> 4, h = bh & 15;
    {
        const int r  = tid >> 2;
        const int c0 = (tid & 3) * 16;
        const unsigned short* src = qkv + ((size_t)(b * TSEQ + j * 64 + r)) * 3072 + 1024 + h * 64 + c0;
        bf16x8 k0 = *(const bf16x8*)src;
        bf16x8 k1 = *(const bf16x8*)(src + 8);
        bf16x8 v0 = *(const bf16x8*)(src + 1024);
        bf16x8 v1 = *(const bf16x8*)(src + 1032);
        *(bf16x8*)&Kt[r][c0]     = k0;
        *(bf16x8*)&Kt[r][c0 + 8] = k1;
        *(bf16x8*)&Vt[r][c0]     = v0;
        *(bf16x8*)&Vt[r][c0 + 8] = v1;
    }
    __syncthreads();
    const int l  = tid & 63;
    const int qd = tid >> 6;
    const size_t tbase = ((size_t)(bh * 32 + j)) * 8 * 512;
    #pragma unroll
    for (int pass = 0; pass < 2; ++pass) {
        const int kc = qd + pass * 4;
        const int sb = kc >> 1, g = kc & 1;
        bf16x8 kv = *(const bf16x8*)&Kt[sb * 16 + (l & 15)][g * 32 + (l >> 4) * 8];
        *(bf16x8*)(kfrag + tbase + kc * 512 + l * 8) = kv;

        const int vc = qd + pass * 4;
        const int kb = vc >> 2, db = vc & 3;
        unsigned short tmp[8];
        #pragma unroll
        for (int i = 0; i < 8; ++i)
            tmp[i] = Vt[kb * 32 + (l >> 4) * 8 + i][db * 16 + (l & 15)];
        *(bf16x8*)(vfrag + tbase + vc * 512 + l * 8) = *(bf16x8*)tmp;
    }
}

// ------------- MFMA GEMM (TN) 128x128 tile, BK=64, chunk-XOR LDS swizzle -----------
// LDS pos (row, pc) holds global chunk pc^(row&7); global source pre-swizzled (rule 21).
// For all fragment reads row&7 == l&7 (row-bases are multiples of 16).
// EPI: 0 = bias -> bf16; 1 = bias + f32 residual -> f32; 2 = bias + fast GELU -> bf16
template<int EPI>
__global__ __launch_bounds__(256) void gemm_kernel(const unsigned short* __restrict__ A,
                                                   const unsigned short* __restrict__ Bt,
                                                   const float* __restrict__ bias,
                                                   const float* __restrict__ res,
                                                   void* __restrict__ Cout,
                                                   int M, int N, int K) {
    __shared__ __align__(16) unsigned short As[128 * 64];   // 16 KB
    __shared__ __align__(16) unsigned short Bs[128 * 64];   // 16 KB
    const int tid = threadIdx.x;
    const int l   = tid & 63;
    const int w   = tid >> 6;
    const int wr  = (w >> 1) * 64;
    const int wc  = (w & 1) * 64;
    const long brow = (long)blockIdx.y * 128;
    const long bcol = (long)blockIdx.x * 128;

    // staging: thread covers rows (tid>>3)+32p, local chunk tid&7, global chunk XOR'd
    const int srow = tid >> 3;                                  // 0..31
    const int schk = ((tid & 7) ^ (srow & 7)) * 8;              // global elem offset
    const unsigned short* gA = A  + (size_t)(brow + srow) * K + schk;
    const unsigned short* gB = Bt + (size_t)(bcol + srow) * K + schk;
    unsigned short* lA = As + tid * 8;
    unsigned short* lB = Bs + tid * 8;

    f32x4 acc[4][4];
    #pragma unroll
    for (int m = 0; m < 4; ++m)
        #pragma unroll
        for (int n = 0; n < 4; ++n) acc[m][n] = (f32x4){0.f, 0.f, 0.f, 0.f};

    for (int k0 = 0; k0 < K; k0 += 64) {
        #pragma unroll
        for (int p = 0; p < 4; ++p) {
            gload_lds16(gA + (size_t)(32 * p) * K + k0, lA + p * 2048);
            gload_lds16(gB + (size_t)(32 * p) * K + k0, lB + p * 2048);
        }
        __syncthreads();
        #pragma unroll
        for (int gg = 0; gg < 2; ++gg) {
            const int koff = ((gg * 4 + (l >> 4)) ^ (l & 7)) * 8;
            bf16x8 af[4], bf[4];
            #pragma unroll
            for (int m = 0; m < 4; ++m)
                af[m] = *(const bf16x8*)&As[(wr + m * 16 + (l & 15)) * 64 + koff];
            #pragma unroll
            for (int n = 0; n < 4; ++n)
                bf[n] = *(const bf16x8*)&Bs[(wc + n * 16 + (l & 15)) * 64 + koff];
            #pragma unroll
            for (int m = 0; m < 4; ++m)
                #pragma unroll
                for (int n = 0; n < 4; ++n)
                    acc[m][n] = __builtin_amdgcn_mfma_f32_16x16x32_bf16(af[m], bf[n], acc[m][n], 0, 0, 0);
        }
        __syncthreads();
    }

    #pragma unroll
    for (int m = 0; m < 4; ++m) {
        const int rown = wr + m * 16 + (l >> 4) * 4;
        #pragma unroll
        for (int n = 0; n < 4; ++n) {
            const long col = bcol + wc + n * 16 + (l & 15);
            const float bb = bias[col];
            #pragma unroll
            for (int r = 0; r < 4; ++r) {
                const long row = brow + rown + r;
                float v = acc[m][n][r] + bb;
                if (EPI == 1) {
                    v += res[row * N + col];
                    ((float*)Cout)[row * N + col] = v;
                } else if (EPI == 2) {
                    ((unsigned short*)Cout)[row * N + col] = f2bf(fast_gelu(v));
                } else {
                    ((unsigned short*)Cout)[row * N + col] = f2bf(v);
                }
            }
        }
    }
}

// ------------- MFMA GEMM (TN) 64x128 tile, BK=64, chunk-XOR LDS swizzle ------------
// For N=1024 GEMMs: grid (8,64) = 512 blocks = 2 blocks/CU; 16 MFMA per barrier pair.
template<int EPI>
__global__ __launch_bounds__(256) void gemm64_kernel(const unsigned short* __restrict__ A,
                                                     const unsigned short* __restrict__ Bt,
                                                     const float* __restrict__ bias,
                                                     const float* __restrict__ res,
                                                     void* __restrict__ Cout,
                                                     int M, int N, int K) {
    __shared__ __align__(16) unsigned short As[64 * 64];    // 8 KB
    __shared__ __align__(16) unsigned short Bs[128 * 64];   // 16 KB
    const int tid = threadIdx.x;
    const int l   = tid & 63;
    const int w   = tid >> 6;
    const int wr  = (w >> 1) * 32;
    const int wc  = (w & 1) * 64;
    const long brow = (long)blockIdx.y * 64;
    const long bcol = (long)blockIdx.x * 128;

    const int srow = tid >> 3;                                  // 0..31
    const int schk = ((tid & 7) ^ (srow & 7)) * 8;
    const unsigned short* gA = A  + (size_t)(brow + srow) * K + schk;
    const unsigned short* gB = Bt + (size_t)(bcol + srow) * K + schk;
    unsigned short* lA = As + tid * 8;
    unsigned short* lB = Bs + tid * 8;

    f32x4 acc[2][4];
    #pragma unroll
    for (int m = 0; m < 2; ++m)
        #pragma unroll
        for (int n = 0; n < 4; ++n) acc[m][n] = (f32x4){0.f, 0.f, 0.f, 0.f};

    for (int k0 = 0; k0 < K; k0 += 64) {
        #pragma unroll
        for (int p = 0; p < 2; ++p)
            gload_lds16(gA + (size_t)(32 * p) * K + k0, lA + p * 2048);
        #pragma unroll
        for (int p = 0; p < 4; ++p)
            gload_lds16(gB + (size_t)(32 * p) * K + k0, lB + p * 2048);
        __syncthreads();
        #pragma unroll
        for (int gg = 0; gg < 2; ++gg) {
            const int koff = ((gg * 4 + (l >> 4)) ^ (l & 7)) * 8;
            bf16x8 af[2], bf[4];
            #pragma unroll
            for (int m = 0; m < 2; ++m)
                af[m] = *(const bf16x8*)&As[(wr + m * 16 + (l & 15)) * 64 + koff];
            #pragma unroll
            for (int n = 0; n < 4; ++n)
                bf[n] = *(const bf16x8*)&Bs[(wc + n * 16 + (l & 15)) * 64 + koff];
            #pragma unroll
            for (int m = 0; m < 2; ++m)
                #pragma unroll
                for (int n = 0; n < 4; ++n)
                    acc[m][n] = __builtin_amdgcn_mfma_f32_16x16x32_bf16(af[m], bf[n], acc[m][n], 0, 0, 0);
        }
        __syncthreads();
    }

    #pragma unroll
    for (int m = 0; m < 2; ++m) {
        const int rown = wr + m * 16 + (l >> 4) * 4;
        #pragma unroll
        for (int n = 0; n < 4; ++n) {
            const long col = bcol + wc + n * 16 + (l & 15);
            const float bb = bias[col];
            #pragma unroll
            for (int r = 0; r < 4; ++r) {
                const long row = brow + rown + r;
                float v = acc[m][n][r] + bb;
                if (EPI == 1) {
                    v += res[row * N + col];
                    ((float*)Cout)[row * N + col] = v;
                } else if (EPI == 2) {
                    ((unsigned short*)Cout)[row * N + col] = f2bf(fast_gelu(v));
                } else {
                    ((unsigned short*)Cout)[row * N + col] = f2bf(v);
                }
            }
        }
    }
}

// ------------------- MFMA causal flash attention (single-wave blocks) ---------------
#define QSCALE 0.18033688011112042f   // 0.125 * log2(e)
__global__ __launch_bounds__(64) void attn_kernel(const unsigned short* __restrict__ qkv,
                                                  const unsigned short* __restrict__ kfrag,
                                                  const unsigned short* __restrict__ vfrag,
                                                  unsigned short* __restrict__ out) {
    __shared__ __align__(16) unsigned short Ps[16 * 128];   // [row][col], chunk-XOR swizzled

    const int l    = threadIdx.x;
    const int lin  = blockIdx.x;
    const int xcd  = lin & 7;
    const int rest = lin >> 3;
    const int h    = xcd + 8 * (rest & 1);
    const int b    = (rest >> 1) & 1;
    const int strip = 127 - (rest >> 2);
    const int jmax  = strip >> 2;
    const size_t rowbase = (size_t)b * TSEQ;
    const int bh = b * NH + h;

    const unsigned short* kfb = kfrag + (size_t)bh * 32 * 8 * 512;
    const unsigned short* vfb = vfrag + (size_t)bh * 32 * 8 * 512;

    bf16x8 aq0, aq1;
    {
        const int qrow = strip * 16 + (l & 15);
        const unsigned short* qp = qkv + (rowbase + qrow) * 3072 + h * 64 + (l >> 4) * 8;
        bf16x8 t0 = *(const bf16x8*)qp;
        bf16x8 t1 = *(const bf16x8*)(qp + 32);
        #pragma unroll
        for (int i = 0; i < 8; ++i) {
            aq0[i] = (short)f2bf(bf2f((unsigned short)t0[i]) * QSCALE);
            aq1[i] = (short)f2bf(bf2f((unsigned short)t1[i]) * QSCALE);
        }
    }

    float mrow[4], lrow[4];
    #pragma unroll
    for (int r = 0; r < 4; ++r) { mrow[r] = -INFINITY; lrow[r] = 0.f; }
    f32x4 o[4];
    #pragma unroll
    for (int d = 0; d < 4; ++d) o[d] = (f32x4){0.f, 0.f, 0.f, 0.f};

    const int qg = strip * 16 + (l >> 4) * 4;

    for (int j = 0; j + 1 <= jmax; j += 2) {
        const bool diag2 = (j + 1 == jmax);

        bf16x8 kf[16];
        #pragma unroll
        for (int t = 0; t < 2; ++t)
            #pragma unroll
            for (int sb = 0; sb < 4; ++sb) {
                const unsigned short* kp = kfb + (size_t)((j + t) * 8 + sb * 2) * 512 + l * 8;
                kf[t * 8 + sb * 2]     = *(const bf16x8*)kp;
                kf[t * 8 + sb * 2 + 1] = *(const bf16x8*)(kp + 512);
            }

        f32x4 sf[8];
        __builtin_amdgcn_s_setprio(1);
        #pragma unroll
        for (int t = 0; t < 2; ++t)
            #pragma unroll
            for (int sb = 0; sb < 4; ++sb) {
                f32x4 acc = (f32x4){0.f, 0.f, 0.f, 0.f};
                acc = __builtin_amdgcn_mfma_f32_16x16x32_bf16(aq0, kf[t*8 + sb*2],     acc, 0, 0, 0);
                acc = __builtin_amdgcn_mfma_f32_16x16x32_bf16(aq1, kf[t*8 + sb*2 + 1], acc, 0, 0, 0);
                sf[t*4 + sb] = acc;
            }
        __builtin_amdgcn_s_setprio(0);

        bf16x8 vf[16];
        #pragma unroll
        for (int kb = 0; kb < 4; ++kb)
            #pragma unroll
            for (int db = 0; db < 4; ++db)
                vf[kb * 4 + db] = *(const bf16x8*)(vfb + (size_t)((j + (kb >> 1)) * 8 + (kb & 1) * 4 + db) * 512 + l * 8);

        if (diag2) {
            #pragma unroll
            for (int sb = 0; sb < 4; ++sb) {
                const int cg = (j + 1) * 64 + sb * 16 + (l & 15);
                #pragma unroll
                for (int r = 0; r < 4; ++r)
                    if (cg > qg + r) sf[4 + sb][r] = -INFINITY;
            }
        }

        float mnew[4], alpha[4], psum[4];
        #pragma unroll
        for (int r = 0; r < 4; ++r) {
            float mx = fmaxf(fmaxf(fmaxf(sf[0][r], sf[1][r]), fmaxf(sf[2][r], sf[3][r])),
                             fmaxf(fmaxf(sf[4][r], sf[5][r]), fmaxf(sf[6][r], sf[7][r])));
            mx = fmaxf(mx, __shfl_xor(mx, 1));
            mx = fmaxf(mx, __shfl_xor(mx, 2));
            mx = fmaxf(mx, __shfl_xor(mx, 4));
            mx = fmaxf(mx, __shfl_xor(mx, 8));
            float mn = fmaxf(mrow[r], mx);
            mnew[r]  = mn;
            alpha[r] = exp2f(mrow[r] - mn);
            mrow[r]  = mn;
            psum[r]  = 0.f;
        }
        #pragma unroll
        for (int t = 0; t < 2; ++t)
            #pragma unroll
            for (int sb = 0; sb < 4; ++sb) {
                const int col = t * 64 + sb * 16 + (l & 15);
                #pragma unroll
                for (int r = 0; r < 4; ++r) {
                    float p = exp2f(sf[t*4 + sb][r] - mnew[r]);
                    psum[r] += p;
                    const int row = (l >> 4) * 4 + r;
                    Ps[row * 128 + (((col >> 3) ^ (row & 7)) << 3) + (col & 7)] = f2bf(p);
                }
            }
        #pragma unroll
        for (int r = 0; r < 4; ++r) {
            float ps = psum[r];
            ps += __shfl_xor(ps, 1);
            ps += __shfl_xor(ps, 2);
            ps += __shfl_xor(ps, 4);
            ps += __shfl_xor(ps, 8);
            lrow[r] = lrow[r] * alpha[r] + ps;
            #pragma unroll
            for (int d = 0; d < 4; ++d) o[d][r] *= alpha[r];
        }

        __builtin_amdgcn_s_setprio(1);
        #pragma unroll
        for (int kb = 0; kb < 4; ++kb) {
            const int row = l & 15;
            bf16x8 pa = *(const bf16x8*)&Ps[row * 128 + (((kb * 4 + (l >> 4)) ^ (row & 7)) << 3)];
            #pragma unroll
            for (int db = 0; db < 4; ++db)
                o[db] = __builtin_amdgcn_mfma_f32_16x16x32_bf16(pa, vf[kb * 4 + db], o[db], 0, 0, 0);
        }
        __builtin_amdgcn_s_setprio(0);
    }

    if ((jmax & 1) == 0) {
        const int j = jmax;
        bf16x8 kf[8];
        #pragma unroll
        for (int sb = 0; sb < 4; ++sb) {
            const unsigned short* kp = kfb + (size_t)(j * 8 + sb * 2) * 512 + l * 8;
            kf[sb * 2]     = *(const bf16x8*)kp;
            kf[sb * 2 + 1] = *(const bf16x8*)(kp + 512);
        }
        f32x4 sf[4];
        __builtin_amdgcn_s_setprio(1);
        #pragma unroll
        for (int sb = 0; sb < 4; ++sb) {
            f32x4 acc = (f32x4){0.f, 0.f, 0.f, 0.f};
            acc = __builtin_amdgcn_mfma_f32_16x16x32_bf16(aq0, kf[sb*2],     acc, 0, 0, 0);
            acc = __builtin_amdgcn_mfma_f32_16x16x32_bf16(aq1, kf[sb*2 + 1], acc, 0, 0, 0);
            sf[sb] = acc;
        }
        __builtin_amdgcn_s_setprio(0);

        bf16x8 vf[8];
        #pragma unroll
        for (int kb = 0; kb < 2; ++kb)
            #pragma unroll
            for (int db = 0; db < 4; ++db)
                vf[kb * 4 + db] = *(const bf16x8*)(vfb + (size_t)(j * 8 + kb * 4 + db) * 512 + l * 8);
        #pragma unroll
        for (int sb = 0; sb < 4; ++sb) {
            const int cg = j * 64 + sb * 16 + (l & 15);
            #pragma unroll
            for (int r = 0; r < 4; ++r)
                if (cg > qg + r) sf[sb][r] = -INFINITY;
        }

        float mnew[4], alpha[4], psum[4];
        #pragma unroll
        for (int r = 0; r < 4; ++r) {
            float mx = fmaxf(fmaxf(sf[0][r], sf[1][r]), fmaxf(sf[2][r], sf[3][r]));
            mx = fmaxf(mx, __shfl_xor(mx, 1));
            mx = fmaxf(mx, __shfl_xor(mx, 2));
            mx = fmaxf(mx, __shfl_xor(mx, 4));
            mx = fmaxf(mx, __shfl_xor(mx, 8));
            float mn = fmaxf(mrow[r], mx);
            mnew[r]  = mn;
            alpha[r] = exp2f(mrow[r] - mn);
            mrow[r]  = mn;
            psum[r]  = 0.f;
        }
        #pragma unroll
        for (int sb = 0; sb < 4; ++sb) {
            const int col = sb * 16 + (l & 15);
            #pragma unroll
            for (int r = 0; r < 4; ++r) {
                float p = exp2f(sf[sb][r] - mnew[r]);
                psum[r] += p;
                const int row = (l >> 4) * 4 + r;
                Ps[row * 128 + (((col >> 3) ^ (row & 7)) << 3) + (col & 7)] = f2bf(p);
            }
        }
        #pragma unroll
        for (int r = 0; r < 4; ++r) {
            float ps = psum[r];
            ps += __shfl_xor(ps, 1);
            ps += __shfl_xor(ps, 2);
            ps += __shfl_xor(ps, 4);
            ps += __shfl_xor(ps, 8);
            lrow[r] = lrow[r] * alpha[r] + ps;
            #pragma unroll
            for (int d = 0; d < 4; ++d) o[d][r] *= alpha[r];
        }
        __builtin_amdgcn_s_setprio(1);
        #pragma unroll
        for (int kb = 0; kb < 2; ++kb) {
            const int row = l & 15;
            bf16x8 pa = *(const bf16x8*)&Ps[row * 128 + (((kb * 4 + (l >> 4)) ^ (row & 7)) << 3)];
            #pragma unroll
            for (int db = 0; db < 4; ++db)
                o[db] = __builtin_amdgcn_mfma_f32_16x16x32_bf16(pa, vf[kb * 4 + db], o[db], 0, 0, 0);
        }
        __builtin_amdgcn_s_setprio(0);
    }

    #pragma unroll
    for (int r = 0; r < 4; ++r) {
        const float inv = 1.0f / lrow[r];
        const size_t rb = (rowbase + strip * 16 + (l >> 4) * 4 + r) * (size_t)CDIM + h * 64 + (l & 15);
        #pragma unroll
        for (int d = 0; d < 4; ++d)
            out[rb + d * 16] = f2bf(o[d][r] * inv);
    }
}

extern "C" void kernel_launch(void* const* d_in, const int* in_sizes, int n_in,
                              void* d_out, int out_size, void* d_ws, size_t ws_size,
                              hipStream_t stream) {
    const float* x     = (const float*)d_in[0];
    const float* ln1_g = (const float*)d_in[1];
    const float* ln1_b = (const float*)d_in[2];
    const float* w_qkv = (const float*)d_in[3];
    const float* b_qkv = (const float*)d_in[4];
    const float* w_out = (const float*)d_in[5];
    const float* b_out = (const float*)d_in[6];
    const float* ln2_g = (const float*)d_in[7];
    const float* ln2_b = (const float*)d_in[8];
    const float* w_ff1 = (const float*)d_in[9];
    const float* b_ff1 = (const float*)d_in[10];
    const float* w_ff2 = (const float*)d_in[11];
    const float* b_ff2 = (const float*)d_in[12];
    float* out = (float*)d_out;

    char* wsb = (char*)d_ws;
    unsigned short* h_bf    = (unsigned short*)(wsb);                          // 8 MB
    unsigned short* qkv_bf  = (unsigned short*)(wsb + 8ll  * 1024 * 1024);     // 24 MB
    unsigned short* attn_bf = (unsigned short*)(wsb + 32ll * 1024 * 1024);     // 8 MB
    float*          x1      = (float*)         (wsb + 40ll * 1024 * 1024);     // 16 MB
    unsigned short* kfrag   = (unsigned short*)(wsb + 40ll * 1024 * 1024);     // 8 MB (overlays x1, dead until step 4)
    unsigned short* vfrag   = (unsigned short*)(wsb + 48ll * 1024 * 1024);     // 8 MB (overlays x1, dead until step 4)
    unsigned short* wqkvT   = (unsigned short*)(wsb + 56ll * 1024 * 1024);     // 6 MB
    unsigned short* woutT   = (unsigned short*)(wsb + 62ll * 1024 * 1024);     // 2 MB
    unsigned short* wff1T   = (unsigned short*)(wsb + 64ll * 1024 * 1024);     // 8 MB
    unsigned short* wff2T   = (unsigned short*)(wsb + 72ll * 1024 * 1024);     // 8 MB
    unsigned short* ff1_bf  = (unsigned short*)(wsb + 8ll  * 1024 * 1024);     // 32 MB, overlays dead qkv+attn

    transpose_cast_kernel<<<dim3(48, 16), 256, 0, stream>>>(w_qkv, wqkvT, 1024, 3072);
    transpose_cast_kernel<<<dim3(16, 16), 256, 0, stream>>>(w_out, woutT, 1024, 1024);
    transpose_cast_kernel<<<dim3(64, 16), 256, 0, stream>>>(w_ff1, wff1T, 1024, 4096);
    transpose_cast_kernel<<<dim3(16, 64), 256, 0, stream>>>(w_ff2, wff2T, 4096, 1024);

    // 1. LN1 -> bf16
    ln_kernel<<<ROWS, 256, 0, stream>>>(x, ln1_g, ln1_b, h_bf);
    // 2. qkv = h @ w_qkv + b  -> bf16
    gemm_kernel<0><<<dim3(24, 32), 256, 0, stream>>>(h_bf, wqkvT, b_qkv, nullptr, qkv_bf, ROWS, 3072, 1024);
    // 2b. K/V fragment-major pre-pass
    kvfrag_kernel<<<dim3(32, 32), 256, 0, stream>>>(qkv_bf, kfrag, vfrag);
    // 3. causal flash attention -> bf16
    attn_kernel<<<4096, 64, 0, stream>>>(qkv_bf, kfrag, vfrag, attn_bf);
    // 4. x1 = x + attn @ w_out + b  -> f32
    gemm64_kernel<1><<<dim3(8, 64), 256, 0, stream>>>(attn_bf, woutT, b_out, x, x1, ROWS, 1024, 1024);
    // 5. LN2 -> bf16
    ln_kernel<<<ROWS, 256, 0, stream>>>(x1, ln2_g, ln2_b, h_bf);
    // 6. ff1 = gelu(h @ w_ff1 + b)  -> bf16
    gemm_kernel<2><<<dim3(32, 32), 256, 0, stream>>>(h_bf, wff1T, b_ff1, nullptr, ff1_bf, ROWS, 4096, 1024);
    // 7. out = x1 + ff1 @ w_ff2 + b  -> f32
    gemm64_kernel<1><<<dim3(8, 64), 256, 0, stream>>>(ff1_bf, wff2T, b_ff2, x1, (float*)out, ROWS, 1024, 4096);
}

// Round 11
// 278.956 us; speedup vs baseline: 1.3854x; 1.0055x over previous
//
#include <hip/hip_runtime.h>
#include <hip/hip_bf16.h>
#include <math.h>

#define TSEQ 2048
#define BATCH 2
#define CDIM 1024
#define NH 16
#define HD 64
#define DFF 4096
#define ROWS (BATCH*TSEQ)   // 4096

typedef __attribute__((ext_vector_type(4))) float f32x4;
typedef __attribute__((ext_vector_type(8))) short bf16x8;   // 8 bf16 in 4 VGPRs
typedef __attribute__((ext_vector_type(4))) unsigned short u16x4;

__device__ __forceinline__ void gload_lds16(const void* g, void* l) {
    void* gv = const_cast<void*>(g);
    __builtin_amdgcn_global_load_lds((__attribute__((address_space(1))) void*)gv,
                                     (__attribute__((address_space(3))) void*)l, 16, 0, 0);
}

__device__ __forceinline__ unsigned short f2bf(float f) {
    unsigned int u = __float_as_uint(f);
    return (unsigned short)((u + 0x7FFFu + ((u >> 16) & 1u)) >> 16);
}
__device__ __forceinline__ float bf2f(unsigned short u) {
    return __uint_as_float((unsigned int)u << 16);
}
// tanh-form GELU: v * sigmoid(1.59577*(v + 0.044715 v^3)); |err vs exact| < ~3e-4
__device__ __forceinline__ float fast_gelu(float v) {
    float u = fmaf(0.044715f * v * v, v, v);
    float e = __expf(-1.5957691216057308f * u);
    return v * __builtin_amdgcn_rcpf(1.0f + e);
}

// ------------------------------- LayerNorm -> bf16 --------------------------------
__global__ __launch_bounds__(256) void ln_kernel(const float* __restrict__ x,
                                                 const float* __restrict__ g,
                                                 const float* __restrict__ b,
                                                 unsigned short* __restrict__ out) {
    int row = blockIdx.x;
    int tid = threadIdx.x;
    const float* xr = x + (size_t)row * CDIM;
    float4 v = *(const float4*)(xr + tid * 4);
    float s  = v.x + v.y + v.z + v.w;
    float s2 = v.x*v.x + v.y*v.y + v.z*v.z + v.w*v.w;
    #pragma unroll
    for (int off = 32; off >= 1; off >>= 1) {
        s  += __shfl_down(s, off);
        s2 += __shfl_down(s2, off);
    }
    __shared__ float red[8];
    int wid = tid >> 6, lane = tid & 63;
    if (lane == 0) { red[wid] = s; red[wid + 4] = s2; }
    __syncthreads();
    float ts  = red[0] + red[1] + red[2] + red[3];
    float ts2 = red[4] + red[5] + red[6] + red[7];
    float mu  = ts * (1.0f / CDIM);
    float var = ts2 * (1.0f / CDIM) - mu * mu;
    float rstd = rsqrtf(var + 1e-5f);
    float4 gv = *(const float4*)(g + tid * 4);
    float4 bv = *(const float4*)(b + tid * 4);
    unsigned short o4[4];
    o4[0] = f2bf((v.x - mu) * rstd * gv.x + bv.x);
    o4[1] = f2bf((v.y - mu) * rstd * gv.y + bv.y);
    o4[2] = f2bf((v.z - mu) * rstd * gv.z + bv.z);
    o4[3] = f2bf((v.w - mu) * rstd * gv.w + bv.w);
    *(u16x4*)(out + (size_t)row * CDIM + tid * 4) = *(u16x4*)o4;
}

// --------------------- transpose + cast: W[K][N] f32 -> Wt[N][K] bf16 ---------------
__global__ __launch_bounds__(256) void transpose_cast_kernel(const float* __restrict__ W,
                                                             unsigned short* __restrict__ Wt,
                                                             int K, int N) {
    __shared__ float T[64][65];
    int tid = threadIdx.x;
    int n0 = blockIdx.x * 64, k0 = blockIdx.y * 64;
    int kr = tid >> 4;
    int nc = (tid & 15) * 4;
    #pragma unroll
    for (int i = 0; i < 4; ++i) {
        float4 v = *(const float4*)&W[(size_t)(k0 + kr + i*16) * N + (n0 + nc)];
        T[kr + i*16][nc + 0] = v.x;
        T[kr + i*16][nc + 1] = v.y;
        T[kr + i*16][nc + 2] = v.z;
        T[kr + i*16][nc + 3] = v.w;
    }
    __syncthreads();
    int n  = tid >> 2;
    int kb = (tid & 3) * 16;
    unsigned short tmp[16];
    #pragma unroll
    for (int i = 0; i < 16; ++i) tmp[i] = f2bf(T[kb + i][n]);
    unsigned short* dst = Wt + (size_t)(n0 + n) * K + (k0 + kb);
    *(int4*)dst       = *(int4*)&tmp[0];
    *(int4*)(dst + 8) = *(int4*)&tmp[8];
}

// ---- K/V fragment-major pre-pass (see R8 notes) -----------------------------------
__global__ __launch_bounds__(256) void kvfrag_kernel(const unsigned short* __restrict__ qkv,
                                                     unsigned short* __restrict__ kfrag,
                                                     unsigned short* __restrict__ vfrag) {
    __shared__ unsigned short Kt[64][72];
    __shared__ unsigned short Vt[64][72];
    const int tid = threadIdx.x;
    const int j  = blockIdx.x;
    const int bh = blockIdx.y;
    const int b = bh >> 4, h = bh & 15;
    {
        const int r  = tid >> 2;
        const int c0 = (tid & 3) * 16;
        const unsigned short* src = qkv + ((size_t)(b * TSEQ + j * 64 + r)) * 3072 + 1024 + h * 64 + c0;
        bf16x8 k0 = *(const bf16x8*)src;
        bf16x8 k1 = *(const bf16x8*)(src + 8);
        bf16x8 v0 = *(const bf16x8*)(src + 1024);
        bf16x8 v1 = *(const bf16x8*)(src + 1032);
        *(bf16x8*)&Kt[r][c0]     = k0;
        *(bf16x8*)&Kt[r][c0 + 8] = k1;
        *(bf16x8*)&Vt[r][c0]     = v0;
        *(bf16x8*)&Vt[r][c0 + 8] = v1;
    }
    __syncthreads();
    const int l  = tid & 63;
    const int qd = tid >> 6;
    const size_t tbase = ((size_t)(bh * 32 + j)) * 8 * 512;
    #pragma unroll
    for (int pass = 0; pass < 2; ++pass) {
        const int kc = qd + pass * 4;
        const int sb = kc >> 1, g = kc & 1;
        bf16x8 kv = *(const bf16x8*)&Kt[sb * 16 + (l & 15)][g * 32 + (l >> 4) * 8];
        *(bf16x8*)(kfrag + tbase + kc * 512 + l * 8) = kv;

        const int vc = qd + pass * 4;
        const int kb = vc >> 2, db = vc & 3;
        unsigned short tmp[8];
        #pragma unroll
        for (int i = 0; i < 8; ++i)
            tmp[i] = Vt[kb * 32 + (l >> 4) * 8 + i][db * 16 + (l & 15)];
        *(bf16x8*)(vfrag + tbase + vc * 512 + l * 8) = *(bf16x8*)tmp;
    }
}

// ------------- MFMA GEMM (TN) 128x128 tile, BK=64, XOR swizzle, XCD-banded ---------
// 1-D grid; xcd = lin&7 owns row-panels [xcd*rpx, (xcd+1)*rpx) so each A-panel is
// fetched into exactly one XCD's L2 (bijective: idx in [0,rpx*nbx)).
template<int EPI>
__global__ __launch_bounds__(256) void gemm_kernel(const unsigned short* __restrict__ A,
                                                   const unsigned short* __restrict__ Bt,
                                                   const float* __restrict__ bias,
                                                   const float* __restrict__ res,
                                                   void* __restrict__ Cout,
                                                   int M, int N, int K, int nbx, int rpx) {
    __shared__ __align__(16) unsigned short As[128 * 64];   // 16 KB
    __shared__ __align__(16) unsigned short Bs[128 * 64];   // 16 KB
    const int tid = threadIdx.x;
    const int l   = tid & 63;
    const int w   = tid >> 6;
    const int wr  = (w >> 1) * 64;
    const int wc  = (w & 1) * 64;
    const int lin = blockIdx.x;
    const int xcd = lin & 7;
    const int idx = lin >> 3;
    const long brow = (long)(xcd * rpx + idx / nbx) * 128;
    const long bcol = (long)(idx % nbx) * 128;

    const int srow = tid >> 3;                                  // 0..31
    const int schk = ((tid & 7) ^ (srow & 7)) * 8;              // global elem offset
    const unsigned short* gA = A  + (size_t)(brow + srow) * K + schk;
    const unsigned short* gB = Bt + (size_t)(bcol + srow) * K + schk;
    unsigned short* lA = As + tid * 8;
    unsigned short* lB = Bs + tid * 8;

    f32x4 acc[4][4];
    #pragma unroll
    for (int m = 0; m < 4; ++m)
        #pragma unroll
        for (int n = 0; n < 4; ++n) acc[m][n] = (f32x4){0.f, 0.f, 0.f, 0.f};

    for (int k0 = 0; k0 < K; k0 += 64) {
        #pragma unroll
        for (int p = 0; p < 4; ++p) {
            gload_lds16(gA + (size_t)(32 * p) * K + k0, lA + p * 2048);
            gload_lds16(gB + (size_t)(32 * p) * K + k0, lB + p * 2048);
        }
        __syncthreads();
        #pragma unroll
        for (int gg = 0; gg < 2; ++gg) {
            const int koff = ((gg * 4 + (l >> 4)) ^ (l & 7)) * 8;
            bf16x8 af[4], bf[4];
            #pragma unroll
            for (int m = 0; m < 4; ++m)
                af[m] = *(const bf16x8*)&As[(wr + m * 16 + (l & 15)) * 64 + koff];
            #pragma unroll
            for (int n = 0; n < 4; ++n)
                bf[n] = *(const bf16x8*)&Bs[(wc + n * 16 + (l & 15)) * 64 + koff];
            #pragma unroll
            for (int m = 0; m < 4; ++m)
                #pragma unroll
                for (int n = 0; n < 4; ++n)
                    acc[m][n] = __builtin_amdgcn_mfma_f32_16x16x32_bf16(af[m], bf[n], acc[m][n], 0, 0, 0);
        }
        __syncthreads();
    }

    #pragma unroll
    for (int m = 0; m < 4; ++m) {
        const int rown = wr + m * 16 + (l >> 4) * 4;
        #pragma unroll
        for (int n = 0; n < 4; ++n) {
            const long col = bcol + wc + n * 16 + (l & 15);
            const float bb = bias[col];
            #pragma unroll
            for (int r = 0; r < 4; ++r) {
                const long row = brow + rown + r;
                float v = acc[m][n][r] + bb;
                if (EPI == 1) {
                    v += res[row * N + col];
                    ((float*)Cout)[row * N + col] = v;
                } else if (EPI == 2) {
                    ((unsigned short*)Cout)[row * N + col] = f2bf(fast_gelu(v));
                } else {
                    ((unsigned short*)Cout)[row * N + col] = f2bf(v);
                }
            }
        }
    }
}

// ------------- MFMA GEMM (TN) 64x128 tile, BK=64, XOR swizzle, XCD-banded ----------
template<int EPI>
__global__ __launch_bounds__(256) void gemm64_kernel(const unsigned short* __restrict__ A,
                                                     const unsigned short* __restrict__ Bt,
                                                     const float* __restrict__ bias,
                                                     const float* __restrict__ res,
                                                     void* __restrict__ Cout,
                                                     int M, int N, int K, int nbx, int rpx) {
    __shared__ __align__(16) unsigned short As[64 * 64];    // 8 KB
    __shared__ __align__(16) unsigned short Bs[128 * 64];   // 16 KB
    const int tid = threadIdx.x;
    const int l   = tid & 63;
    const int w   = tid >> 6;
    const int wr  = (w >> 1) * 32;
    const int wc  = (w & 1) * 64;
    const int lin = blockIdx.x;
    const int xcd = lin & 7;
    const int idx = lin >> 3;
    const long brow = (long)(xcd * rpx + idx / nbx) * 64;
    const long bcol = (long)(idx % nbx) * 128;

    const int srow = tid >> 3;                                  // 0..31
    const int schk = ((tid & 7) ^ (srow & 7)) * 8;
    const unsigned short* gA = A  + (size_t)(brow + srow) * K + schk;
    const unsigned short* gB = Bt + (size_t)(bcol + srow) * K + schk;
    unsigned short* lA = As + tid * 8;
    unsigned short* lB = Bs + tid * 8;

    f32x4 acc[2][4];
    #pragma unroll
    for (int m = 0; m < 2; ++m)
        #pragma unroll
        for (int n = 0; n < 4; ++n) acc[m][n] = (f32x4){0.f, 0.f, 0.f, 0.f};

    for (int k0 = 0; k0 < K; k0 += 64) {
        #pragma unroll
        for (int p = 0; p < 2; ++p)
            gload_lds16(gA + (size_t)(32 * p) * K + k0, lA + p * 2048);
        #pragma unroll
        for (int p = 0; p < 4; ++p)
            gload_lds16(gB + (size_t)(32 * p) * K + k0, lB + p * 2048);
        __syncthreads();
        #pragma unroll
        for (int gg = 0; gg < 2; ++gg) {
            const int koff = ((gg * 4 + (l >> 4)) ^ (l & 7)) * 8;
            bf16x8 af[2], bf[4];
            #pragma unroll
            for (int m = 0; m < 2; ++m)
                af[m] = *(const bf16x8*)&As[(wr + m * 16 + (l & 15)) * 64 + koff];
            #pragma unroll
            for (int n = 0; n < 4; ++n)
                bf[n] = *(const bf16x8*)&Bs[(wc + n * 16 + (l & 15)) * 64 + koff];
            #pragma unroll
            for (int m = 0; m < 2; ++m)
                #pragma unroll
                for (int n = 0; n < 4; ++n)
                    acc[m][n] = __builtin_amdgcn_mfma_f32_16x16x32_bf16(af[m], bf[n], acc[m][n], 0, 0, 0);
        }
        __syncthreads();
    }

    #pragma unroll
    for (int m = 0; m < 2; ++m) {
        const int rown = wr + m * 16 + (l >> 4) * 4;
        #pragma unroll
        for (int n = 0; n < 4; ++n) {
            const long col = bcol + wc + n * 16 + (l & 15);
            const float bb = bias[col];
            #pragma unroll
            for (int r = 0; r < 4; ++r) {
                const long row = brow + rown + r;
                float v = acc[m][n][r] + bb;
                if (EPI == 1) {
                    v += res[row * N + col];
                    ((float*)Cout)[row * N + col] = v;
                } else if (EPI == 2) {
                    ((unsigned short*)Cout)[row * N + col] = f2bf(fast_gelu(v));
                } else {
                    ((unsigned short*)Cout)[row * N + col] = f2bf(v);
                }
            }
        }
    }
}

// ------------------- MFMA causal flash attention (single-wave blocks) ---------------
#define QSCALE 0.18033688011112042f   // 0.125 * log2(e)
__global__ __launch_bounds__(64) void attn_kernel(const unsigned short* __restrict__ qkv,
                                                  const unsigned short* __restrict__ kfrag,
                                                  const unsigned short* __restrict__ vfrag,
                                                  unsigned short* __restrict__ out) {
    __shared__ __align__(16) unsigned short Ps[16 * 128];   // [row][col], chunk-XOR swizzled

    const int l    = threadIdx.x;
    const int lin  = blockIdx.x;
    const int xcd  = lin & 7;
    const int rest = lin >> 3;
    const int h    = xcd + 8 * (rest & 1);
    const int b    = (rest >> 1) & 1;
    const int strip = 127 - (rest >> 2);
    const int jmax  = strip >> 2;
    const size_t rowbase = (size_t)b * TSEQ;
    const int bh = b * NH + h;

    const unsigned short* kfb = kfrag + (size_t)bh * 32 * 8 * 512;
    const unsigned short* vfb = vfrag + (size_t)bh * 32 * 8 * 512;

    bf16x8 aq0, aq1;
    {
        const int qrow = strip * 16 + (l & 15);
        const unsigned short* qp = qkv + (rowbase + qrow) * 3072 + h * 64 + (l >> 4) * 8;
        bf16x8 t0 = *(const bf16x8*)qp;
        bf16x8 t1 = *(const bf16x8*)(qp + 32);
        #pragma unroll
        for (int i = 0; i < 8; ++i) {
            aq0[i] = (short)f2bf(bf2f((unsigned short)t0[i]) * QSCALE);
            aq1[i] = (short)f2bf(bf2f((unsigned short)t1[i]) * QSCALE);
        }
    }

    float mrow[4], lrow[4];
    #pragma unroll
    for (int r = 0; r < 4; ++r) { mrow[r] = -INFINITY; lrow[r] = 0.f; }
    f32x4 o[4];
    #pragma unroll
    for (int d = 0; d < 4; ++d) o[d] = (f32x4){0.f, 0.f, 0.f, 0.f};

    const int qg = strip * 16 + (l >> 4) * 4;

    for (int j = 0; j + 1 <= jmax; j += 2) {
        const bool diag2 = (j + 1 == jmax);

        bf16x8 kf[16];
        #pragma unroll
        for (int t = 0; t < 2; ++t)
            #pragma unroll
            for (int sb = 0; sb < 4; ++sb) {
                const unsigned short* kp = kfb + (size_t)((j + t) * 8 + sb * 2) * 512 + l * 8;
                kf[t * 8 + sb * 2]     = *(const bf16x8*)kp;
                kf[t * 8 + sb * 2 + 1] = *(const bf16x8*)(kp + 512);
            }

        f32x4 sf[8];
        __builtin_amdgcn_s_setprio(1);
        #pragma unroll
        for (int t = 0; t < 2; ++t)
            #pragma unroll
            for (int sb = 0; sb < 4; ++sb) {
                f32x4 acc = (f32x4){0.f, 0.f, 0.f, 0.f};
                acc = __builtin_amdgcn_mfma_f32_16x16x32_bf16(aq0, kf[t*8 + sb*2],     acc, 0, 0, 0);
                acc = __builtin_amdgcn_mfma_f32_16x16x32_bf16(aq1, kf[t*8 + sb*2 + 1], acc, 0, 0, 0);
                sf[t*4 + sb] = acc;
            }
        __builtin_amdgcn_s_setprio(0);

        bf16x8 vf[16];
        #pragma unroll
        for (int kb = 0; kb < 4; ++kb)
            #pragma unroll
            for (int db = 0; db < 4; ++db)
                vf[kb * 4 + db] = *(const bf16x8*)(vfb + (size_t)((j + (kb >> 1)) * 8 + (kb & 1) * 4 + db) * 512 + l * 8);

        if (diag2) {
            #pragma unroll
            for (int sb = 0; sb < 4; ++sb) {
                const int cg = (j + 1) * 64 + sb * 16 + (l & 15);
                #pragma unroll
                for (int r = 0; r < 4; ++r)
                    if (cg > qg + r) sf[4 + sb][r] = -INFINITY;
            }
        }

        float mnew[4], alpha[4], psum[4];
        #pragma unroll
        for (int r = 0; r < 4; ++r) {
            float mx = fmaxf(fmaxf(fmaxf(sf[0][r], sf[1][r]), fmaxf(sf[2][r], sf[3][r])),
                             fmaxf(fmaxf(sf[4][r], sf[5][r]), fmaxf(sf[6][r], sf[7][r])));
            mx = fmaxf(mx, __shfl_xor(mx, 1));
            mx = fmaxf(mx, __shfl_xor(mx, 2));
            mx = fmaxf(mx, __shfl_xor(mx, 4));
            mx = fmaxf(mx, __shfl_xor(mx, 8));
            float mn = fmaxf(mrow[r], mx);
            mnew[r]  = mn;
            alpha[r] = exp2f(mrow[r] - mn);
            mrow[r]  = mn;
            psum[r]  = 0.f;
        }
        #pragma unroll
        for (int t = 0; t < 2; ++t)
            #pragma unroll
            for (int sb = 0; sb < 4; ++sb) {
                const int col = t * 64 + sb * 16 + (l & 15);
                #pragma unroll
                for (int r = 0; r < 4; ++r) {
                    float p = exp2f(sf[t*4 + sb][r] - mnew[r]);
                    psum[r] += p;
                    const int row = (l >> 4) * 4 + r;
                    Ps[row * 128 + (((col >> 3) ^ (row & 7)) << 3) + (col & 7)] = f2bf(p);
                }
            }
        #pragma unroll
        for (int r = 0; r < 4; ++r) {
            float ps = psum[r];
            ps += __shfl_xor(ps, 1);
            ps += __shfl_xor(ps, 2);
            ps += __shfl_xor(ps, 4);
            ps += __shfl_xor(ps, 8);
            lrow[r] = lrow[r] * alpha[r] + ps;
            #pragma unroll
            for (int d = 0; d < 4; ++d) o[d][r] *= alpha[r];
        }

        __builtin_amdgcn_s_setprio(1);
        #pragma unroll
        for (int kb = 0; kb < 4; ++kb) {
            const int row = l & 15;
            bf16x8 pa = *(const bf16x8*)&Ps[row * 128 + (((kb * 4 + (l >> 4)) ^ (row & 7)) << 3)];
            #pragma unroll
            for (int db = 0; db < 4; ++db)
                o[db] = __builtin_amdgcn_mfma_f32_16x16x32_bf16(pa, vf[kb * 4 + db], o[db], 0, 0, 0);
        }
        __builtin_amdgcn_s_setprio(0);
    }

    if ((jmax & 1) == 0) {
        const int j = jmax;
        bf16x8 kf[8];
        #pragma unroll
        for (int sb = 0; sb < 4; ++sb) {
            const unsigned short* kp = kfb + (size_t)(j * 8 + sb * 2) * 512 + l * 8;
            kf[sb * 2]     = *(const bf16x8*)kp;
            kf[sb * 2 + 1] = *(const bf16x8*)(kp + 512);
        }
        f32x4 sf[4];
        __builtin_amdgcn_s_setprio(1);
        #pragma unroll
        for (int sb = 0; sb < 4; ++sb) {
            f32x4 acc = (f32x4){0.f, 0.f, 0.f, 0.f};
            acc = __builtin_amdgcn_mfma_f32_16x16x32_bf16(aq0, kf[sb*2],     acc, 0, 0, 0);
            acc = __builtin_amdgcn_mfma_f32_16x16x32_bf16(aq1, kf[sb*2 + 1], acc, 0, 0, 0);
            sf[sb] = acc;
        }
        __builtin_amdgcn_s_setprio(0);

        bf16x8 vf[8];
        #pragma unroll
        for (int kb = 0; kb < 2; ++kb)
            #pragma unroll
            for (int db = 0; db < 4; ++db)
                vf[kb * 4 + db] = *(const bf16x8*)(vfb + (size_t)(j * 8 + kb * 4 + db) * 512 + l * 8);
        #pragma unroll
        for (int sb = 0; sb < 4; ++sb) {
            const int cg = j * 64 + sb * 16 + (l & 15);
            #pragma unroll
            for (int r = 0; r < 4; ++r)
                if (cg > qg + r) sf[sb][r] = -INFINITY;
        }

        float mnew[4], alpha[4], psum[4];
        #pragma unroll
        for (int r = 0; r < 4; ++r) {
            float mx = fmaxf(fmaxf(sf[0][r], sf[1][r]), fmaxf(sf[2][r], sf[3][r]));
            mx = fmaxf(mx, __shfl_xor(mx, 1));
            mx = fmaxf(mx, __shfl_xor(mx, 2));
            mx = fmaxf(mx, __shfl_xor(mx, 4));
            mx = fmaxf(mx, __shfl_xor(mx, 8));
            float mn = fmaxf(mrow[r], mx);
            mnew[r]  = mn;
            alpha[r] = exp2f(mrow[r] - mn);
            mrow[r]  = mn;
            psum[r]  = 0.f;
        }
        #pragma unroll
        for (int sb = 0; sb < 4; ++sb) {
            const int col = sb * 16 + (l & 15);
            #pragma unroll
            for (int r = 0; r < 4; ++r) {
                float p = exp2f(sf[sb][r] - mnew[r]);
                psum[r] += p;
                const int row = (l >> 4) * 4 + r;
                Ps[row * 128 + (((col >> 3) ^ (row & 7)) << 3) + (col & 7)] = f2bf(p);
            }
        }
        #pragma unroll
        for (int r = 0; r < 4; ++r) {
            float ps = psum[r];
            ps += __shfl_xor(ps, 1);
            ps += __shfl_xor(ps, 2);
            ps += __shfl_xor(ps, 4);
            ps += __shfl_xor(ps, 8);
            lrow[r] = lrow[r] * alpha[r] + ps;
            #pragma unroll
            for (int d = 0; d < 4; ++d) o[d][r] *= alpha[r];
        }
        __builtin_amdgcn_s_setprio(1);
        #pragma unroll
        for (int kb = 0; kb < 2; ++kb) {
            const int row = l & 15;
            bf16x8 pa = *(const bf16x8*)&Ps[row * 128 + (((kb * 4 + (l >> 4)) ^ (row & 7)) << 3)];
            #pragma unroll
            for (int db = 0; db < 4; ++db)
                o[db] = __builtin_amdgcn_mfma_f32_16x16x32_bf16(pa, vf[kb * 4 + db], o[db], 0, 0, 0);
        }
        __builtin_amdgcn_s_setprio(0);
    }

    #pragma unroll
    for (int r = 0; r < 4; ++r) {
        const float inv = 1.0f / lrow[r];
        const size_t rb = (rowbase + strip * 16 + (l >> 4) * 4 + r) * (size_t)CDIM + h * 64 + (l & 15);
        #pragma unroll
        for (int d = 0; d < 4; ++d)
            out[rb + d * 16] = f2bf(o[d][r] * inv);
    }
}

extern "C" void kernel_launch(void* const* d_in, const int* in_sizes, int n_in,
                              void* d_out, int out_size, void* d_ws, size_t ws_size,
                              hipStream_t stream) {
    const float* x     = (const float*)d_in[0];
    const float* ln1_g = (const float*)d_in[1];
    const float* ln1_b = (const float*)d_in[2];
    const float* w_qkv = (const float*)d_in[3];
    const float* b_qkv = (const float*)d_in[4];
    const float* w_out = (const float*)d_in[5];
    const float* b_out = (const float*)d_in[6];
    const float* ln2_g = (const float*)d_in[7];
    const float* ln2_b = (const float*)d_in[8];
    const float* w_ff1 = (const float*)d_in[9];
    const float* b_ff1 = (const float*)d_in[10];
    const float* w_ff2 = (const float*)d_in[11];
    const float* b_ff2 = (const float*)d_in[12];
    float* out = (float*)d_out;

    char* wsb = (char*)d_ws;
    unsigned short* h_bf    = (unsigned short*)(wsb);                          // 8 MB
    unsigned short* qkv_bf  = (unsigned short*)(wsb + 8ll  * 1024 * 1024);     // 24 MB
    unsigned short* attn_bf = (unsigned short*)(wsb + 32ll * 1024 * 1024);     // 8 MB
    float*          x1      = (float*)         (wsb + 40ll * 1024 * 1024);     // 16 MB
    unsigned short* kfrag   = (unsigned short*)(wsb + 40ll * 1024 * 1024);     // 8 MB (overlays x1, dead until step 4)
    unsigned short* vfrag   = (unsigned short*)(wsb + 48ll * 1024 * 1024);     // 8 MB (overlays x1, dead until step 4)
    unsigned short* wqkvT   = (unsigned short*)(wsb + 56ll * 1024 * 1024);     // 6 MB
    unsigned short* woutT   = (unsigned short*)(wsb + 62ll * 1024 * 1024);     // 2 MB
    unsigned short* wff1T   = (unsigned short*)(wsb + 64ll * 1024 * 1024);     // 8 MB
    unsigned short* wff2T   = (unsigned short*)(wsb + 72ll * 1024 * 1024);     // 8 MB
    unsigned short* ff1_bf  = (unsigned short*)(wsb + 8ll  * 1024 * 1024);     // 32 MB, overlays dead qkv+attn

    transpose_cast_kernel<<<dim3(48, 16), 256, 0, stream>>>(w_qkv, wqkvT, 1024, 3072);
    transpose_cast_kernel<<<dim3(16, 16), 256, 0, stream>>>(w_out, woutT, 1024, 1024);
    transpose_cast_kernel<<<dim3(64, 16), 256, 0, stream>>>(w_ff1, wff1T, 1024, 4096);
    transpose_cast_kernel<<<dim3(16, 64), 256, 0, stream>>>(w_ff2, wff2T, 4096, 1024);

    // 1. LN1 -> bf16
    ln_kernel<<<ROWS, 256, 0, stream>>>(x, ln1_g, ln1_b, h_bf);
    // 2. qkv = h @ w_qkv + b  -> bf16   (768 blocks: nbx=24, 4 row-panels/XCD)
    gemm_kernel<0><<<768, 256, 0, stream>>>(h_bf, wqkvT, b_qkv, nullptr, qkv_bf, ROWS, 3072, 1024, 24, 4);
    // 2b. K/V fragment-major pre-pass
    kvfrag_kernel<<<dim3(32, 32), 256, 0, stream>>>(qkv_bf, kfrag, vfrag);
    // 3. causal flash attention -> bf16
    attn_kernel<<<4096, 64, 0, stream>>>(qkv_bf, kfrag, vfrag, attn_bf);
    // 4. x1 = x + attn @ w_out + b  -> f32   (512 blocks: nbx=8, 8 row-panels/XCD)
    gemm64_kernel<1><<<512, 256, 0, stream>>>(attn_bf, woutT, b_out, x, x1, ROWS, 1024, 1024, 8, 8);
    // 5. LN2 -> bf16
    ln_kernel<<<ROWS, 256, 0, stream>>>(x1, ln2_g, ln2_b, h_bf);
    // 6. ff1 = gelu(h @ w_ff1 + b)  -> bf16   (1024 blocks: nbx=32, 4 row-panels/XCD)
    gemm_kernel<2><<<1024, 256, 0, stream>>>(h_bf, wff1T, b_ff1, nullptr, ff1_bf, ROWS, 4096, 1024, 32, 4);
    // 7. out = x1 + ff1 @ w_ff2 + b  -> f32   (512 blocks: nbx=8, 8 row-panels/XCD)
    gemm64_kernel<1><<<512, 256, 0, stream>>>(ff1_bf, wff2T, b_ff2, x1, (float*)out, ROWS, 1024, 4096, 8, 8);
}

// Round 12
// 268.671 us; speedup vs baseline: 1.4385x; 1.0383x over previous
//
#include <hip/hip_runtime.h>
#include <hip/hip_bf16.h>
#include <math.h>

#define TSEQ 2048
#define BATCH 2
#define CDIM 1024
#define NH 16
#define HD 64
#define DFF 4096
#define ROWS (BATCH*TSEQ)   // 4096

typedef __attribute__((ext_vector_type(4))) float f32x4;
typedef __attribute__((ext_vector_type(8))) short bf16x8;   // 8 bf16 in 4 VGPRs
typedef __attribute__((ext_vector_type(4))) unsigned short u16x4;

__device__ __forceinline__ void gload_lds16(const void* g, void* l) {
    void* gv = const_cast<void*>(g);
    __builtin_amdgcn_global_load_lds((__attribute__((address_space(1))) void*)gv,
                                     (__attribute__((address_space(3))) void*)l, 16, 0, 0);
}

__device__ __forceinline__ unsigned short f2bf(float f) {
    unsigned int u = __float_as_uint(f);
    return (unsigned short)((u + 0x7FFFu + ((u >> 16) & 1u)) >> 16);
}
__device__ __forceinline__ float bf2f(unsigned short u) {
    return __uint_as_float((unsigned int)u << 16);
}
// packed f32x2 -> bf16x2 (low half = first arg); no builtin on gfx950 (T12)
__device__ __forceinline__ unsigned int cvt_pk_bf16(float lo, float hi) {
    unsigned int r;
    asm("v_cvt_pk_bf16_f32 %0, %1, %2" : "=v"(r) : "v"(lo), "v"(hi));
    return r;
}
// tanh-form GELU: v * sigmoid(1.59577*(v + 0.044715 v^3)); |err vs exact| < ~3e-4
__device__ __forceinline__ float fast_gelu(float v) {
    float u = fmaf(0.044715f * v * v, v, v);
    float e = __expf(-1.5957691216057308f * u);
    return v * __builtin_amdgcn_rcpf(1.0f + e);
}

// ------------------------------- LayerNorm -> bf16 --------------------------------
__global__ __launch_bounds__(256) void ln_kernel(const float* __restrict__ x,
                                                 const float* __restrict__ g,
                                                 const float* __restrict__ b,
                                                 unsigned short* __restrict__ out) {
    int row = blockIdx.x;
    int tid = threadIdx.x;
    const float* xr = x + (size_t)row * CDIM;
    float4 v = *(const float4*)(xr + tid * 4);
    float s  = v.x + v.y + v.z + v.w;
    float s2 = v.x*v.x + v.y*v.y + v.z*v.z + v.w*v.w;
    #pragma unroll
    for (int off = 32; off >= 1; off >>= 1) {
        s  += __shfl_down(s, off);
        s2 += __shfl_down(s2, off);
    }
    __shared__ float red[8];
    int wid = tid >> 6, lane = tid & 63;
    if (lane == 0) { red[wid] = s; red[wid + 4] = s2; }
    __syncthreads();
    float ts  = red[0] + red[1] + red[2] + red[3];
    float ts2 = red[4] + red[5] + red[6] + red[7];
    float mu  = ts * (1.0f / CDIM);
    float var = ts2 * (1.0f / CDIM) - mu * mu;
    float rstd = rsqrtf(var + 1e-5f);
    float4 gv = *(const float4*)(g + tid * 4);
    float4 bv = *(const float4*)(b + tid * 4);
    unsigned short o4[4];
    o4[0] = f2bf((v.x - mu) * rstd * gv.x + bv.x);
    o4[1] = f2bf((v.y - mu) * rstd * gv.y + bv.y);
    o4[2] = f2bf((v.z - mu) * rstd * gv.z + bv.z);
    o4[3] = f2bf((v.w - mu) * rstd * gv.w + bv.w);
    *(u16x4*)(out + (size_t)row * CDIM + tid * 4) = *(u16x4*)o4;
}

// --------------------- transpose + cast: W[K][N] f32 -> Wt[N][K] bf16 ---------------
__global__ __launch_bounds__(256) void transpose_cast_kernel(const float* __restrict__ W,
                                                             unsigned short* __restrict__ Wt,
                                                             int K, int N) {
    __shared__ float T[64][65];
    int tid = threadIdx.x;
    int n0 = blockIdx.x * 64, k0 = blockIdx.y * 64;
    int kr = tid >> 4;
    int nc = (tid & 15) * 4;
    #pragma unroll
    for (int i = 0; i < 4; ++i) {
        float4 v = *(const float4*)&W[(size_t)(k0 + kr + i*16) * N + (n0 + nc)];
        T[kr + i*16][nc + 0] = v.x;
        T[kr + i*16][nc + 1] = v.y;
        T[kr + i*16][nc + 2] = v.z;
        T[kr + i*16][nc + 3] = v.w;
    }
    __syncthreads();
    int n  = tid >> 2;
    int kb = (tid & 3) * 16;
    unsigned short tmp[16];
    #pragma unroll
    for (int i = 0; i < 16; ++i) tmp[i] = f2bf(T[kb + i][n]);
    unsigned short* dst = Wt + (size_t)(n0 + n) * K + (k0 + kb);
    *(int4*)dst       = *(int4*)&tmp[0];
    *(int4*)(dst + 8) = *(int4*)&tmp[8];
}

// ---- K/V fragment-major pre-pass (see R8 notes) -----------------------------------
__global__ __launch_bounds__(256) void kvfrag_kernel(const unsigned short* __restrict__ qkv,
                                                     unsigned short* __restrict__ kfrag,
                                                     unsigned short* __restrict__ vfrag) {
    __shared__ unsigned short Kt[64][72];
    __shared__ unsigned short Vt[64][72];
    const int tid = threadIdx.x;
    const int j  = blockIdx.x;
    const int bh = blockIdx.y;
    const int b = bh >> 4, h = bh & 15;
    {
        const int r  = tid >> 2;
        const int c0 = (tid & 3) * 16;
        const unsigned short* src = qkv + ((size_t)(b * TSEQ + j * 64 + r)) * 3072 + 1024 + h * 64 + c0;
        bf16x8 k0 = *(const bf16x8*)src;
        bf16x8 k1 = *(const bf16x8*)(src + 8);
        bf16x8 v0 = *(const bf16x8*)(src + 1024);
        bf16x8 v1 = *(const bf16x8*)(src + 1032);
        *(bf16x8*)&Kt[r][c0]     = k0;
        *(bf16x8*)&Kt[r][c0 + 8] = k1;
        *(bf16x8*)&Vt[r][c0]     = v0;
        *(bf16x8*)&Vt[r][c0 + 8] = v1;
    }
    __syncthreads();
    const int l  = tid & 63;
    const int qd = tid >> 6;
    const size_t tbase = ((size_t)(bh * 32 + j)) * 8 * 512;
    #pragma unroll
    for (int pass = 0; pass < 2; ++pass) {
        const int kc = qd + pass * 4;
        const int sb = kc >> 1, g = kc & 1;
        bf16x8 kv = *(const bf16x8*)&Kt[sb * 16 + (l & 15)][g * 32 + (l >> 4) * 8];
        *(bf16x8*)(kfrag + tbase + kc * 512 + l * 8) = kv;

        const int vc = qd + pass * 4;
        const int kb = vc >> 2, db = vc & 3;
        unsigned short tmp[8];
        #pragma unroll
        for (int i = 0; i < 8; ++i)
            tmp[i] = Vt[kb * 32 + (l >> 4) * 8 + i][db * 16 + (l & 15)];
        *(bf16x8*)(vfrag + tbase + vc * 512 + l * 8) = *(bf16x8*)tmp;
    }
}

// ------------- MFMA GEMM (TN) 128x128 tile, BK=64, XOR swizzle, XCD-banded ---------
template<int EPI>
__global__ __launch_bounds__(256) void gemm_kernel(const unsigned short* __restrict__ A,
                                                   const unsigned short* __restrict__ Bt,
                                                   const float* __restrict__ bias,
                                                   const float* __restrict__ res,
                                                   void* __restrict__ Cout,
                                                   int M, int N, int K, int nbx, int rpx) {
    __shared__ __align__(16) unsigned short As[128 * 64];   // 16 KB
    __shared__ __align__(16) unsigned short Bs[128 * 64];   // 16 KB
    const int tid = threadIdx.x;
    const int l   = tid & 63;
    const int w   = tid >> 6;
    const int wr  = (w >> 1) * 64;
    const int wc  = (w & 1) * 64;
    const int lin = blockIdx.x;
    const int xcd = lin & 7;
    const int idx = lin >> 3;
    const long brow = (long)(xcd * rpx + idx / nbx) * 128;
    const long bcol = (long)(idx % nbx) * 128;

    const int srow = tid >> 3;                                  // 0..31
    const int schk = ((tid & 7) ^ (srow & 7)) * 8;              // global elem offset
    const unsigned short* gA = A  + (size_t)(brow + srow) * K + schk;
    const unsigned short* gB = Bt + (size_t)(bcol + srow) * K + schk;
    unsigned short* lA = As + tid * 8;
    unsigned short* lB = Bs + tid * 8;

    f32x4 acc[4][4];
    #pragma unroll
    for (int m = 0; m < 4; ++m)
        #pragma unroll
        for (int n = 0; n < 4; ++n) acc[m][n] = (f32x4){0.f, 0.f, 0.f, 0.f};

    for (int k0 = 0; k0 < K; k0 += 64) {
        #pragma unroll
        for (int p = 0; p < 4; ++p) {
            gload_lds16(gA + (size_t)(32 * p) * K + k0, lA + p * 2048);
            gload_lds16(gB + (size_t)(32 * p) * K + k0, lB + p * 2048);
        }
        __syncthreads();
        #pragma unroll
        for (int gg = 0; gg < 2; ++gg) {
            const int koff = ((gg * 4 + (l >> 4)) ^ (l & 7)) * 8;
            bf16x8 af[4], bf[4];
            #pragma unroll
            for (int m = 0; m < 4; ++m)
                af[m] = *(const bf16x8*)&As[(wr + m * 16 + (l & 15)) * 64 + koff];
            #pragma unroll
            for (int n = 0; n < 4; ++n)
                bf[n] = *(const bf16x8*)&Bs[(wc + n * 16 + (l & 15)) * 64 + koff];
            #pragma unroll
            for (int m = 0; m < 4; ++m)
                #pragma unroll
                for (int n = 0; n < 4; ++n)
                    acc[m][n] = __builtin_amdgcn_mfma_f32_16x16x32_bf16(af[m], bf[n], acc[m][n], 0, 0, 0);
        }
        __syncthreads();
    }

    #pragma unroll
    for (int m = 0; m < 4; ++m) {
        const int rown = wr + m * 16 + (l >> 4) * 4;
        #pragma unroll
        for (int n = 0; n < 4; ++n) {
            const long col = bcol + wc + n * 16 + (l & 15);
            const float bb = bias[col];
            #pragma unroll
            for (int r = 0; r < 4; ++r) {
                const long row = brow + rown + r;
                float v = acc[m][n][r] + bb;
                if (EPI == 1) {
                    v += res[row * N + col];
                    ((float*)Cout)[row * N + col] = v;
                } else if (EPI == 2) {
                    ((unsigned short*)Cout)[row * N + col] = f2bf(fast_gelu(v));
                } else {
                    ((unsigned short*)Cout)[row * N + col] = f2bf(v);
                }
            }
        }
    }
}

// ------------- MFMA GEMM (TN) 64x128 tile, BK=64, XOR swizzle, XCD-banded ----------
template<int EPI>
__global__ __launch_bounds__(256) void gemm64_kernel(const unsigned short* __restrict__ A,
                                                     const unsigned short* __restrict__ Bt,
                                                     const float* __restrict__ bias,
                                                     const float* __restrict__ res,
                                                     void* __restrict__ Cout,
                                                     int M, int N, int K, int nbx, int rpx) {
    __shared__ __align__(16) unsigned short As[64 * 64];    // 8 KB
    __shared__ __align__(16) unsigned short Bs[128 * 64];   // 16 KB
    const int tid = threadIdx.x;
    const int l   = tid & 63;
    const int w   = tid >> 6;
    const int wr  = (w >> 1) * 32;
    const int wc  = (w & 1) * 64;
    const int lin = blockIdx.x;
    const int xcd = lin & 7;
    const int idx = lin >> 3;
    const long brow = (long)(xcd * rpx + idx / nbx) * 64;
    const long bcol = (long)(idx % nbx) * 128;

    const int srow = tid >> 3;                                  // 0..31
    const int schk = ((tid & 7) ^ (srow & 7)) * 8;
    const unsigned short* gA = A  + (size_t)(brow + srow) * K + schk;
    const unsigned short* gB = Bt + (size_t)(bcol + srow) * K + schk;
    unsigned short* lA = As + tid * 8;
    unsigned short* lB = Bs + tid * 8;

    f32x4 acc[2][4];
    #pragma unroll
    for (int m = 0; m < 2; ++m)
        #pragma unroll
        for (int n = 0; n < 4; ++n) acc[m][n] = (f32x4){0.f, 0.f, 0.f, 0.f};

    for (int k0 = 0; k0 < K; k0 += 64) {
        #pragma unroll
        for (int p = 0; p < 2; ++p)
            gload_lds16(gA + (size_t)(32 * p) * K + k0, lA + p * 2048);
        #pragma unroll
        for (int p = 0; p < 4; ++p)
            gload_lds16(gB + (size_t)(32 * p) * K + k0, lB + p * 2048);
        __syncthreads();
        #pragma unroll
        for (int gg = 0; gg < 2; ++gg) {
            const int koff = ((gg * 4 + (l >> 4)) ^ (l & 7)) * 8;
            bf16x8 af[2], bf[4];
            #pragma unroll
            for (int m = 0; m < 2; ++m)
                af[m] = *(const bf16x8*)&As[(wr + m * 16 + (l & 15)) * 64 + koff];
            #pragma unroll
            for (int n = 0; n < 4; ++n)
                bf[n] = *(const bf16x8*)&Bs[(wc + n * 16 + (l & 15)) * 64 + koff];
            #pragma unroll
            for (int m = 0; m < 2; ++m)
                #pragma unroll
                for (int n = 0; n < 4; ++n)
                    acc[m][n] = __builtin_amdgcn_mfma_f32_16x16x32_bf16(af[m], bf[n], acc[m][n], 0, 0, 0);
        }
        __syncthreads();
    }

    #pragma unroll
    for (int m = 0; m < 2; ++m) {
        const int rown = wr + m * 16 + (l >> 4) * 4;
        #pragma unroll
        for (int n = 0; n < 4; ++n) {
            const long col = bcol + wc + n * 16 + (l & 15);
            const float bb = bias[col];
            #pragma unroll
            for (int r = 0; r < 4; ++r) {
                const long row = brow + rown + r;
                float v = acc[m][n][r] + bb;
                if (EPI == 1) {
                    v += res[row * N + col];
                    ((float*)Cout)[row * N + col] = v;
                } else if (EPI == 2) {
                    ((unsigned short*)Cout)[row * N + col] = f2bf(fast_gelu(v));
                } else {
                    ((unsigned short*)Cout)[row * N + col] = f2bf(v);
                }
            }
        }
    }
}

// ------------- MFMA causal flash attention (swapped QK^T, in-lane softmax) ----------
// mfma(K,Q) puts one q-row per lane (q=l&15): softmax is in-lane + 2 group merges.
// P packed via v_cvt_pk_bf16_f32, stored as [q][s] with 16B-chunk XOR swizzle
// (c16 ^= q&7): writes 8x b64, PV reads 4x b128, both 2-way (free).
#define QSCALE 0.18033688011112042f   // 0.125 * log2(e)
__global__ __launch_bounds__(64) void attn_kernel(const unsigned short* __restrict__ qkv,
                                                  const unsigned short* __restrict__ kfrag,
                                                  const unsigned short* __restrict__ vfrag,
                                                  unsigned short* __restrict__ out) {
    __shared__ __align__(16) unsigned short Ps[16 * 128];   // [q][s], 16B-chunk swizzled

    const int l    = threadIdx.x;
    const int q    = l & 15;                   // lane's softmax row
    const int g    = l >> 4;                   // lane group 0..3
    const int lin  = blockIdx.x;
    const int xcd  = lin & 7;
    const int rest = lin >> 3;
    const int h    = xcd + 8 * (rest & 1);
    const int b    = (rest >> 1) & 1;
    const int strip = 127 - (rest >> 2);
    const int jmax  = strip >> 2;
    const size_t rowbase = (size_t)b * TSEQ;
    const int bh = b * NH + h;
    const int qglob = strip * 16 + q;

    const unsigned short* kfb = kfrag + (size_t)bh * 32 * 8 * 512;
    const unsigned short* vfb = vfrag + (size_t)bh * 32 * 8 * 512;

    // Q fragments (B operand: col=q, k-slice g*8), pre-scaled by 0.125*log2e
    bf16x8 aq0, aq1;
    {
        const unsigned short* qp = qkv + (rowbase + qglob) * 3072 + h * 64 + g * 8;
        bf16x8 t0 = *(const bf16x8*)qp;
        bf16x8 t1 = *(const bf16x8*)(qp + 32);
        #pragma unroll
        for (int i = 0; i < 8; ++i) {
            aq0[i] = (short)f2bf(bf2f((unsigned short)t0[i]) * QSCALE);
            aq1[i] = (short)f2bf(bf2f((unsigned short)t1[i]) * QSCALE);
        }
    }

    float mrow = -INFINITY, lrow = 0.f;
    f32x4 o[4];
    #pragma unroll
    for (int d = 0; d < 4; ++d) o[d] = (f32x4){0.f, 0.f, 0.f, 0.f};

    // ---------------- pair steps: tiles j, j+1 (128 s-cols per softmax) --------------
    for (int j = 0; j + 1 <= jmax; j += 2) {
        const bool diag2 = (j + 1 == jmax);

        bf16x8 kf[16];
        #pragma unroll
        for (int t = 0; t < 2; ++t)
            #pragma unroll
            for (int sb = 0; sb < 4; ++sb) {
                const unsigned short* kp = kfb + (size_t)((j + t) * 8 + sb * 2) * 512 + l * 8;
                kf[t * 8 + sb * 2]     = *(const bf16x8*)kp;
                kf[t * 8 + sb * 2 + 1] = *(const bf16x8*)(kp + 512);
            }

        // S^T = K Q^T : lane holds q=l&15, s = t*64 + sb*16 + 4g + r
        f32x4 sf[8];
        __builtin_amdgcn_s_setprio(1);
        #pragma unroll
        for (int t = 0; t < 2; ++t)
            #pragma unroll
            for (int sb = 0; sb < 4; ++sb) {
                f32x4 acc = (f32x4){0.f, 0.f, 0.f, 0.f};
                acc = __builtin_amdgcn_mfma_f32_16x16x32_bf16(kf[t*8 + sb*2],     aq0, acc, 0, 0, 0);
                acc = __builtin_amdgcn_mfma_f32_16x16x32_bf16(kf[t*8 + sb*2 + 1], aq1, acc, 0, 0, 0);
                sf[t*4 + sb] = acc;
            }
        __builtin_amdgcn_s_setprio(0);

        bf16x8 vf[16];
        #pragma unroll
        for (int kb = 0; kb < 4; ++kb)
            #pragma unroll
            for (int db = 0; db < 4; ++db)
                vf[kb * 4 + db] = *(const bf16x8*)(vfb + (size_t)((j + (kb >> 1)) * 8 + (kb & 1) * 4 + db) * 512 + l * 8);

        if (diag2) {
            #pragma unroll
            for (int sb = 0; sb < 4; ++sb) {
                const int sg = (j + 1) * 64 + sb * 16 + 4 * g;
                #pragma unroll
                for (int r = 0; r < 4; ++r)
                    if (sg + r > qglob) sf[4 + sb][r] = -INFINITY;
            }
        }

        // in-lane max over 32 + merge across the 4 groups
        f32x4 mv = sf[0];
        #pragma unroll
        for (int i = 1; i < 8; ++i)
            #pragma unroll
            for (int r = 0; r < 4; ++r) mv[r] = fmaxf(mv[r], sf[i][r]);
        float mloc = fmaxf(fmaxf(mv[0], mv[1]), fmaxf(mv[2], mv[3]));
        mloc = fmaxf(mloc, __shfl_xor(mloc, 16));
        mloc = fmaxf(mloc, __shfl_xor(mloc, 32));
        const float mn = fmaxf(mrow, mloc);
        const float alpha = exp2f(mrow - mn);
        mrow = mn;

        float psum = 0.f;
        #pragma unroll
        for (int i = 0; i < 8; ++i) {
            const int t = i >> 2, sb = i & 3;
            float p0 = exp2f(sf[i][0] - mn);
            float p1 = exp2f(sf[i][1] - mn);
            float p2 = exp2f(sf[i][2] - mn);
            float p3 = exp2f(sf[i][3] - mn);
            psum += (p0 + p1) + (p2 + p3);
            unsigned int pk0 = cvt_pk_bf16(p0, p1);
            unsigned int pk1 = cvt_pk_bf16(p2, p3);
            const int c16 = (t * 8 + sb * 2 + (g >> 1)) ^ (q & 7);
            *(uint2*)((char*)Ps + q * 256 + c16 * 16 + (g & 1) * 8) = make_uint2(pk0, pk1);
        }
        psum += __shfl_xor(psum, 16);
        psum += __shfl_xor(psum, 32);
        lrow = lrow * alpha + psum;

        float al[4];
        #pragma unroll
        for (int r = 0; r < 4; ++r) al[r] = __shfl(alpha, g * 4 + r);
        #pragma unroll
        for (int d = 0; d < 4; ++d)
            #pragma unroll
            for (int r = 0; r < 4; ++r) o[d][r] *= al[r];

        // O += P V  (pa: row=q, s-slice = kb*32 + g*8; lgkmcnt orders write->read)
        __builtin_amdgcn_s_setprio(1);
        #pragma unroll
        for (int kb = 0; kb < 4; ++kb) {
            const int c16 = (kb * 4 + g) ^ (q & 7);
            bf16x8 pa = *(const bf16x8*)((const char*)Ps + q * 256 + c16 * 16);
            #pragma unroll
            for (int db = 0; db < 4; ++db)
                o[db] = __builtin_amdgcn_mfma_f32_16x16x32_bf16(pa, vf[kb * 4 + db], o[db], 0, 0, 0);
        }
        __builtin_amdgcn_s_setprio(0);
    }

    // ---------------- tail single tile (j = jmax) when tile count is odd -------------
    if ((jmax & 1) == 0) {
        const int j = jmax;
        bf16x8 kf[8];
        #pragma unroll
        for (int sb = 0; sb < 4; ++sb) {
            const unsigned short* kp = kfb + (size_t)(j * 8 + sb * 2) * 512 + l * 8;
            kf[sb * 2]     = *(const bf16x8*)kp;
            kf[sb * 2 + 1] = *(const bf16x8*)(kp + 512);
        }
        f32x4 sf[4];
        __builtin_amdgcn_s_setprio(1);
        #pragma unroll
        for (int sb = 0; sb < 4; ++sb) {
            f32x4 acc = (f32x4){0.f, 0.f, 0.f, 0.f};
            acc = __builtin_amdgcn_mfma_f32_16x16x32_bf16(kf[sb*2],     aq0, acc, 0, 0, 0);
            acc = __builtin_amdgcn_mfma_f32_16x16x32_bf16(kf[sb*2 + 1], aq1, acc, 0, 0, 0);
            sf[sb] = acc;
        }
        __builtin_amdgcn_s_setprio(0);

        bf16x8 vf[8];
        #pragma unroll
        for (int kb = 0; kb < 2; ++kb)
            #pragma unroll
            for (int db = 0; db < 4; ++db)
                vf[kb * 4 + db] = *(const bf16x8*)(vfb + (size_t)(j * 8 + kb * 4 + db) * 512 + l * 8);

        #pragma unroll
        for (int sb = 0; sb < 4; ++sb) {
            const int sg = j * 64 + sb * 16 + 4 * g;
            #pragma unroll
            for (int r = 0; r < 4; ++r)
                if (sg + r > qglob) sf[sb][r] = -INFINITY;
        }

        f32x4 mv = sf[0];
        #pragma unroll
        for (int i = 1; i < 4; ++i)
            #pragma unroll
            for (int r = 0; r < 4; ++r) mv[r] = fmaxf(mv[r], sf[i][r]);
        float mloc = fmaxf(fmaxf(mv[0], mv[1]), fmaxf(mv[2], mv[3]));
        mloc = fmaxf(mloc, __shfl_xor(mloc, 16));
        mloc = fmaxf(mloc, __shfl_xor(mloc, 32));
        const float mn = fmaxf(mrow, mloc);
        const float alpha = exp2f(mrow - mn);
        mrow = mn;

        float psum = 0.f;
        #pragma unroll
        for (int sb = 0; sb < 4; ++sb) {
            float p0 = exp2f(sf[sb][0] - mn);
            float p1 = exp2f(sf[sb][1] - mn);
            float p2 = exp2f(sf[sb][2] - mn);
            float p3 = exp2f(sf[sb][3] - mn);
            psum += (p0 + p1) + (p2 + p3);
            unsigned int pk0 = cvt_pk_bf16(p0, p1);
            unsigned int pk1 = cvt_pk_bf16(p2, p3);
            const int c16 = (sb * 2 + (g >> 1)) ^ (q & 7);
            *(uint2*)((char*)Ps + q * 256 + c16 * 16 + (g & 1) * 8) = make_uint2(pk0, pk1);
        }
        psum += __shfl_xor(psum, 16);
        psum += __shfl_xor(psum, 32);
        lrow = lrow * alpha + psum;

        float al[4];
        #pragma unroll
        for (int r = 0; r < 4; ++r) al[r] = __shfl(alpha, g * 4 + r);
        #pragma unroll
        for (int d = 0; d < 4; ++d)
            #pragma unroll
            for (int r = 0; r < 4; ++r) o[d][r] *= al[r];

        __builtin_amdgcn_s_setprio(1);
        #pragma unroll
        for (int kb = 0; kb < 2; ++kb) {
            const int c16 = (kb * 4 + g) ^ (q & 7);
            bf16x8 pa = *(const bf16x8*)((const char*)Ps + q * 256 + c16 * 16);
            #pragma unroll
            for (int db = 0; db < 4; ++db)
                o[db] = __builtin_amdgcn_mfma_f32_16x16x32_bf16(pa, vf[kb * 4 + db], o[db], 0, 0, 0);
        }
        __builtin_amdgcn_s_setprio(0);
    }

    // epilogue: O rows = g*4+r, cols = q + db*16 (same addressing as before)
    float linv[4];
    #pragma unroll
    for (int r = 0; r < 4; ++r) linv[r] = 1.0f / __shfl(lrow, g * 4 + r);
    #pragma unroll
    for (int r = 0; r < 4; ++r) {
        const size_t rb = (rowbase + strip * 16 + g * 4 + r) * (size_t)CDIM + h * 64 + q;
        #pragma unroll
        for (int d = 0; d < 4; ++d)
            out[rb + d * 16] = f2bf(o[d][r] * linv[r]);
    }
}

extern "C" void kernel_launch(void* const* d_in, const int* in_sizes, int n_in,
                              void* d_out, int out_size, void* d_ws, size_t ws_size,
                              hipStream_t stream) {
    const float* x     = (const float*)d_in[0];
    const float* ln1_g = (const float*)d_in[1];
    const float* ln1_b = (const float*)d_in[2];
    const float* w_qkv = (const float*)d_in[3];
    const float* b_qkv = (const float*)d_in[4];
    const float* w_out = (const float*)d_in[5];
    const float* b_out = (const float*)d_in[6];
    const float* ln2_g = (const float*)d_in[7];
    const float* ln2_b = (const float*)d_in[8];
    const float* w_ff1 = (const float*)d_in[9];
    const float* b_ff1 = (const float*)d_in[10];
    const float* w_ff2 = (const float*)d_in[11];
    const float* b_ff2 = (const float*)d_in[12];
    float* out = (float*)d_out;

    char* wsb = (char*)d_ws;
    unsigned short* h_bf    = (unsigned short*)(wsb);                          // 8 MB
    unsigned short* qkv_bf  = (unsigned short*)(wsb + 8ll  * 1024 * 1024);     // 24 MB
    unsigned short* attn_bf = (unsigned short*)(wsb + 32ll * 1024 * 1024);     // 8 MB
    float*          x1      = (float*)         (wsb + 40ll * 1024 * 1024);     // 16 MB
    unsigned short* kfrag   = (unsigned short*)(wsb + 40ll * 1024 * 1024);     // 8 MB (overlays x1, dead until step 4)
    unsigned short* vfrag   = (unsigned short*)(wsb + 48ll * 1024 * 1024);     // 8 MB (overlays x1, dead until step 4)
    unsigned short* wqkvT   = (unsigned short*)(wsb + 56ll * 1024 * 1024);     // 6 MB
    unsigned short* woutT   = (unsigned short*)(wsb + 62ll * 1024 * 1024);     // 2 MB
    unsigned short* wff1T   = (unsigned short*)(wsb + 64ll * 1024 * 1024);     // 8 MB
    unsigned short* wff2T   = (unsigned short*)(wsb + 72ll * 1024 * 1024);     // 8 MB
    unsigned short* ff1_bf  = (unsigned short*)(wsb + 8ll  * 1024 * 1024);     // 32 MB, overlays dead qkv+attn

    transpose_cast_kernel<<<dim3(48, 16), 256, 0, stream>>>(w_qkv, wqkvT, 1024, 3072);
    transpose_cast_kernel<<<dim3(16, 16), 256, 0, stream>>>(w_out, woutT, 1024, 1024);
    transpose_cast_kernel<<<dim3(64, 16), 256, 0, stream>>>(w_ff1, wff1T, 1024, 4096);
    transpose_cast_kernel<<<dim3(16, 64), 256, 0, stream>>>(w_ff2, wff2T, 4096, 1024);

    // 1. LN1 -> bf16
    ln_kernel<<<ROWS, 256, 0, stream>>>(x, ln1_g, ln1_b, h_bf);
    // 2. qkv = h @ w_qkv + b  -> bf16   (768 blocks: nbx=24, 4 row-panels/XCD)
    gemm_kernel<0><<<768, 256, 0, stream>>>(h_bf, wqkvT, b_qkv, nullptr, qkv_bf, ROWS, 3072, 1024, 24, 4);
    // 2b. K/V fragment-major pre-pass
    kvfrag_kernel<<<dim3(32, 32), 256, 0, stream>>>(qkv_bf, kfrag, vfrag);
    // 3. causal flash attention -> bf16 (swapped QK^T, in-lane softmax)
    attn_kernel<<<4096, 64, 0, stream>>>(qkv_bf, kfrag, vfrag, attn_bf);
    // 4. x1 = x + attn @ w_out + b  -> f32   (512 blocks: nbx=8, 8 row-panels/XCD)
    gemm64_kernel<1><<<512, 256, 0, stream>>>(attn_bf, woutT, b_out, x, x1, ROWS, 1024, 1024, 8, 8);
    // 5. LN2 -> bf16
    ln_kernel<<<ROWS, 256, 0, stream>>>(x1, ln2_g, ln2_b, h_bf);
    // 6. ff1 = gelu(h @ w_ff1 + b)  -> bf16   (1024 blocks: nbx=32, 4 row-panels/XCD)
    gemm_kernel<2><<<1024, 256, 0, stream>>>(h_bf, wff1T, b_ff1, nullptr, ff1_bf, ROWS, 4096, 1024, 32, 4);
    // 7. out = x1 + ff1 @ w_ff2 + b  -> f32   (512 blocks: nbx=8, 8 row-panels/XCD)
    gemm64_kernel<1><<<512, 256, 0, stream>>>(ff1_bf, wff2T, b_ff2, x1, (float*)out, ROWS, 1024, 4096, 8, 8);
}

// Round 13
// 266.222 us; speedup vs baseline: 1.4517x; 1.0092x over previous
//
#include <hip/hip_runtime.h>
#include <hip/hip_bf16.h>
#include <math.h>

#define TSEQ 2048
#define BATCH 2
#define CDIM 1024
#define NH 16
#define HD 64
#define DFF 4096
#define ROWS (BATCH*TSEQ)   // 4096

typedef __attribute__((ext_vector_type(4))) float f32x4;
typedef __attribute__((ext_vector_type(8))) short bf16x8;   // 8 bf16 in 4 VGPRs
typedef __attribute__((ext_vector_type(4))) unsigned short u16x4;

__device__ __forceinline__ void gload_lds16(const void* g, void* l) {
    void* gv = const_cast<void*>(g);
    __builtin_amdgcn_global_load_lds((__attribute__((address_space(1))) void*)gv,
                                     (__attribute__((address_space(3))) void*)l, 16, 0, 0);
}

__device__ __forceinline__ unsigned short f2bf(float f) {
    unsigned int u = __float_as_uint(f);
    return (unsigned short)((u + 0x7FFFu + ((u >> 16) & 1u)) >> 16);
}
__device__ __forceinline__ float bf2f(unsigned short u) {
    return __uint_as_float((unsigned int)u << 16);
}
// packed f32x2 -> bf16x2 (low half = first arg); no builtin on gfx950 (T12)
__device__ __forceinline__ unsigned int cvt_pk_bf16(float lo, float hi) {
    unsigned int r;
    asm("v_cvt_pk_bf16_f32 %0, %1, %2" : "=v"(r) : "v"(lo), "v"(hi));
    return r;
}
// tanh-form GELU: v * sigmoid(1.59577*(v + 0.044715 v^3)); |err vs exact| < ~3e-4
__device__ __forceinline__ float fast_gelu(float v) {
    float u = fmaf(0.044715f * v * v, v, v);
    float e = __expf(-1.5957691216057308f * u);
    return v * __builtin_amdgcn_rcpf(1.0f + e);
}

// ------------------------------- LayerNorm -> bf16 --------------------------------
__global__ __launch_bounds__(256) void ln_kernel(const float* __restrict__ x,
                                                 const float* __restrict__ g,
                                                 const float* __restrict__ b,
                                                 unsigned short* __restrict__ out) {
    int row = blockIdx.x;
    int tid = threadIdx.x;
    const float* xr = x + (size_t)row * CDIM;
    float4 v = *(const float4*)(xr + tid * 4);
    float s  = v.x + v.y + v.z + v.w;
    float s2 = v.x*v.x + v.y*v.y + v.z*v.z + v.w*v.w;
    #pragma unroll
    for (int off = 32; off >= 1; off >>= 1) {
        s  += __shfl_down(s, off);
        s2 += __shfl_down(s2, off);
    }
    __shared__ float red[8];
    int wid = tid >> 6, lane = tid & 63;
    if (lane == 0) { red[wid] = s; red[wid + 4] = s2; }
    __syncthreads();
    float ts  = red[0] + red[1] + red[2] + red[3];
    float ts2 = red[4] + red[5] + red[6] + red[7];
    float mu  = ts * (1.0f / CDIM);
    float var = ts2 * (1.0f / CDIM) - mu * mu;
    float rstd = rsqrtf(var + 1e-5f);
    float4 gv = *(const float4*)(g + tid * 4);
    float4 bv = *(const float4*)(b + tid * 4);
    unsigned short o4[4];
    o4[0] = f2bf((v.x - mu) * rstd * gv.x + bv.x);
    o4[1] = f2bf((v.y - mu) * rstd * gv.y + bv.y);
    o4[2] = f2bf((v.z - mu) * rstd * gv.z + bv.z);
    o4[3] = f2bf((v.w - mu) * rstd * gv.w + bv.w);
    *(u16x4*)(out + (size_t)row * CDIM + tid * 4) = *(u16x4*)o4;
}

// --------------------- transpose + cast: W[K][N] f32 -> Wt[N][K] bf16 ---------------
__global__ __launch_bounds__(256) void transpose_cast_kernel(const float* __restrict__ W,
                                                             unsigned short* __restrict__ Wt,
                                                             int K, int N) {
    __shared__ float T[64][65];
    int tid = threadIdx.x;
    int n0 = blockIdx.x * 64, k0 = blockIdx.y * 64;
    int kr = tid >> 4;
    int nc = (tid & 15) * 4;
    #pragma unroll
    for (int i = 0; i < 4; ++i) {
        float4 v = *(const float4*)&W[(size_t)(k0 + kr + i*16) * N + (n0 + nc)];
        T[kr + i*16][nc + 0] = v.x;
        T[kr + i*16][nc + 1] = v.y;
        T[kr + i*16][nc + 2] = v.z;
        T[kr + i*16][nc + 3] = v.w;
    }
    __syncthreads();
    int n  = tid >> 2;
    int kb = (tid & 3) * 16;
    unsigned short tmp[16];
    #pragma unroll
    for (int i = 0; i < 16; ++i) tmp[i] = f2bf(T[kb + i][n]);
    unsigned short* dst = Wt + (size_t)(n0 + n) * K + (k0 + kb);
    *(int4*)dst       = *(int4*)&tmp[0];
    *(int4*)(dst + 8) = *(int4*)&tmp[8];
}

// ---- K/V fragment-major pre-pass (see R8 notes) -----------------------------------
__global__ __launch_bounds__(256) void kvfrag_kernel(const unsigned short* __restrict__ qkv,
                                                     unsigned short* __restrict__ kfrag,
                                                     unsigned short* __restrict__ vfrag) {
    __shared__ unsigned short Kt[64][72];
    __shared__ unsigned short Vt[64][72];
    const int tid = threadIdx.x;
    const int j  = blockIdx.x;
    const int bh = blockIdx.y;
    const int b = bh >> 4, h = bh & 15;
    {
        const int r  = tid >> 2;
        const int c0 = (tid & 3) * 16;
        const unsigned short* src = qkv + ((size_t)(b * TSEQ + j * 64 + r)) * 3072 + 1024 + h * 64 + c0;
        bf16x8 k0 = *(const bf16x8*)src;
        bf16x8 k1 = *(const bf16x8*)(src + 8);
        bf16x8 v0 = *(const bf16x8*)(src + 1024);
        bf16x8 v1 = *(const bf16x8*)(src + 1032);
        *(bf16x8*)&Kt[r][c0]     = k0;
        *(bf16x8*)&Kt[r][c0 + 8] = k1;
        *(bf16x8*)&Vt[r][c0]     = v0;
        *(bf16x8*)&Vt[r][c0 + 8] = v1;
    }
    __syncthreads();
    const int l  = tid & 63;
    const int qd = tid >> 6;
    const size_t tbase = ((size_t)(bh * 32 + j)) * 8 * 512;
    #pragma unroll
    for (int pass = 0; pass < 2; ++pass) {
        const int kc = qd + pass * 4;
        const int sb = kc >> 1, g = kc & 1;
        bf16x8 kv = *(const bf16x8*)&Kt[sb * 16 + (l & 15)][g * 32 + (l >> 4) * 8];
        *(bf16x8*)(kfrag + tbase + kc * 512 + l * 8) = kv;

        const int vc = qd + pass * 4;
        const int kb = vc >> 2, db = vc & 3;
        unsigned short tmp[8];
        #pragma unroll
        for (int i = 0; i < 8; ++i)
            tmp[i] = Vt[kb * 32 + (l >> 4) * 8 + i][db * 16 + (l & 15)];
        *(bf16x8*)(vfrag + tbase + vc * 512 + l * 8) = *(bf16x8*)tmp;
    }
}

// ------------- MFMA GEMM (TN) 128x128 tile, BK=64, XOR swizzle, XCD-banded ---------
template<int EPI>
__global__ __launch_bounds__(256) void gemm_kernel(const unsigned short* __restrict__ A,
                                                   const unsigned short* __restrict__ Bt,
                                                   const float* __restrict__ bias,
                                                   const float* __restrict__ res,
                                                   void* __restrict__ Cout,
                                                   int M, int N, int K, int nbx, int rpx) {
    __shared__ __align__(16) unsigned short As[128 * 64];   // 16 KB
    __shared__ __align__(16) unsigned short Bs[128 * 64];   // 16 KB
    const int tid = threadIdx.x;
    const int l   = tid & 63;
    const int w   = tid >> 6;
    const int wr  = (w >> 1) * 64;
    const int wc  = (w & 1) * 64;
    const int lin = blockIdx.x;
    const int xcd = lin & 7;
    const int idx = lin >> 3;
    const long brow = (long)(xcd * rpx + idx / nbx) * 128;
    const long bcol = (long)(idx % nbx) * 128;

    const int srow = tid >> 3;                                  // 0..31
    const int schk = ((tid & 7) ^ (srow & 7)) * 8;              // global elem offset
    const unsigned short* gA = A  + (size_t)(brow + srow) * K + schk;
    const unsigned short* gB = Bt + (size_t)(bcol + srow) * K + schk;
    unsigned short* lA = As + tid * 8;
    unsigned short* lB = Bs + tid * 8;

    f32x4 acc[4][4];
    #pragma unroll
    for (int m = 0; m < 4; ++m)
        #pragma unroll
        for (int n = 0; n < 4; ++n) acc[m][n] = (f32x4){0.f, 0.f, 0.f, 0.f};

    for (int k0 = 0; k0 < K; k0 += 64) {
        #pragma unroll
        for (int p = 0; p < 4; ++p) {
            gload_lds16(gA + (size_t)(32 * p) * K + k0, lA + p * 2048);
            gload_lds16(gB + (size_t)(32 * p) * K + k0, lB + p * 2048);
        }
        __syncthreads();
        #pragma unroll
        for (int gg = 0; gg < 2; ++gg) {
            const int koff = ((gg * 4 + (l >> 4)) ^ (l & 7)) * 8;
            bf16x8 af[4], bf[4];
            #pragma unroll
            for (int m = 0; m < 4; ++m)
                af[m] = *(const bf16x8*)&As[(wr + m * 16 + (l & 15)) * 64 + koff];
            #pragma unroll
            for (int n = 0; n < 4; ++n)
                bf[n] = *(const bf16x8*)&Bs[(wc + n * 16 + (l & 15)) * 64 + koff];
            #pragma unroll
            for (int m = 0; m < 4; ++m)
                #pragma unroll
                for (int n = 0; n < 4; ++n)
                    acc[m][n] = __builtin_amdgcn_mfma_f32_16x16x32_bf16(af[m], bf[n], acc[m][n], 0, 0, 0);
        }
        __syncthreads();
    }

    #pragma unroll
    for (int m = 0; m < 4; ++m) {
        const int rown = wr + m * 16 + (l >> 4) * 4;
        #pragma unroll
        for (int n = 0; n < 4; ++n) {
            const long col = bcol + wc + n * 16 + (l & 15);
            const float bb = bias[col];
            #pragma unroll
            for (int r = 0; r < 4; ++r) {
                const long row = brow + rown + r;
                float v = acc[m][n][r] + bb;
                if (EPI == 1) {
                    v += res[row * N + col];
                    ((float*)Cout)[row * N + col] = v;
                } else if (EPI == 2) {
                    ((unsigned short*)Cout)[row * N + col] = f2bf(fast_gelu(v));
                } else {
                    ((unsigned short*)Cout)[row * N + col] = f2bf(v);
                }
            }
        }
    }
}

// ------ MFMA GEMM (TN) 64x128 tile, BK=64, XOR swizzle, XCD-banded, DOUBLE-BUFFERED
// 2-phase pipeline (T3-minimum): issue STAGE(t+1) BEFORE compute(t); ONE barrier/tile.
// LDS 48 KB (2 x 24); load latency overlaps ds_read+MFMA instead of preceding it.
template<int EPI>
__global__ __launch_bounds__(256) void gemm64_kernel(const unsigned short* __restrict__ A,
                                                     const unsigned short* __restrict__ Bt,
                                                     const float* __restrict__ bias,
                                                     const float* __restrict__ res,
                                                     void* __restrict__ Cout,
                                                     int M, int N, int K, int nbx, int rpx) {
    __shared__ __align__(16) unsigned short As[2][64 * 64];    // 2 x 8 KB
    __shared__ __align__(16) unsigned short Bs[2][128 * 64];   // 2 x 16 KB
    const int tid = threadIdx.x;
    const int l   = tid & 63;
    const int w   = tid >> 6;
    const int wr  = (w >> 1) * 32;
    const int wc  = (w & 1) * 64;
    const int lin = blockIdx.x;
    const int xcd = lin & 7;
    const int idx = lin >> 3;
    const long brow = (long)(xcd * rpx + idx / nbx) * 64;
    const long bcol = (long)(idx % nbx) * 128;

    const int srow = tid >> 3;                                  // 0..31
    const int schk = ((tid & 7) ^ (srow & 7)) * 8;
    const unsigned short* gA = A  + (size_t)(brow + srow) * K + schk;
    const unsigned short* gB = Bt + (size_t)(bcol + srow) * K + schk;

    f32x4 acc[2][4];
    #pragma unroll
    for (int m = 0; m < 2; ++m)
        #pragma unroll
        for (int n = 0; n < 4; ++n) acc[m][n] = (f32x4){0.f, 0.f, 0.f, 0.f};

    // prologue: stage tile 0 into buffer 0
    {
        unsigned short* lA = As[0] + tid * 8;
        unsigned short* lB = Bs[0] + tid * 8;
        #pragma unroll
        for (int p = 0; p < 2; ++p)
            gload_lds16(gA + (size_t)(32 * p) * K, lA + p * 2048);
        #pragma unroll
        for (int p = 0; p < 4; ++p)
            gload_lds16(gB + (size_t)(32 * p) * K, lB + p * 2048);
    }
    __syncthreads();

    int cur = 0;
    for (int k0 = 0; k0 < K; k0 += 64) {
        // issue next tile's loads FIRST (latency hides under this tile's compute)
        if (k0 + 64 < K) {
            unsigned short* lA = As[cur ^ 1] + tid * 8;
            unsigned short* lB = Bs[cur ^ 1] + tid * 8;
            #pragma unroll
            for (int p = 0; p < 2; ++p)
                gload_lds16(gA + (size_t)(32 * p) * K + k0 + 64, lA + p * 2048);
            #pragma unroll
            for (int p = 0; p < 4; ++p)
                gload_lds16(gB + (size_t)(32 * p) * K + k0 + 64, lB + p * 2048);
        }
        const unsigned short* cA = As[cur];
        const unsigned short* cB = Bs[cur];
        #pragma unroll
        for (int gg = 0; gg < 2; ++gg) {
            const int koff = ((gg * 4 + (l >> 4)) ^ (l & 7)) * 8;
            bf16x8 af[2], bf[4];
            #pragma unroll
            for (int m = 0; m < 2; ++m)
                af[m] = *(const bf16x8*)&cA[(wr + m * 16 + (l & 15)) * 64 + koff];
            #pragma unroll
            for (int n = 0; n < 4; ++n)
                bf[n] = *(const bf16x8*)&cB[(wc + n * 16 + (l & 15)) * 64 + koff];
            #pragma unroll
            for (int m = 0; m < 2; ++m)
                #pragma unroll
                for (int n = 0; n < 4; ++n)
                    acc[m][n] = __builtin_amdgcn_mfma_f32_16x16x32_bf16(af[m], bf[n], acc[m][n], 0, 0, 0);
        }
        __syncthreads();   // drains staged loads (overlapped w/ compute) + read-safety
        cur ^= 1;
    }

    #pragma unroll
    for (int m = 0; m < 2; ++m) {
        const int rown = wr + m * 16 + (l >> 4) * 4;
        #pragma unroll
        for (int n = 0; n < 4; ++n) {
            const long col = bcol + wc + n * 16 + (l & 15);
            const float bb = bias[col];
            #pragma unroll
            for (int r = 0; r < 4; ++r) {
                const long row = brow + rown + r;
                float v = acc[m][n][r] + bb;
                if (EPI == 1) {
                    v += res[row * N + col];
                    ((float*)Cout)[row * N + col] = v;
                } else if (EPI == 2) {
                    ((unsigned short*)Cout)[row * N + col] = f2bf(fast_gelu(v));
                } else {
                    ((unsigned short*)Cout)[row * N + col] = f2bf(v);
                }
            }
        }
    }
}

// ------------- MFMA causal flash attention (swapped QK^T, in-lane softmax) ----------
#define QSCALE 0.18033688011112042f   // 0.125 * log2(e)
__global__ __launch_bounds__(64) void attn_kernel(const unsigned short* __restrict__ qkv,
                                                  const unsigned short* __restrict__ kfrag,
                                                  const unsigned short* __restrict__ vfrag,
                                                  unsigned short* __restrict__ out) {
    __shared__ __align__(16) unsigned short Ps[16 * 128];   // [q][s], 16B-chunk swizzled

    const int l    = threadIdx.x;
    const int q    = l & 15;                   // lane's softmax row
    const int g    = l >> 4;                   // lane group 0..3
    const int lin  = blockIdx.x;
    const int xcd  = lin & 7;
    const int rest = lin >> 3;
    const int h    = xcd + 8 * (rest & 1);
    const int b    = (rest >> 1) & 1;
    const int strip = 127 - (rest >> 2);
    const int jmax  = strip >> 2;
    const size_t rowbase = (size_t)b * TSEQ;
    const int bh = b * NH + h;
    const int qglob = strip * 16 + q;

    const unsigned short* kfb = kfrag + (size_t)bh * 32 * 8 * 512;
    const unsigned short* vfb = vfrag + (size_t)bh * 32 * 8 * 512;

    // Q fragments (B operand: col=q, k-slice g*8), pre-scaled by 0.125*log2e
    bf16x8 aq0, aq1;
    {
        const unsigned short* qp = qkv + (rowbase + qglob) * 3072 + h * 64 + g * 8;
        bf16x8 t0 = *(const bf16x8*)qp;
        bf16x8 t1 = *(const bf16x8*)(qp + 32);
        #pragma unroll
        for (int i = 0; i < 8; ++i) {
            aq0[i] = (short)f2bf(bf2f((unsigned short)t0[i]) * QSCALE);
            aq1[i] = (short)f2bf(bf2f((unsigned short)t1[i]) * QSCALE);
        }
    }

    float mrow = -INFINITY, lrow = 0.f;
    f32x4 o[4];
    #pragma unroll
    for (int d = 0; d < 4; ++d) o[d] = (f32x4){0.f, 0.f, 0.f, 0.f};

    for (int j = 0; j + 1 <= jmax; j += 2) {
        const bool diag2 = (j + 1 == jmax);

        bf16x8 kf[16];
        #pragma unroll
        for (int t = 0; t < 2; ++t)
            #pragma unroll
            for (int sb = 0; sb < 4; ++sb) {
                const unsigned short* kp = kfb + (size_t)((j + t) * 8 + sb * 2) * 512 + l * 8;
                kf[t * 8 + sb * 2]     = *(const bf16x8*)kp;
                kf[t * 8 + sb * 2 + 1] = *(const bf16x8*)(kp + 512);
            }

        // S^T = K Q^T : lane holds q=l&15, s = t*64 + sb*16 + 4g + r
        f32x4 sf[8];
        __builtin_amdgcn_s_setprio(1);
        #pragma unroll
        for (int t = 0; t < 2; ++t)
            #pragma unroll
            for (int sb = 0; sb < 4; ++sb) {
                f32x4 acc = (f32x4){0.f, 0.f, 0.f, 0.f};
                acc = __builtin_amdgcn_mfma_f32_16x16x32_bf16(kf[t*8 + sb*2],     aq0, acc, 0, 0, 0);
                acc = __builtin_amdgcn_mfma_f32_16x16x32_bf16(kf[t*8 + sb*2 + 1], aq1, acc, 0, 0, 0);
                sf[t*4 + sb] = acc;
            }
        __builtin_amdgcn_s_setprio(0);

        bf16x8 vf[16];
        #pragma unroll
        for (int kb = 0; kb < 4; ++kb)
            #pragma unroll
            for (int db = 0; db < 4; ++db)
                vf[kb * 4 + db] = *(const bf16x8*)(vfb + (size_t)((j + (kb >> 1)) * 8 + (kb & 1) * 4 + db) * 512 + l * 8);

        if (diag2) {
            #pragma unroll
            for (int sb = 0; sb < 4; ++sb) {
                const int sg = (j + 1) * 64 + sb * 16 + 4 * g;
                #pragma unroll
                for (int r = 0; r < 4; ++r)
                    if (sg + r > qglob) sf[4 + sb][r] = -INFINITY;
            }
        }

        // in-lane max over 32 + merge across the 4 groups
        f32x4 mv = sf[0];
        #pragma unroll
        for (int i = 1; i < 8; ++i)
            #pragma unroll
            for (int r = 0; r < 4; ++r) mv[r] = fmaxf(mv[r], sf[i][r]);
        float mloc = fmaxf(fmaxf(mv[0], mv[1]), fmaxf(mv[2], mv[3]));
        mloc = fmaxf(mloc, __shfl_xor(mloc, 16));
        mloc = fmaxf(mloc, __shfl_xor(mloc, 32));
        const float mn = fmaxf(mrow, mloc);
        const float alpha = exp2f(mrow - mn);
        mrow = mn;

        float psum = 0.f;
        #pragma unroll
        for (int i = 0; i < 8; ++i) {
            const int t = i >> 2, sb = i & 3;
            float p0 = exp2f(sf[i][0] - mn);
            float p1 = exp2f(sf[i][1] - mn);
            float p2 = exp2f(sf[i][2] - mn);
            float p3 = exp2f(sf[i][3] - mn);
            psum += (p0 + p1) + (p2 + p3);
            unsigned int pk0 = cvt_pk_bf16(p0, p1);
            unsigned int pk1 = cvt_pk_bf16(p2, p3);
            const int c16 = (t * 8 + sb * 2 + (g >> 1)) ^ (q & 7);
            *(uint2*)((char*)Ps + q * 256 + c16 * 16 + (g & 1) * 8) = make_uint2(pk0, pk1);
        }
        psum += __shfl_xor(psum, 16);
        psum += __shfl_xor(psum, 32);
        lrow = lrow * alpha + psum;

        float al[4];
        #pragma unroll
        for (int r = 0; r < 4; ++r) al[r] = __shfl(alpha, g * 4 + r);
        #pragma unroll
        for (int d = 0; d < 4; ++d)
            #pragma unroll
            for (int r = 0; r < 4; ++r) o[d][r] *= al[r];

        // O += P V  (pa: row=q, s-slice = kb*32 + g*8; lgkmcnt orders write->read)
        __builtin_amdgcn_s_setprio(1);
        #pragma unroll
        for (int kb = 0; kb < 4; ++kb) {
            const int c16 = (kb * 4 + g) ^ (q & 7);
            bf16x8 pa = *(const bf16x8*)((const char*)Ps + q * 256 + c16 * 16);
            #pragma unroll
            for (int db = 0; db < 4; ++db)
                o[db] = __builtin_amdgcn_mfma_f32_16x16x32_bf16(pa, vf[kb * 4 + db], o[db], 0, 0, 0);
        }
        __builtin_amdgcn_s_setprio(0);
    }

    if ((jmax & 1) == 0) {
        const int j = jmax;
        bf16x8 kf[8];
        #pragma unroll
        for (int sb = 0; sb < 4; ++sb) {
            const unsigned short* kp = kfb + (size_t)(j * 8 + sb * 2) * 512 + l * 8;
            kf[sb * 2]     = *(const bf16x8*)kp;
            kf[sb * 2 + 1] = *(const bf16x8*)(kp + 512);
        }
        f32x4 sf[4];
        __builtin_amdgcn_s_setprio(1);
        #pragma unroll
        for (int sb = 0; sb < 4; ++sb) {
            f32x4 acc = (f32x4){0.f, 0.f, 0.f, 0.f};
            acc = __builtin_amdgcn_mfma_f32_16x16x32_bf16(kf[sb*2],     aq0, acc, 0, 0, 0);
            acc = __builtin_amdgcn_mfma_f32_16x16x32_bf16(kf[sb*2 + 1], aq1, acc, 0, 0, 0);
            sf[sb] = acc;
        }
        __builtin_amdgcn_s_setprio(0);

        bf16x8 vf[8];
        #pragma unroll
        for (int kb = 0; kb < 2; ++kb)
            #pragma unroll
            for (int db = 0; db < 4; ++db)
                vf[kb * 4 + db] = *(const bf16x8*)(vfb + (size_t)(j * 8 + kb * 4 + db) * 512 + l * 8);

        #pragma unroll
        for (int sb = 0; sb < 4; ++sb) {
            const int sg = j * 64 + sb * 16 + 4 * g;
            #pragma unroll
            for (int r = 0; r < 4; ++r)
                if (sg + r > qglob) sf[sb][r] = -INFINITY;
        }

        f32x4 mv = sf[0];
        #pragma unroll
        for (int i = 1; i < 4; ++i)
            #pragma unroll
            for (int r = 0; r < 4; ++r) mv[r] = fmaxf(mv[r], sf[i][r]);
        float mloc = fmaxf(fmaxf(mv[0], mv[1]), fmaxf(mv[2], mv[3]));
        mloc = fmaxf(mloc, __shfl_xor(mloc, 16));
        mloc = fmaxf(mloc, __shfl_xor(mloc, 32));
        const float mn = fmaxf(mrow, mloc);
        const float alpha = exp2f(mrow - mn);
        mrow = mn;

        float psum = 0.f;
        #pragma unroll
        for (int sb = 0; sb < 4; ++sb) {
            float p0 = exp2f(sf[sb][0] - mn);
            float p1 = exp2f(sf[sb][1] - mn);
            float p2 = exp2f(sf[sb][2] - mn);
            float p3 = exp2f(sf[sb][3] - mn);
            psum += (p0 + p1) + (p2 + p3);
            unsigned int pk0 = cvt_pk_bf16(p0, p1);
            unsigned int pk1 = cvt_pk_bf16(p2, p3);
            const int c16 = (sb * 2 + (g >> 1)) ^ (q & 7);
            *(uint2*)((char*)Ps + q * 256 + c16 * 16 + (g & 1) * 8) = make_uint2(pk0, pk1);
        }
        psum += __shfl_xor(psum, 16);
        psum += __shfl_xor(psum, 32);
        lrow = lrow * alpha + psum;

        float al[4];
        #pragma unroll
        for (int r = 0; r < 4; ++r) al[r] = __shfl(alpha, g * 4 + r);
        #pragma unroll
        for (int d = 0; d < 4; ++d)
            #pragma unroll
            for (int r = 0; r < 4; ++r) o[d][r] *= al[r];

        __builtin_amdgcn_s_setprio(1);
        #pragma unroll
        for (int kb = 0; kb < 2; ++kb) {
            const int c16 = (kb * 4 + g) ^ (q & 7);
            bf16x8 pa = *(const bf16x8*)((const char*)Ps + q * 256 + c16 * 16);
            #pragma unroll
            for (int db = 0; db < 4; ++db)
                o[db] = __builtin_amdgcn_mfma_f32_16x16x32_bf16(pa, vf[kb * 4 + db], o[db], 0, 0, 0);
        }
        __builtin_amdgcn_s_setprio(0);
    }

    // epilogue: O rows = g*4+r, cols = q + db*16
    float linv[4];
    #pragma unroll
    for (int r = 0; r < 4; ++r) linv[r] = 1.0f / __shfl(lrow, g * 4 + r);
    #pragma unroll
    for (int r = 0; r < 4; ++r) {
        const size_t rb = (rowbase + strip * 16 + g * 4 + r) * (size_t)CDIM + h * 64 + q;
        #pragma unroll
        for (int d = 0; d < 4; ++d)
            out[rb + d * 16] = f2bf(o[d][r] * linv[r]);
    }
}

extern "C" void kernel_launch(void* const* d_in, const int* in_sizes, int n_in,
                              void* d_out, int out_size, void* d_ws, size_t ws_size,
                              hipStream_t stream) {
    const float* x     = (const float*)d_in[0];
    const float* ln1_g = (const float*)d_in[1];
    const float* ln1_b = (const float*)d_in[2];
    const float* w_qkv = (const float*)d_in[3];
    const float* b_qkv = (const float*)d_in[4];
    const float* w_out = (const float*)d_in[5];
    const float* b_out = (const float*)d_in[6];
    const float* ln2_g = (const float*)d_in[7];
    const float* ln2_b = (const float*)d_in[8];
    const float* w_ff1 = (const float*)d_in[9];
    const float* b_ff1 = (const float*)d_in[10];
    const float* w_ff2 = (const float*)d_in[11];
    const float* b_ff2 = (const float*)d_in[12];
    float* out = (float*)d_out;

    char* wsb = (char*)d_ws;
    unsigned short* h_bf    = (unsigned short*)(wsb);                          // 8 MB
    unsigned short* qkv_bf  = (unsigned short*)(wsb + 8ll  * 1024 * 1024);     // 24 MB
    unsigned short* attn_bf = (unsigned short*)(wsb + 32ll * 1024 * 1024);     // 8 MB
    float*          x1      = (float*)         (wsb + 40ll * 1024 * 1024);     // 16 MB
    unsigned short* kfrag   = (unsigned short*)(wsb + 40ll * 1024 * 1024);     // 8 MB (overlays x1, dead until step 4)
    unsigned short* vfrag   = (unsigned short*)(wsb + 48ll * 1024 * 1024);     // 8 MB (overlays x1, dead until step 4)
    unsigned short* wqkvT   = (unsigned short*)(wsb + 56ll * 1024 * 1024);     // 6 MB
    unsigned short* woutT   = (unsigned short*)(wsb + 62ll * 1024 * 1024);     // 2 MB
    unsigned short* wff1T   = (unsigned short*)(wsb + 64ll * 1024 * 1024);     // 8 MB
    unsigned short* wff2T   = (unsigned short*)(wsb + 72ll * 1024 * 1024);     // 8 MB
    unsigned short* ff1_bf  = (unsigned short*)(wsb + 8ll  * 1024 * 1024);     // 32 MB, overlays dead qkv+attn

    transpose_cast_kernel<<<dim3(48, 16), 256, 0, stream>>>(w_qkv, wqkvT, 1024, 3072);
    transpose_cast_kernel<<<dim3(16, 16), 256, 0, stream>>>(w_out, woutT, 1024, 1024);
    transpose_cast_kernel<<<dim3(64, 16), 256, 0, stream>>>(w_ff1, wff1T, 1024, 4096);
    transpose_cast_kernel<<<dim3(16, 64), 256, 0, stream>>>(w_ff2, wff2T, 4096, 1024);

    // 1. LN1 -> bf16
    ln_kernel<<<ROWS, 256, 0, stream>>>(x, ln1_g, ln1_b, h_bf);
    // 2. qkv = h @ w_qkv + b  -> bf16   (768 blocks: nbx=24, 4 row-panels/XCD)
    gemm_kernel<0><<<768, 256, 0, stream>>>(h_bf, wqkvT, b_qkv, nullptr, qkv_bf, ROWS, 3072, 1024, 24, 4);
    // 2b. K/V fragment-major pre-pass
    kvfrag_kernel<<<dim3(32, 32), 256, 0, stream>>>(qkv_bf, kfrag, vfrag);
    // 3. causal flash attention -> bf16 (swapped QK^T, in-lane softmax)
    attn_kernel<<<4096, 64, 0, stream>>>(qkv_bf, kfrag, vfrag, attn_bf);
    // 4. x1 = x + attn @ w_out + b  -> f32   (512 blocks: nbx=8, 8 row-panels/XCD)
    gemm64_kernel<1><<<512, 256, 0, stream>>>(attn_bf, woutT, b_out, x, x1, ROWS, 1024, 1024, 8, 8);
    // 5. LN2 -> bf16
    ln_kernel<<<ROWS, 256, 0, stream>>>(x1, ln2_g, ln2_b, h_bf);
    // 6. ff1 = gelu(h @ w_ff1 + b)  -> bf16   (1024 blocks: nbx=32, 4 row-panels/XCD)
    gemm_kernel<2><<<1024, 256, 0, stream>>>(h_bf, wff1T, b_ff1, nullptr, ff1_bf, ROWS, 4096, 1024, 32, 4);
    // 7. out = x1 + ff1 @ w_ff2 + b  -> f32   (512 blocks: nbx=8, 8 row-panels/XCD)
    gemm64_kernel<1><<<512, 256, 0, stream>>>(ff1_bf, wff2T, b_ff2, x1, (float*)out, ROWS, 1024, 4096, 8, 8);
}

// Round 14
// 254.532 us; speedup vs baseline: 1.5184x; 1.0459x over previous
//
#include <hip/hip_runtime.h>
#include <hip/hip_bf16.h>
#include <math.h>

#define TSEQ 2048
#define BATCH 2
#define CDIM 1024
#define NH 16
#define HD 64
#define DFF 4096
#define ROWS (BATCH*TSEQ)   // 4096

typedef __attribute__((ext_vector_type(4))) float f32x4;
typedef __attribute__((ext_vector_type(8))) short bf16x8;   // 8 bf16 in 4 VGPRs
typedef __attribute__((ext_vector_type(4))) unsigned short u16x4;

__device__ __forceinline__ void gload_lds16(const void* g, void* l) {
    void* gv = const_cast<void*>(g);
    __builtin_amdgcn_global_load_lds((__attribute__((address_space(1))) void*)gv,
                                     (__attribute__((address_space(3))) void*)l, 16, 0, 0);
}

__device__ __forceinline__ unsigned short f2bf(float f) {
    unsigned int u = __float_as_uint(f);
    return (unsigned short)((u + 0x7FFFu + ((u >> 16) & 1u)) >> 16);
}
__device__ __forceinline__ float bf2f(unsigned short u) {
    return __uint_as_float((unsigned int)u << 16);
}
// packed f32x2 -> bf16x2 (low half = first arg); no builtin on gfx950 (T12)
__device__ __forceinline__ unsigned int cvt_pk_bf16(float lo, float hi) {
    unsigned int r;
    asm("v_cvt_pk_bf16_f32 %0, %1, %2" : "=v"(r) : "v"(lo), "v"(hi));
    return r;
}
// tanh-form GELU: v * sigmoid(1.59577*(v + 0.044715 v^3)); |err vs exact| < ~3e-4
__device__ __forceinline__ float fast_gelu(float v) {
    float u = fmaf(0.044715f * v * v, v, v);
    float e = __expf(-1.5957691216057308f * u);
    return v * __builtin_amdgcn_rcpf(1.0f + e);
}

// ------------------------------- LayerNorm -> bf16 --------------------------------
__global__ __launch_bounds__(256) void ln_kernel(const float* __restrict__ x,
                                                 const float* __restrict__ g,
                                                 const float* __restrict__ b,
                                                 unsigned short* __restrict__ out) {
    int row = blockIdx.x;
    int tid = threadIdx.x;
    const float* xr = x + (size_t)row * CDIM;
    float4 v = *(const float4*)(xr + tid * 4);
    float s  = v.x + v.y + v.z + v.w;
    float s2 = v.x*v.x + v.y*v.y + v.z*v.z + v.w*v.w;
    #pragma unroll
    for (int off = 32; off >= 1; off >>= 1) {
        s  += __shfl_down(s, off);
        s2 += __shfl_down(s2, off);
    }
    __shared__ float red[8];
    int wid = tid >> 6, lane = tid & 63;
    if (lane == 0) { red[wid] = s; red[wid + 4] = s2; }
    __syncthreads();
    float ts  = red[0] + red[1] + red[2] + red[3];
    float ts2 = red[4] + red[5] + red[6] + red[7];
    float mu  = ts * (1.0f / CDIM);
    float var = ts2 * (1.0f / CDIM) - mu * mu;
    float rstd = rsqrtf(var + 1e-5f);
    float4 gv = *(const float4*)(g + tid * 4);
    float4 bv = *(const float4*)(b + tid * 4);
    unsigned short o4[4];
    o4[0] = f2bf((v.x - mu) * rstd * gv.x + bv.x);
    o4[1] = f2bf((v.y - mu) * rstd * gv.y + bv.y);
    o4[2] = f2bf((v.z - mu) * rstd * gv.z + bv.z);
    o4[3] = f2bf((v.w - mu) * rstd * gv.w + bv.w);
    *(u16x4*)(out + (size_t)row * CDIM + tid * 4) = *(u16x4*)o4;
}

// --------------------- transpose + cast: W[K][N] f32 -> Wt[N][K] bf16 ---------------
__global__ __launch_bounds__(256) void transpose_cast_kernel(const float* __restrict__ W,
                                                             unsigned short* __restrict__ Wt,
                                                             int K, int N) {
    __shared__ float T[64][65];
    int tid = threadIdx.x;
    int n0 = blockIdx.x * 64, k0 = blockIdx.y * 64;
    int kr = tid >> 4;
    int nc = (tid & 15) * 4;
    #pragma unroll
    for (int i = 0; i < 4; ++i) {
        float4 v = *(const float4*)&W[(size_t)(k0 + kr + i*16) * N + (n0 + nc)];
        T[kr + i*16][nc + 0] = v.x;
        T[kr + i*16][nc + 1] = v.y;
        T[kr + i*16][nc + 2] = v.z;
        T[kr + i*16][nc + 3] = v.w;
    }
    __syncthreads();
    int n  = tid >> 2;
    int kb = (tid & 3) * 16;
    unsigned short tmp[16];
    #pragma unroll
    for (int i = 0; i < 16; ++i) tmp[i] = f2bf(T[kb + i][n]);
    unsigned short* dst = Wt + (size_t)(n0 + n) * K + (k0 + kb);
    *(int4*)dst       = *(int4*)&tmp[0];
    *(int4*)(dst + 8) = *(int4*)&tmp[8];
}

// ---- K/V fragment-major pre-pass (see R8 notes) -----------------------------------
__global__ __launch_bounds__(256) void kvfrag_kernel(const unsigned short* __restrict__ qkv,
                                                     unsigned short* __restrict__ kfrag,
                                                     unsigned short* __restrict__ vfrag) {
    __shared__ unsigned short Kt[64][72];
    __shared__ unsigned short Vt[64][72];
    const int tid = threadIdx.x;
    const int j  = blockIdx.x;
    const int bh = blockIdx.y;
    const int b = bh >> 4, h = bh & 15;
    {
        const int r  = tid >> 2;
        const int c0 = (tid & 3) * 16;
        const unsigned short* src = qkv + ((size_t)(b * TSEQ + j * 64 + r)) * 3072 + 1024 + h * 64 + c0;
        bf16x8 k0 = *(const bf16x8*)src;
        bf16x8 k1 = *(const bf16x8*)(src + 8);
        bf16x8 v0 = *(const bf16x8*)(src + 1024);
        bf16x8 v1 = *(const bf16x8*)(src + 1032);
        *(bf16x8*)&Kt[r][c0]     = k0;
        *(bf16x8*)&Kt[r][c0 + 8] = k1;
        *(bf16x8*)&Vt[r][c0]     = v0;
        *(bf16x8*)&Vt[r][c0 + 8] = v1;
    }
    __syncthreads();
    const int l  = tid & 63;
    const int qd = tid >> 6;
    const size_t tbase = ((size_t)(bh * 32 + j)) * 8 * 512;
    #pragma unroll
    for (int pass = 0; pass < 2; ++pass) {
        const int kc = qd + pass * 4;
        const int sb = kc >> 1, g = kc & 1;
        bf16x8 kv = *(const bf16x8*)&Kt[sb * 16 + (l & 15)][g * 32 + (l >> 4) * 8];
        *(bf16x8*)(kfrag + tbase + kc * 512 + l * 8) = kv;

        const int vc = qd + pass * 4;
        const int kb = vc >> 2, db = vc & 3;
        unsigned short tmp[8];
        #pragma unroll
        for (int i = 0; i < 8; ++i)
            tmp[i] = Vt[kb * 32 + (l >> 4) * 8 + i][db * 16 + (l & 15)];
        *(bf16x8*)(vfrag + tbase + vc * 512 + l * 8) = *(bf16x8*)tmp;
    }
}

// ------------- MFMA GEMM (TN) 128x128 tile, BK=64, XOR swizzle, XCD-banded ---------
template<int EPI>
__global__ __launch_bounds__(256) void gemm_kernel(const unsigned short* __restrict__ A,
                                                   const unsigned short* __restrict__ Bt,
                                                   const float* __restrict__ bias,
                                                   const float* __restrict__ res,
                                                   void* __restrict__ Cout,
                                                   int M, int N, int K, int nbx, int rpx) {
    __shared__ __align__(16) unsigned short As[128 * 64];   // 16 KB
    __shared__ __align__(16) unsigned short Bs[128 * 64];   // 16 KB
    const int tid = threadIdx.x;
    const int l   = tid & 63;
    const int w   = tid >> 6;
    const int wr  = (w >> 1) * 64;
    const int wc  = (w & 1) * 64;
    const int lin = blockIdx.x;
    const int xcd = lin & 7;
    const int idx = lin >> 3;
    const long brow = (long)(xcd * rpx + idx / nbx) * 128;
    const long bcol = (long)(idx % nbx) * 128;

    const int srow = tid >> 3;                                  // 0..31
    const int schk = ((tid & 7) ^ (srow & 7)) * 8;              // global elem offset
    const unsigned short* gA = A  + (size_t)(brow + srow) * K + schk;
    const unsigned short* gB = Bt + (size_t)(bcol + srow) * K + schk;
    unsigned short* lA = As + tid * 8;
    unsigned short* lB = Bs + tid * 8;

    f32x4 acc[4][4];
    #pragma unroll
    for (int m = 0; m < 4; ++m)
        #pragma unroll
        for (int n = 0; n < 4; ++n) acc[m][n] = (f32x4){0.f, 0.f, 0.f, 0.f};

    for (int k0 = 0; k0 < K; k0 += 64) {
        #pragma unroll
        for (int p = 0; p < 4; ++p) {
            gload_lds16(gA + (size_t)(32 * p) * K + k0, lA + p * 2048);
            gload_lds16(gB + (size_t)(32 * p) * K + k0, lB + p * 2048);
        }
        __syncthreads();
        #pragma unroll
        for (int gg = 0; gg < 2; ++gg) {
            const int koff = ((gg * 4 + (l >> 4)) ^ (l & 7)) * 8;
            bf16x8 af[4], bf[4];
            #pragma unroll
            for (int m = 0; m < 4; ++m)
                af[m] = *(const bf16x8*)&As[(wr + m * 16 + (l & 15)) * 64 + koff];
            #pragma unroll
            for (int n = 0; n < 4; ++n)
                bf[n] = *(const bf16x8*)&Bs[(wc + n * 16 + (l & 15)) * 64 + koff];
            #pragma unroll
            for (int m = 0; m < 4; ++m)
                #pragma unroll
                for (int n = 0; n < 4; ++n)
                    acc[m][n] = __builtin_amdgcn_mfma_f32_16x16x32_bf16(af[m], bf[n], acc[m][n], 0, 0, 0);
        }
        __syncthreads();
    }

    #pragma unroll
    for (int m = 0; m < 4; ++m) {
        const int rown = wr + m * 16 + (l >> 4) * 4;
        #pragma unroll
        for (int n = 0; n < 4; ++n) {
            const long col = bcol + wc + n * 16 + (l & 15);
            const float bb = bias[col];
            #pragma unroll
            for (int r = 0; r < 4; ++r) {
                const long row = brow + rown + r;
                float v = acc[m][n][r] + bb;
                if (EPI == 1) {
                    v += res[row * N + col];
                    ((float*)Cout)[row * N + col] = v;
                } else if (EPI == 2) {
                    ((unsigned short*)Cout)[row * N + col] = f2bf(fast_gelu(v));
                } else {
                    ((unsigned short*)Cout)[row * N + col] = f2bf(v);
                }
            }
        }
    }
}

// ------ MFMA GEMM (TN) 64x128 tile, BK=64, XOR swizzle, XCD-banded, 3-DEEP PIPELINE
// Counted vmcnt (T4): 6 prefetch loads stay in flight ACROSS the barrier; never
// drained to 0 in steady state. Schedule per tile t:
//   { vmcnt(6|0); s_barrier; compute buf[t%3]; stage(t+2 -> buf[(t+2)%3]) }
// Safety: buf[(t+2)%3] last read at compute(t-1), all waves passed barrier(t) before
// the stage issues (WAR ok); tile t's loads are the 6 oldest outstanding -> vmcnt(6)
// retires them before the barrier (RAW ok). LDS 72 KB -> 2 blocks/CU (144 < 160 KB).
template<int EPI>
__global__ __launch_bounds__(256) void gemm64_kernel(const unsigned short* __restrict__ A,
                                                     const unsigned short* __restrict__ Bt,
                                                     const float* __restrict__ bias,
                                                     const float* __restrict__ res,
                                                     void* __restrict__ Cout,
                                                     int M, int N, int K, int nbx, int rpx) {
    __shared__ __align__(16) unsigned short As[3 * 64 * 64];    // 3 x 8 KB
    __shared__ __align__(16) unsigned short Bs[3 * 128 * 64];   // 3 x 16 KB
    const int tid = threadIdx.x;
    const int l   = tid & 63;
    const int w   = tid >> 6;
    const int wr  = (w >> 1) * 32;
    const int wc  = (w & 1) * 64;
    const int lin = blockIdx.x;
    const int xcd = lin & 7;
    const int idx = lin >> 3;
    const long brow = (long)(xcd * rpx + idx / nbx) * 64;
    const long bcol = (long)(idx % nbx) * 128;

    const int srow = tid >> 3;                                  // 0..31
    const int schk = ((tid & 7) ^ (srow & 7)) * 8;
    const unsigned short* gA = A  + (size_t)(brow + srow) * K + schk;
    const unsigned short* gB = Bt + (size_t)(bcol + srow) * K + schk;

    f32x4 acc[2][4];
    #pragma unroll
    for (int m = 0; m < 2; ++m)
        #pragma unroll
        for (int n = 0; n < 4; ++n) acc[m][n] = (f32x4){0.f, 0.f, 0.f, 0.f};

    // 6 loads per stage: 2 A-chunks + 4 B-chunks
    #define STAGE64(buf, koff_)                                                        \
        do {                                                                           \
            unsigned short* lA_ = As + (buf) * 4096 + tid * 8;                         \
            unsigned short* lB_ = Bs + (buf) * 8192 + tid * 8;                         \
            _Pragma("unroll")                                                          \
            for (int p = 0; p < 2; ++p)                                                \
                gload_lds16(gA + (size_t)(32 * p) * K + (koff_), lA_ + p * 2048);      \
            _Pragma("unroll")                                                          \
            for (int p = 0; p < 4; ++p)                                                \
                gload_lds16(gB + (size_t)(32 * p) * K + (koff_), lB_ + p * 2048);      \
        } while (0)

    // prologue: tiles 0 and 1 in flight (12 loads)
    STAGE64(0, 0);
    STAGE64(1, 64);

    int cur = 0;
    for (int k0 = 0; k0 < K; k0 += 64) {
        if (k0 + 64 < K) asm volatile("s_waitcnt vmcnt(6)" ::: "memory");
        else             asm volatile("s_waitcnt vmcnt(0)" ::: "memory");
        __builtin_amdgcn_s_barrier();
        asm volatile("" ::: "memory");   // fence: no LDS read hoists above the barrier

        const unsigned short* cA = As + cur * 4096;
        const unsigned short* cB = Bs + cur * 8192;
        #pragma unroll
        for (int gg = 0; gg < 2; ++gg) {
            const int koff = ((gg * 4 + (l >> 4)) ^ (l & 7)) * 8;
            bf16x8 af[2], bf[4];
            #pragma unroll
            for (int m = 0; m < 2; ++m)
                af[m] = *(const bf16x8*)&cA[(wr + m * 16 + (l & 15)) * 64 + koff];
            #pragma unroll
            for (int n = 0; n < 4; ++n)
                bf[n] = *(const bf16x8*)&cB[(wc + n * 16 + (l & 15)) * 64 + koff];
            #pragma unroll
            for (int m = 0; m < 2; ++m)
                #pragma unroll
                for (int n = 0; n < 4; ++n)
                    acc[m][n] = __builtin_amdgcn_mfma_f32_16x16x32_bf16(af[m], bf[n], acc[m][n], 0, 0, 0);
        }

        // stage tile t+2 (issued after this wave passed barrier(t) -> WAR-safe)
        if (k0 + 128 < K) {
            int nxt = cur + 2; if (nxt >= 3) nxt -= 3;
            STAGE64(nxt, k0 + 128);
        }
        cur = cur + 1; if (cur == 3) cur = 0;
    }
    #undef STAGE64

    #pragma unroll
    for (int m = 0; m < 2; ++m) {
        const int rown = wr + m * 16 + (l >> 4) * 4;
        #pragma unroll
        for (int n = 0; n < 4; ++n) {
            const long col = bcol + wc + n * 16 + (l & 15);
            const float bb = bias[col];
            #pragma unroll
            for (int r = 0; r < 4; ++r) {
                const long row = brow + rown + r;
                float v = acc[m][n][r] + bb;
                if (EPI == 1) {
                    v += res[row * N + col];
                    ((float*)Cout)[row * N + col] = v;
                } else if (EPI == 2) {
                    ((unsigned short*)Cout)[row * N + col] = f2bf(fast_gelu(v));
                } else {
                    ((unsigned short*)Cout)[row * N + col] = f2bf(v);
                }
            }
        }
    }
}

// ------------- MFMA causal flash attention (swapped QK^T, in-lane softmax) ----------
#define QSCALE 0.18033688011112042f   // 0.125 * log2(e)
__global__ __launch_bounds__(64) void attn_kernel(const unsigned short* __restrict__ qkv,
                                                  const unsigned short* __restrict__ kfrag,
                                                  const unsigned short* __restrict__ vfrag,
                                                  unsigned short* __restrict__ out) {
    __shared__ __align__(16) unsigned short Ps[16 * 128];   // [q][s], 16B-chunk swizzled

    const int l    = threadIdx.x;
    const int q    = l & 15;                   // lane's softmax row
    const int g    = l >> 4;                   // lane group 0..3
    const int lin  = blockIdx.x;
    const int xcd  = lin & 7;
    const int rest = lin >> 3;
    const int h    = xcd + 8 * (rest & 1);
    const int b    = (rest >> 1) & 1;
    const int strip = 127 - (rest >> 2);
    const int jmax  = strip >> 2;
    const size_t rowbase = (size_t)b * TSEQ;
    const int bh = b * NH + h;
    const int qglob = strip * 16 + q;

    const unsigned short* kfb = kfrag + (size_t)bh * 32 * 8 * 512;
    const unsigned short* vfb = vfrag + (size_t)bh * 32 * 8 * 512;

    // Q fragments (B operand: col=q, k-slice g*8), pre-scaled by 0.125*log2e
    bf16x8 aq0, aq1;
    {
        const unsigned short* qp = qkv + (rowbase + qglob) * 3072 + h * 64 + g * 8;
        bf16x8 t0 = *(const bf16x8*)qp;
        bf16x8 t1 = *(const bf16x8*)(qp + 32);
        #pragma unroll
        for (int i = 0; i < 8; ++i) {
            aq0[i] = (short)f2bf(bf2f((unsigned short)t0[i]) * QSCALE);
            aq1[i] = (short)f2bf(bf2f((unsigned short)t1[i]) * QSCALE);
        }
    }

    float mrow = -INFINITY, lrow = 0.f;
    f32x4 o[4];
    #pragma unroll
    for (int d = 0; d < 4; ++d) o[d] = (f32x4){0.f, 0.f, 0.f, 0.f};

    for (int j = 0; j + 1 <= jmax; j += 2) {
        const bool diag2 = (j + 1 == jmax);

        bf16x8 kf[16];
        #pragma unroll
        for (int t = 0; t < 2; ++t)
            #pragma unroll
            for (int sb = 0; sb < 4; ++sb) {
                const unsigned short* kp = kfb + (size_t)((j + t) * 8 + sb * 2) * 512 + l * 8;
                kf[t * 8 + sb * 2]     = *(const bf16x8*)kp;
                kf[t * 8 + sb * 2 + 1] = *(const bf16x8*)(kp + 512);
            }

        // S^T = K Q^T : lane holds q=l&15, s = t*64 + sb*16 + 4g + r
        f32x4 sf[8];
        __builtin_amdgcn_s_setprio(1);
        #pragma unroll
        for (int t = 0; t < 2; ++t)
            #pragma unroll
            for (int sb = 0; sb < 4; ++sb) {
                f32x4 acc = (f32x4){0.f, 0.f, 0.f, 0.f};
                acc = __builtin_amdgcn_mfma_f32_16x16x32_bf16(kf[t*8 + sb*2],     aq0, acc, 0, 0, 0);
                acc = __builtin_amdgcn_mfma_f32_16x16x32_bf16(kf[t*8 + sb*2 + 1], aq1, acc, 0, 0, 0);
                sf[t*4 + sb] = acc;
            }
        __builtin_amdgcn_s_setprio(0);

        bf16x8 vf[16];
        #pragma unroll
        for (int kb = 0; kb < 4; ++kb)
            #pragma unroll
            for (int db = 0; db < 4; ++db)
                vf[kb * 4 + db] = *(const bf16x8*)(vfb + (size_t)((j + (kb >> 1)) * 8 + (kb & 1) * 4 + db) * 512 + l * 8);

        if (diag2) {
            #pragma unroll
            for (int sb = 0; sb < 4; ++sb) {
                const int sg = (j + 1) * 64 + sb * 16 + 4 * g;
                #pragma unroll
                for (int r = 0; r < 4; ++r)
                    if (sg + r > qglob) sf[4 + sb][r] = -INFINITY;
            }
        }

        // in-lane max over 32 + merge across the 4 groups
        f32x4 mv = sf[0];
        #pragma unroll
        for (int i = 1; i < 8; ++i)
            #pragma unroll
            for (int r = 0; r < 4; ++r) mv[r] = fmaxf(mv[r], sf[i][r]);
        float mloc = fmaxf(fmaxf(mv[0], mv[1]), fmaxf(mv[2], mv[3]));
        mloc = fmaxf(mloc, __shfl_xor(mloc, 16));
        mloc = fmaxf(mloc, __shfl_xor(mloc, 32));
        const float mn = fmaxf(mrow, mloc);
        const float alpha = exp2f(mrow - mn);
        mrow = mn;

        float psum = 0.f;
        #pragma unroll
        for (int i = 0; i < 8; ++i) {
            const int t = i >> 2, sb = i & 3;
            float p0 = exp2f(sf[i][0] - mn);
            float p1 = exp2f(sf[i][1] - mn);
            float p2 = exp2f(sf[i][2] - mn);
            float p3 = exp2f(sf[i][3] - mn);
            psum += (p0 + p1) + (p2 + p3);
            unsigned int pk0 = cvt_pk_bf16(p0, p1);
            unsigned int pk1 = cvt_pk_bf16(p2, p3);
            const int c16 = (t * 8 + sb * 2 + (g >> 1)) ^ (q & 7);
            *(uint2*)((char*)Ps + q * 256 + c16 * 16 + (g & 1) * 8) = make_uint2(pk0, pk1);
        }
        psum += __shfl_xor(psum, 16);
        psum += __shfl_xor(psum, 32);
        lrow = lrow * alpha + psum;

        float al[4];
        #pragma unroll
        for (int r = 0; r < 4; ++r) al[r] = __shfl(alpha, g * 4 + r);
        #pragma unroll
        for (int d = 0; d < 4; ++d)
            #pragma unroll
            for (int r = 0; r < 4; ++r) o[d][r] *= al[r];

        // O += P V  (pa: row=q, s-slice = kb*32 + g*8; lgkmcnt orders write->read)
        __builtin_amdgcn_s_setprio(1);
        #pragma unroll
        for (int kb = 0; kb < 4; ++kb) {
            const int c16 = (kb * 4 + g) ^ (q & 7);
            bf16x8 pa = *(const bf16x8*)((const char*)Ps + q * 256 + c16 * 16);
            #pragma unroll
            for (int db = 0; db < 4; ++db)
                o[db] = __builtin_amdgcn_mfma_f32_16x16x32_bf16(pa, vf[kb * 4 + db], o[db], 0, 0, 0);
        }
        __builtin_amdgcn_s_setprio(0);
    }

    if ((jmax & 1) == 0) {
        const int j = jmax;
        bf16x8 kf[8];
        #pragma unroll
        for (int sb = 0; sb < 4; ++sb) {
            const unsigned short* kp = kfb + (size_t)(j * 8 + sb * 2) * 512 + l * 8;
            kf[sb * 2]     = *(const bf16x8*)kp;
            kf[sb * 2 + 1] = *(const bf16x8*)(kp + 512);
        }
        f32x4 sf[4];
        __builtin_amdgcn_s_setprio(1);
        #pragma unroll
        for (int sb = 0; sb < 4; ++sb) {
            f32x4 acc = (f32x4){0.f, 0.f, 0.f, 0.f};
            acc = __builtin_amdgcn_mfma_f32_16x16x32_bf16(kf[sb*2],     aq0, acc, 0, 0, 0);
            acc = __builtin_amdgcn_mfma_f32_16x16x32_bf16(kf[sb*2 + 1], aq1, acc, 0, 0, 0);
            sf[sb] = acc;
        }
        __builtin_amdgcn_s_setprio(0);

        bf16x8 vf[8];
        #pragma unroll
        for (int kb = 0; kb < 2; ++kb)
            #pragma unroll
            for (int db = 0; db < 4; ++db)
                vf[kb * 4 + db] = *(const bf16x8*)(vfb + (size_t)(j * 8 + kb * 4 + db) * 512 + l * 8);

        #pragma unroll
        for (int sb = 0; sb < 4; ++sb) {
            const int sg = j * 64 + sb * 16 + 4 * g;
            #pragma unroll
            for (int r = 0; r < 4; ++r)
                if (sg + r > qglob) sf[sb][r] = -INFINITY;
        }

        f32x4 mv = sf[0];
        #pragma unroll
        for (int i = 1; i < 4; ++i)
            #pragma unroll
            for (int r = 0; r < 4; ++r) mv[r] = fmaxf(mv[r], sf[i][r]);
        float mloc = fmaxf(fmaxf(mv[0], mv[1]), fmaxf(mv[2], mv[3]));
        mloc = fmaxf(mloc, __shfl_xor(mloc, 16));
        mloc = fmaxf(mloc, __shfl_xor(mloc, 32));
        const float mn = fmaxf(mrow, mloc);
        const float alpha = exp2f(mrow - mn);
        mrow = mn;

        float psum = 0.f;
        #pragma unroll
        for (int sb = 0; sb < 4; ++sb) {
            float p0 = exp2f(sf[sb][0] - mn);
            float p1 = exp2f(sf[sb][1] - mn);
            float p2 = exp2f(sf[sb][2] - mn);
            float p3 = exp2f(sf[sb][3] - mn);
            psum += (p0 + p1) + (p2 + p3);
            unsigned int pk0 = cvt_pk_bf16(p0, p1);
            unsigned int pk1 = cvt_pk_bf16(p2, p3);
            const int c16 = (sb * 2 + (g >> 1)) ^ (q & 7);
            *(uint2*)((char*)Ps + q * 256 + c16 * 16 + (g & 1) * 8) = make_uint2(pk0, pk1);
        }
        psum += __shfl_xor(psum, 16);
        psum += __shfl_xor(psum, 32);
        lrow = lrow * alpha + psum;

        float al[4];
        #pragma unroll
        for (int r = 0; r < 4; ++r) al[r] = __shfl(alpha, g * 4 + r);
        #pragma unroll
        for (int d = 0; d < 4; ++d)
            #pragma unroll
            for (int r = 0; r < 4; ++r) o[d][r] *= al[r];

        __builtin_amdgcn_s_setprio(1);
        #pragma unroll
        for (int kb = 0; kb < 2; ++kb) {
            const int c16 = (kb * 4 + g) ^ (q & 7);
            bf16x8 pa = *(const bf16x8*)((const char*)Ps + q * 256 + c16 * 16);
            #pragma unroll
            for (int db = 0; db < 4; ++db)
                o[db] = __builtin_amdgcn_mfma_f32_16x16x32_bf16(pa, vf[kb * 4 + db], o[db], 0, 0, 0);
        }
        __builtin_amdgcn_s_setprio(0);
    }

    // epilogue: O rows = g*4+r, cols = q + db*16
    float linv[4];
    #pragma unroll
    for (int r = 0; r < 4; ++r) linv[r] = 1.0f / __shfl(lrow, g * 4 + r);
    #pragma unroll
    for (int r = 0; r < 4; ++r) {
        const size_t rb = (rowbase + strip * 16 + g * 4 + r) * (size_t)CDIM + h * 64 + q;
        #pragma unroll
        for (int d = 0; d < 4; ++d)
            out[rb + d * 16] = f2bf(o[d][r] * linv[r]);
    }
}

extern "C" void kernel_launch(void* const* d_in, const int* in_sizes, int n_in,
                              void* d_out, int out_size, void* d_ws, size_t ws_size,
                              hipStream_t stream) {
    const float* x     = (const float*)d_in[0];
    const float* ln1_g = (const float*)d_in[1];
    const float* ln1_b = (const float*)d_in[2];
    const float* w_qkv = (const float*)d_in[3];
    const float* b_qkv = (const float*)d_in[4];
    const float* w_out = (const float*)d_in[5];
    const float* b_out = (const float*)d_in[6];
    const float* ln2_g = (const float*)d_in[7];
    const float* ln2_b = (const float*)d_in[8];
    const float* w_ff1 = (const float*)d_in[9];
    const float* b_ff1 = (const float*)d_in[10];
    const float* w_ff2 = (const float*)d_in[11];
    const float* b_ff2 = (const float*)d_in[12];
    float* out = (float*)d_out;

    char* wsb = (char*)d_ws;
    unsigned short* h_bf    = (unsigned short*)(wsb);                          // 8 MB
    unsigned short* qkv_bf  = (unsigned short*)(wsb + 8ll  * 1024 * 1024);     // 24 MB
    unsigned short* attn_bf = (unsigned short*)(wsb + 32ll * 1024 * 1024);     // 8 MB
    float*          x1      = (float*)         (wsb + 40ll * 1024 * 1024);     // 16 MB
    unsigned short* kfrag   = (unsigned short*)(wsb + 40ll * 1024 * 1024);     // 8 MB (overlays x1, dead until step 4)
    unsigned short* vfrag   = (unsigned short*)(wsb + 48ll * 1024 * 1024);     // 8 MB (overlays x1, dead until step 4)
    unsigned short* wqkvT   = (unsigned short*)(wsb + 56ll * 1024 * 1024);     // 6 MB
    unsigned short* woutT   = (unsigned short*)(wsb + 62ll * 1024 * 1024);     // 2 MB
    unsigned short* wff1T   = (unsigned short*)(wsb + 64ll * 1024 * 1024);     // 8 MB
    unsigned short* wff2T   = (unsigned short*)(wsb + 72ll * 1024 * 1024);     // 8 MB
    unsigned short* ff1_bf  = (unsigned short*)(wsb + 8ll  * 1024 * 1024);     // 32 MB, overlays dead qkv+attn

    transpose_cast_kernel<<<dim3(48, 16), 256, 0, stream>>>(w_qkv, wqkvT, 1024, 3072);
    transpose_cast_kernel<<<dim3(16, 16), 256, 0, stream>>>(w_out, woutT, 1024, 1024);
    transpose_cast_kernel<<<dim3(64, 16), 256, 0, stream>>>(w_ff1, wff1T, 1024, 4096);
    transpose_cast_kernel<<<dim3(16, 64), 256, 0, stream>>>(w_ff2, wff2T, 4096, 1024);

    // 1. LN1 -> bf16
    ln_kernel<<<ROWS, 256, 0, stream>>>(x, ln1_g, ln1_b, h_bf);
    // 2. qkv = h @ w_qkv + b  -> bf16   (768 blocks: nbx=24, 4 row-panels/XCD)
    gemm_kernel<0><<<768, 256, 0, stream>>>(h_bf, wqkvT, b_qkv, nullptr, qkv_bf, ROWS, 3072, 1024, 24, 4);
    // 2b. K/V fragment-major pre-pass
    kvfrag_kernel<<<dim3(32, 32), 256, 0, stream>>>(qkv_bf, kfrag, vfrag);
    // 3. causal flash attention -> bf16 (swapped QK^T, in-lane softmax)
    attn_kernel<<<4096, 64, 0, stream>>>(qkv_bf, kfrag, vfrag, attn_bf);
    // 4. x1 = x + attn @ w_out + b  -> f32   (512 blocks: nbx=8, 8 row-panels/XCD)
    gemm64_kernel<1><<<512, 256, 0, stream>>>(attn_bf, woutT, b_out, x, x1, ROWS, 1024, 1024, 8, 8);
    // 5. LN2 -> bf16
    ln_kernel<<<ROWS, 256, 0, stream>>>(x1, ln2_g, ln2_b, h_bf);
    // 6. ff1 = gelu(h @ w_ff1 + b)  -> bf16   (1024 blocks: nbx=32, 4 row-panels/XCD)
    gemm_kernel<2><<<1024, 256, 0, stream>>>(h_bf, wff1T, b_ff1, nullptr, ff1_bf, ROWS, 4096, 1024, 32, 4);
    // 7. out = x1 + ff1 @ w_ff2 + b  -> f32   (512 blocks: nbx=8, 8 row-panels/XCD)
    gemm64_kernel<1><<<512, 256, 0, stream>>>(ff1_bf, wff2T, b_ff2, x1, (float*)out, ROWS, 1024, 4096, 8, 8);
}

// Round 15
// 242.064 us; speedup vs baseline: 1.5966x; 1.0515x over previous
//
#include <hip/hip_runtime.h>
#include <hip/hip_bf16.h>
#include <math.h>

#define TSEQ 2048
#define BATCH 2
#define CDIM 1024
#define NH 16
#define HD 64
#define DFF 4096
#define ROWS (BATCH*TSEQ)   // 4096

typedef __attribute__((ext_vector_type(4))) float f32x4;
typedef __attribute__((ext_vector_type(8))) short bf16x8;   // 8 bf16 in 4 VGPRs
typedef __attribute__((ext_vector_type(4))) unsigned short u16x4;

__device__ __forceinline__ void gload_lds16(const void* g, void* l) {
    void* gv = const_cast<void*>(g);
    __builtin_amdgcn_global_load_lds((__attribute__((address_space(1))) void*)gv,
                                     (__attribute__((address_space(3))) void*)l, 16, 0, 0);
}

__device__ __forceinline__ unsigned short f2bf(float f) {
    unsigned int u = __float_as_uint(f);
    return (unsigned short)((u + 0x7FFFu + ((u >> 16) & 1u)) >> 16);
}
__device__ __forceinline__ float bf2f(unsigned short u) {
    return __uint_as_float((unsigned int)u << 16);
}
// packed f32x2 -> bf16x2 (low half = first arg); no builtin on gfx950 (T12)
__device__ __forceinline__ unsigned int cvt_pk_bf16(float lo, float hi) {
    unsigned int r;
    asm("v_cvt_pk_bf16_f32 %0, %1, %2" : "=v"(r) : "v"(lo), "v"(hi));
    return r;
}
// tanh-form GELU: v * sigmoid(1.59577*(v + 0.044715 v^3)); |err vs exact| < ~3e-4
__device__ __forceinline__ float fast_gelu(float v) {
    float u = fmaf(0.044715f * v * v, v, v);
    float e = __expf(-1.5957691216057308f * u);
    return v * __builtin_amdgcn_rcpf(1.0f + e);
}

// ------------------------------- LayerNorm -> bf16 --------------------------------
__global__ __launch_bounds__(256) void ln_kernel(const float* __restrict__ x,
                                                 const float* __restrict__ g,
                                                 const float* __restrict__ b,
                                                 unsigned short* __restrict__ out) {
    int row = blockIdx.x;
    int tid = threadIdx.x;
    const float* xr = x + (size_t)row * CDIM;
    float4 v = *(const float4*)(xr + tid * 4);
    float s  = v.x + v.y + v.z + v.w;
    float s2 = v.x*v.x + v.y*v.y + v.z*v.z + v.w*v.w;
    #pragma unroll
    for (int off = 32; off >= 1; off >>= 1) {
        s  += __shfl_down(s, off);
        s2 += __shfl_down(s2, off);
    }
    __shared__ float red[8];
    int wid = tid >> 6, lane = tid & 63;
    if (lane == 0) { red[wid] = s; red[wid + 4] = s2; }
    __syncthreads();
    float ts  = red[0] + red[1] + red[2] + red[3];
    float ts2 = red[4] + red[5] + red[6] + red[7];
    float mu  = ts * (1.0f / CDIM);
    float var = ts2 * (1.0f / CDIM) - mu * mu;
    float rstd = rsqrtf(var + 1e-5f);
    float4 gv = *(const float4*)(g + tid * 4);
    float4 bv = *(const float4*)(b + tid * 4);
    unsigned short o4[4];
    o4[0] = f2bf((v.x - mu) * rstd * gv.x + bv.x);
    o4[1] = f2bf((v.y - mu) * rstd * gv.y + bv.y);
    o4[2] = f2bf((v.z - mu) * rstd * gv.z + bv.z);
    o4[3] = f2bf((v.w - mu) * rstd * gv.w + bv.w);
    *(u16x4*)(out + (size_t)row * CDIM + tid * 4) = *(u16x4*)o4;
}

// --------------------- transpose + cast: W[K][N] f32 -> Wt[N][K] bf16 ---------------
__global__ __launch_bounds__(256) void transpose_cast_kernel(const float* __restrict__ W,
                                                             unsigned short* __restrict__ Wt,
                                                             int K, int N) {
    __shared__ float T[64][65];
    int tid = threadIdx.x;
    int n0 = blockIdx.x * 64, k0 = blockIdx.y * 64;
    int kr = tid >> 4;
    int nc = (tid & 15) * 4;
    #pragma unroll
    for (int i = 0; i < 4; ++i) {
        float4 v = *(const float4*)&W[(size_t)(k0 + kr + i*16) * N + (n0 + nc)];
        T[kr + i*16][nc + 0] = v.x;
        T[kr + i*16][nc + 1] = v.y;
        T[kr + i*16][nc + 2] = v.z;
        T[kr + i*16][nc + 3] = v.w;
    }
    __syncthreads();
    int n  = tid >> 2;
    int kb = (tid & 3) * 16;
    unsigned short tmp[16];
    #pragma unroll
    for (int i = 0; i < 16; ++i) tmp[i] = f2bf(T[kb + i][n]);
    unsigned short* dst = Wt + (size_t)(n0 + n) * K + (k0 + kb);
    *(int4*)dst       = *(int4*)&tmp[0];
    *(int4*)(dst + 8) = *(int4*)&tmp[8];
}

// ---- K/V fragment-major pre-pass (see R8 notes) -----------------------------------
__global__ __launch_bounds__(256) void kvfrag_kernel(const unsigned short* __restrict__ qkv,
                                                     unsigned short* __restrict__ kfrag,
                                                     unsigned short* __restrict__ vfrag) {
    __shared__ unsigned short Kt[64][72];
    __shared__ unsigned short Vt[64][72];
    const int tid = threadIdx.x;
    const int j  = blockIdx.x;
    const int bh = blockIdx.y;
    const int b = bh >> 4, h = bh & 15;
    {
        const int r  = tid >> 2;
        const int c0 = (tid & 3) * 16;
        const unsigned short* src = qkv + ((size_t)(b * TSEQ + j * 64 + r)) * 3072 + 1024 + h * 64 + c0;
        bf16x8 k0 = *(const bf16x8*)src;
        bf16x8 k1 = *(const bf16x8*)(src + 8);
        bf16x8 v0 = *(const bf16x8*)(src + 1024);
        bf16x8 v1 = *(const bf16x8*)(src + 1032);
        *(bf16x8*)&Kt[r][c0]     = k0;
        *(bf16x8*)&Kt[r][c0 + 8] = k1;
        *(bf16x8*)&Vt[r][c0]     = v0;
        *(bf16x8*)&Vt[r][c0 + 8] = v1;
    }
    __syncthreads();
    const int l  = tid & 63;
    const int qd = tid >> 6;
    const size_t tbase = ((size_t)(bh * 32 + j)) * 8 * 512;
    #pragma unroll
    for (int pass = 0; pass < 2; ++pass) {
        const int kc = qd + pass * 4;
        const int sb = kc >> 1, g = kc & 1;
        bf16x8 kv = *(const bf16x8*)&Kt[sb * 16 + (l & 15)][g * 32 + (l >> 4) * 8];
        *(bf16x8*)(kfrag + tbase + kc * 512 + l * 8) = kv;

        const int vc = qd + pass * 4;
        const int kb = vc >> 2, db = vc & 3;
        unsigned short tmp[8];
        #pragma unroll
        for (int i = 0; i < 8; ++i)
            tmp[i] = Vt[kb * 32 + (l >> 4) * 8 + i][db * 16 + (l & 15)];
        *(bf16x8*)(vfrag + tbase + vc * 512 + l * 8) = *(bf16x8*)tmp;
    }
}

// ---- MFMA GEMM (TN) 128x128 tile, BK=32 stages, 3-DEEP counted-vmcnt pipeline -----
// LDS 48 KB (3 x (8A + 8B)) -> 3 blocks/CU. Per stage: 4 gload_lds (2A + 2B chunks).
// Rows have 4 x 16B chunks; LDS pos p holds global chunk p^(row&3); read koff
// = ((l>>4)^(l&3))*8 (both-sides swizzle). Schedule per tile t:
//   { vmcnt(4|0); s_barrier; 16 MFMA on buf[t%3]; stage(t+2 -> buf[(t+2)%3]) }
template<int EPI>
__global__ __launch_bounds__(256) void gemm_kernel(const unsigned short* __restrict__ A,
                                                   const unsigned short* __restrict__ Bt,
                                                   const float* __restrict__ bias,
                                                   const float* __restrict__ res,
                                                   void* __restrict__ Cout,
                                                   int M, int N, int K, int nbx, int rpx) {
    __shared__ __align__(16) unsigned short As[3 * 4096];   // 3 x 8 KB
    __shared__ __align__(16) unsigned short Bs[3 * 4096];   // 3 x 8 KB
    const int tid = threadIdx.x;
    const int l   = tid & 63;
    const int w   = tid >> 6;
    const int wr  = (w >> 1) * 64;
    const int wc  = (w & 1) * 64;
    const int lin = blockIdx.x;
    const int xcd = lin & 7;
    const int idx = lin >> 3;
    const long brow = (long)(xcd * rpx + idx / nbx) * 128;
    const long bcol = (long)(idx % nbx) * 128;

    // staging: thread covers rows r=tid>>2 and r+64, LDS pos tid&3, global chunk XOR'd
    const int srow = tid >> 2;                                  // 0..63
    const int schk = ((tid & 3) ^ (srow & 3)) * 8;              // global elem offset
    const unsigned short* gA = A  + (size_t)(brow + srow) * K + schk;
    const unsigned short* gB = Bt + (size_t)(bcol + srow) * K + schk;

    f32x4 acc[4][4];
    #pragma unroll
    for (int m = 0; m < 4; ++m)
        #pragma unroll
        for (int n = 0; n < 4; ++n) acc[m][n] = (f32x4){0.f, 0.f, 0.f, 0.f};

    // 4 loads per stage: rows [0,64) and [64,128) of A and B
    #define STAGE128(buf, koff_)                                                       \
        do {                                                                           \
            unsigned short* lA_ = As + (buf) * 4096 + tid * 8;                         \
            unsigned short* lB_ = Bs + (buf) * 4096 + tid * 8;                         \
            gload_lds16(gA + (koff_), lA_);                                            \
            gload_lds16(gA + (size_t)64 * K + (koff_), lA_ + 2048);                    \
            gload_lds16(gB + (koff_), lB_);                                            \
            gload_lds16(gB + (size_t)64 * K + (koff_), lB_ + 2048);                    \
        } while (0)

    // prologue: tiles 0 and 1 in flight (8 loads)
    STAGE128(0, 0);
    STAGE128(1, 32);

    int cur = 0;
    for (int k0 = 0; k0 < K; k0 += 32) {
        if (k0 + 32 < K) asm volatile("s_waitcnt vmcnt(4)" ::: "memory");
        else             asm volatile("s_waitcnt vmcnt(0)" ::: "memory");
        __builtin_amdgcn_s_barrier();
        asm volatile("" ::: "memory");   // no LDS read hoists above the barrier

        const unsigned short* cA = As + cur * 4096 + (wr >> 6) * 2048;
        const unsigned short* cB = Bs + cur * 4096 + (wc >> 6) * 2048;
        const int koff = ((l >> 4) ^ (l & 3)) * 8;
        bf16x8 af[4], bf[4];
        #pragma unroll
        for (int m = 0; m < 4; ++m)
            af[m] = *(const bf16x8*)&cA[(m * 16 + (l & 15)) * 32 + koff];
        #pragma unroll
        for (int n = 0; n < 4; ++n)
            bf[n] = *(const bf16x8*)&cB[(n * 16 + (l & 15)) * 32 + koff];
        #pragma unroll
        for (int m = 0; m < 4; ++m)
            #pragma unroll
            for (int n = 0; n < 4; ++n)
                acc[m][n] = __builtin_amdgcn_mfma_f32_16x16x32_bf16(af[m], bf[n], acc[m][n], 0, 0, 0);

        // stage tile t+2 (after barrier(t) -> WAR-safe vs compute(t-1) readers)
        if (k0 + 64 < K) {
            int nxt = cur + 2; if (nxt >= 3) nxt -= 3;
            STAGE128(nxt, k0 + 64);
        }
        cur = cur + 1; if (cur == 3) cur = 0;
    }
    #undef STAGE128

    #pragma unroll
    for (int m = 0; m < 4; ++m) {
        const int rown = wr + m * 16 + (l >> 4) * 4;
        #pragma unroll
        for (int n = 0; n < 4; ++n) {
            const long col = bcol + wc + n * 16 + (l & 15);
            const float bb = bias[col];
            #pragma unroll
            for (int r = 0; r < 4; ++r) {
                const long row = brow + rown + r;
                float v = acc[m][n][r] + bb;
                if (EPI == 1) {
                    v += res[row * N + col];
                    ((float*)Cout)[row * N + col] = v;
                } else if (EPI == 2) {
                    ((unsigned short*)Cout)[row * N + col] = f2bf(fast_gelu(v));
                } else {
                    ((unsigned short*)Cout)[row * N + col] = f2bf(v);
                }
            }
        }
    }
}

// ------ MFMA GEMM (TN) 64x128 tile, BK=64, XOR swizzle, XCD-banded, 3-DEEP PIPELINE
template<int EPI>
__global__ __launch_bounds__(256) void gemm64_kernel(const unsigned short* __restrict__ A,
                                                     const unsigned short* __restrict__ Bt,
                                                     const float* __restrict__ bias,
                                                     const float* __restrict__ res,
                                                     void* __restrict__ Cout,
                                                     int M, int N, int K, int nbx, int rpx) {
    __shared__ __align__(16) unsigned short As[3 * 64 * 64];    // 3 x 8 KB
    __shared__ __align__(16) unsigned short Bs[3 * 128 * 64];   // 3 x 16 KB
    const int tid = threadIdx.x;
    const int l   = tid & 63;
    const int w   = tid >> 6;
    const int wr  = (w >> 1) * 32;
    const int wc  = (w & 1) * 64;
    const int lin = blockIdx.x;
    const int xcd = lin & 7;
    const int idx = lin >> 3;
    const long brow = (long)(xcd * rpx + idx / nbx) * 64;
    const long bcol = (long)(idx % nbx) * 128;

    const int srow = tid >> 3;                                  // 0..31
    const int schk = ((tid & 7) ^ (srow & 7)) * 8;
    const unsigned short* gA = A  + (size_t)(brow + srow) * K + schk;
    const unsigned short* gB = Bt + (size_t)(bcol + srow) * K + schk;

    f32x4 acc[2][4];
    #pragma unroll
    for (int m = 0; m < 2; ++m)
        #pragma unroll
        for (int n = 0; n < 4; ++n) acc[m][n] = (f32x4){0.f, 0.f, 0.f, 0.f};

    #define STAGE64(buf, koff_)                                                        \
        do {                                                                           \
            unsigned short* lA_ = As + (buf) * 4096 + tid * 8;                         \
            unsigned short* lB_ = Bs + (buf) * 8192 + tid * 8;                         \
            _Pragma("unroll")                                                          \
            for (int p = 0; p < 2; ++p)                                                \
                gload_lds16(gA + (size_t)(32 * p) * K + (koff_), lA_ + p * 2048);      \
            _Pragma("unroll")                                                          \
            for (int p = 0; p < 4; ++p)                                                \
                gload_lds16(gB + (size_t)(32 * p) * K + (koff_), lB_ + p * 2048);      \
        } while (0)

    STAGE64(0, 0);
    STAGE64(1, 64);

    int cur = 0;
    for (int k0 = 0; k0 < K; k0 += 64) {
        if (k0 + 64 < K) asm volatile("s_waitcnt vmcnt(6)" ::: "memory");
        else             asm volatile("s_waitcnt vmcnt(0)" ::: "memory");
        __builtin_amdgcn_s_barrier();
        asm volatile("" ::: "memory");

        const unsigned short* cA = As + cur * 4096;
        const unsigned short* cB = Bs + cur * 8192;
        #pragma unroll
        for (int gg = 0; gg < 2; ++gg) {
            const int koff = ((gg * 4 + (l >> 4)) ^ (l & 7)) * 8;
            bf16x8 af[2], bf[4];
            #pragma unroll
            for (int m = 0; m < 2; ++m)
                af[m] = *(const bf16x8*)&cA[(wr + m * 16 + (l & 15)) * 64 + koff];
            #pragma unroll
            for (int n = 0; n < 4; ++n)
                bf[n] = *(const bf16x8*)&cB[(wc + n * 16 + (l & 15)) * 64 + koff];
            #pragma unroll
            for (int m = 0; m < 2; ++m)
                #pragma unroll
                for (int n = 0; n < 4; ++n)
                    acc[m][n] = __builtin_amdgcn_mfma_f32_16x16x32_bf16(af[m], bf[n], acc[m][n], 0, 0, 0);
        }

        if (k0 + 128 < K) {
            int nxt = cur + 2; if (nxt >= 3) nxt -= 3;
            STAGE64(nxt, k0 + 128);
        }
        cur = cur + 1; if (cur == 3) cur = 0;
    }
    #undef STAGE64

    #pragma unroll
    for (int m = 0; m < 2; ++m) {
        const int rown = wr + m * 16 + (l >> 4) * 4;
        #pragma unroll
        for (int n = 0; n < 4; ++n) {
            const long col = bcol + wc + n * 16 + (l & 15);
            const float bb = bias[col];
            #pragma unroll
            for (int r = 0; r < 4; ++r) {
                const long row = brow + rown + r;
                float v = acc[m][n][r] + bb;
                if (EPI == 1) {
                    v += res[row * N + col];
                    ((float*)Cout)[row * N + col] = v;
                } else if (EPI == 2) {
                    ((unsigned short*)Cout)[row * N + col] = f2bf(fast_gelu(v));
                } else {
                    ((unsigned short*)Cout)[row * N + col] = f2bf(v);
                }
            }
        }
    }
}

// ------------- MFMA causal flash attention (swapped QK^T, in-lane softmax) ----------
#define QSCALE 0.18033688011112042f   // 0.125 * log2(e)
__global__ __launch_bounds__(64) void attn_kernel(const unsigned short* __restrict__ qkv,
                                                  const unsigned short* __restrict__ kfrag,
                                                  const unsigned short* __restrict__ vfrag,
                                                  unsigned short* __restrict__ out) {
    __shared__ __align__(16) unsigned short Ps[16 * 128];   // [q][s], 16B-chunk swizzled

    const int l    = threadIdx.x;
    const int q    = l & 15;                   // lane's softmax row
    const int g    = l >> 4;                   // lane group 0..3
    const int lin  = blockIdx.x;
    const int xcd  = lin & 7;
    const int rest = lin >> 3;
    const int h    = xcd + 8 * (rest & 1);
    const int b    = (rest >> 1) & 1;
    const int strip = 127 - (rest >> 2);
    const int jmax  = strip >> 2;
    const size_t rowbase = (size_t)b * TSEQ;
    const int bh = b * NH + h;
    const int qglob = strip * 16 + q;

    const unsigned short* kfb = kfrag + (size_t)bh * 32 * 8 * 512;
    const unsigned short* vfb = vfrag + (size_t)bh * 32 * 8 * 512;

    bf16x8 aq0, aq1;
    {
        const unsigned short* qp = qkv + (rowbase + qglob) * 3072 + h * 64 + g * 8;
        bf16x8 t0 = *(const bf16x8*)qp;
        bf16x8 t1 = *(const bf16x8*)(qp + 32);
        #pragma unroll
        for (int i = 0; i < 8; ++i) {
            aq0[i] = (short)f2bf(bf2f((unsigned short)t0[i]) * QSCALE);
            aq1[i] = (short)f2bf(bf2f((unsigned short)t1[i]) * QSCALE);
        }
    }

    float mrow = -INFINITY, lrow = 0.f;
    f32x4 o[4];
    #pragma unroll
    for (int d = 0; d < 4; ++d) o[d] = (f32x4){0.f, 0.f, 0.f, 0.f};

    for (int j = 0; j + 1 <= jmax; j += 2) {
        const bool diag2 = (j + 1 == jmax);

        bf16x8 kf[16];
        #pragma unroll
        for (int t = 0; t < 2; ++t)
            #pragma unroll
            for (int sb = 0; sb < 4; ++sb) {
                const unsigned short* kp = kfb + (size_t)((j + t) * 8 + sb * 2) * 512 + l * 8;
                kf[t * 8 + sb * 2]     = *(const bf16x8*)kp;
                kf[t * 8 + sb * 2 + 1] = *(const bf16x8*)(kp + 512);
            }

        f32x4 sf[8];
        __builtin_amdgcn_s_setprio(1);
        #pragma unroll
        for (int t = 0; t < 2; ++t)
            #pragma unroll
            for (int sb = 0; sb < 4; ++sb) {
                f32x4 acc = (f32x4){0.f, 0.f, 0.f, 0.f};
                acc = __builtin_amdgcn_mfma_f32_16x16x32_bf16(kf[t*8 + sb*2],     aq0, acc, 0, 0, 0);
                acc = __builtin_amdgcn_mfma_f32_16x16x32_bf16(kf[t*8 + sb*2 + 1], aq1, acc, 0, 0, 0);
                sf[t*4 + sb] = acc;
            }
        __builtin_amdgcn_s_setprio(0);

        bf16x8 vf[16];
        #pragma unroll
        for (int kb = 0; kb < 4; ++kb)
            #pragma unroll
            for (int db = 0; db < 4; ++db)
                vf[kb * 4 + db] = *(const bf16x8*)(vfb + (size_t)((j + (kb >> 1)) * 8 + (kb & 1) * 4 + db) * 512 + l * 8);

        if (diag2) {
            #pragma unroll
            for (int sb = 0; sb < 4; ++sb) {
                const int sg = (j + 1) * 64 + sb * 16 + 4 * g;
                #pragma unroll
                for (int r = 0; r < 4; ++r)
                    if (sg + r > qglob) sf[4 + sb][r] = -INFINITY;
            }
        }

        f32x4 mv = sf[0];
        #pragma unroll
        for (int i = 1; i < 8; ++i)
            #pragma unroll
            for (int r = 0; r < 4; ++r) mv[r] = fmaxf(mv[r], sf[i][r]);
        float mloc = fmaxf(fmaxf(mv[0], mv[1]), fmaxf(mv[2], mv[3]));
        mloc = fmaxf(mloc, __shfl_xor(mloc, 16));
        mloc = fmaxf(mloc, __shfl_xor(mloc, 32));
        const float mn = fmaxf(mrow, mloc);
        const float alpha = exp2f(mrow - mn);
        mrow = mn;

        float psum = 0.f;
        #pragma unroll
        for (int i = 0; i < 8; ++i) {
            const int t = i >> 2, sb = i & 3;
            float p0 = exp2f(sf[i][0] - mn);
            float p1 = exp2f(sf[i][1] - mn);
            float p2 = exp2f(sf[i][2] - mn);
            float p3 = exp2f(sf[i][3] - mn);
            psum += (p0 + p1) + (p2 + p3);
            unsigned int pk0 = cvt_pk_bf16(p0, p1);
            unsigned int pk1 = cvt_pk_bf16(p2, p3);
            const int c16 = (t * 8 + sb * 2 + (g >> 1)) ^ (q & 7);
            *(uint2*)((char*)Ps + q * 256 + c16 * 16 + (g & 1) * 8) = make_uint2(pk0, pk1);
        }
        psum += __shfl_xor(psum, 16);
        psum += __shfl_xor(psum, 32);
        lrow = lrow * alpha + psum;

        float al[4];
        #pragma unroll
        for (int r = 0; r < 4; ++r) al[r] = __shfl(alpha, g * 4 + r);
        #pragma unroll
        for (int d = 0; d < 4; ++d)
            #pragma unroll
            for (int r = 0; r < 4; ++r) o[d][r] *= al[r];

        __builtin_amdgcn_s_setprio(1);
        #pragma unroll
        for (int kb = 0; kb < 4; ++kb) {
            const int c16 = (kb * 4 + g) ^ (q & 7);
            bf16x8 pa = *(const bf16x8*)((const char*)Ps + q * 256 + c16 * 16);
            #pragma unroll
            for (int db = 0; db < 4; ++db)
                o[db] = __builtin_amdgcn_mfma_f32_16x16x32_bf16(pa, vf[kb * 4 + db], o[db], 0, 0, 0);
        }
        __builtin_amdgcn_s_setprio(0);
    }

    if ((jmax & 1) == 0) {
        const int j = jmax;
        bf16x8 kf[8];
        #pragma unroll
        for (int sb = 0; sb < 4; ++sb) {
            const unsigned short* kp = kfb + (size_t)(j * 8 + sb * 2) * 512 + l * 8;
            kf[sb * 2]     = *(const bf16x8*)kp;
            kf[sb * 2 + 1] = *(const bf16x8*)(kp + 512);
        }
        f32x4 sf[4];
        __builtin_amdgcn_s_setprio(1);
        #pragma unroll
        for (int sb = 0; sb < 4; ++sb) {
            f32x4 acc = (f32x4){0.f, 0.f, 0.f, 0.f};
            acc = __builtin_amdgcn_mfma_f32_16x16x32_bf16(kf[sb*2],     aq0, acc, 0, 0, 0);
            acc = __builtin_amdgcn_mfma_f32_16x16x32_bf16(kf[sb*2 + 1], aq1, acc, 0, 0, 0);
            sf[sb] = acc;
        }
        __builtin_amdgcn_s_setprio(0);

        bf16x8 vf[8];
        #pragma unroll
        for (int kb = 0; kb < 2; ++kb)
            #pragma unroll
            for (int db = 0; db < 4; ++db)
                vf[kb * 4 + db] = *(const bf16x8*)(vfb + (size_t)(j * 8 + kb * 4 + db) * 512 + l * 8);

        #pragma unroll
        for (int sb = 0; sb < 4; ++sb) {
            const int sg = j * 64 + sb * 16 + 4 * g;
            #pragma unroll
            for (int r = 0; r < 4; ++r)
                if (sg + r > qglob) sf[sb][r] = -INFINITY;
        }

        f32x4 mv = sf[0];
        #pragma unroll
        for (int i = 1; i < 4; ++i)
            #pragma unroll
            for (int r = 0; r < 4; ++r) mv[r] = fmaxf(mv[r], sf[i][r]);
        float mloc = fmaxf(fmaxf(mv[0], mv[1]), fmaxf(mv[2], mv[3]));
        mloc = fmaxf(mloc, __shfl_xor(mloc, 16));
        mloc = fmaxf(mloc, __shfl_xor(mloc, 32));
        const float mn = fmaxf(mrow, mloc);
        const float alpha = exp2f(mrow - mn);
        mrow = mn;

        float psum = 0.f;
        #pragma unroll
        for (int sb = 0; sb < 4; ++sb) {
            float p0 = exp2f(sf[sb][0] - mn);
            float p1 = exp2f(sf[sb][1] - mn);
            float p2 = exp2f(sf[sb][2] - mn);
            float p3 = exp2f(sf[sb][3] - mn);
            psum += (p0 + p1) + (p2 + p3);
            unsigned int pk0 = cvt_pk_bf16(p0, p1);
            unsigned int pk1 = cvt_pk_bf16(p2, p3);
            const int c16 = (sb * 2 + (g >> 1)) ^ (q & 7);
            *(uint2*)((char*)Ps + q * 256 + c16 * 16 + (g & 1) * 8) = make_uint2(pk0, pk1);
        }
        psum += __shfl_xor(psum, 16);
        psum += __shfl_xor(psum, 32);
        lrow = lrow * alpha + psum;

        float al[4];
        #pragma unroll
        for (int r = 0; r < 4; ++r) al[r] = __shfl(alpha, g * 4 + r);
        #pragma unroll
        for (int d = 0; d < 4; ++d)
            #pragma unroll
            for (int r = 0; r < 4; ++r) o[d][r] *= al[r];

        __builtin_amdgcn_s_setprio(1);
        #pragma unroll
        for (int kb = 0; kb < 2; ++kb) {
            const int c16 = (kb * 4 + g) ^ (q & 7);
            bf16x8 pa = *(const bf16x8*)((const char*)Ps + q * 256 + c16 * 16);
            #pragma unroll
            for (int db = 0; db < 4; ++db)
                o[db] = __builtin_amdgcn_mfma_f32_16x16x32_bf16(pa, vf[kb * 4 + db], o[db], 0, 0, 0);
        }
        __builtin_amdgcn_s_setprio(0);
    }

    // epilogue: O rows = g*4+r, cols = q + db*16
    float linv[4];
    #pragma unroll
    for (int r = 0; r < 4; ++r) linv[r] = 1.0f / __shfl(lrow, g * 4 + r);
    #pragma unroll
    for (int r = 0; r < 4; ++r) {
        const size_t rb = (rowbase + strip * 16 + g * 4 + r) * (size_t)CDIM + h * 64 + q;
        #pragma unroll
        for (int d = 0; d < 4; ++d)
            out[rb + d * 16] = f2bf(o[d][r] * linv[r]);
    }
}

extern "C" void kernel_launch(void* const* d_in, const int* in_sizes, int n_in,
                              void* d_out, int out_size, void* d_ws, size_t ws_size,
                              hipStream_t stream) {
    const float* x     = (const float*)d_in[0];
    const float* ln1_g = (const float*)d_in[1];
    const float* ln1_b = (const float*)d_in[2];
    const float* w_qkv = (const float*)d_in[3];
    const float* b_qkv = (const float*)d_in[4];
    const float* w_out = (const float*)d_in[5];
    const float* b_out = (const float*)d_in[6];
    const float* ln2_g = (const float*)d_in[7];
    const float* ln2_b = (const float*)d_in[8];
    const float* w_ff1 = (const float*)d_in[9];
    const float* b_ff1 = (const float*)d_in[10];
    const float* w_ff2 = (const float*)d_in[11];
    const float* b_ff2 = (const float*)d_in[12];
    float* out = (float*)d_out;

    char* wsb = (char*)d_ws;
    unsigned short* h_bf    = (unsigned short*)(wsb);                          // 8 MB
    unsigned short* qkv_bf  = (unsigned short*)(wsb + 8ll  * 1024 * 1024);     // 24 MB
    unsigned short* attn_bf = (unsigned short*)(wsb + 32ll * 1024 * 1024);     // 8 MB
    float*          x1      = (float*)         (wsb + 40ll * 1024 * 1024);     // 16 MB
    unsigned short* kfrag   = (unsigned short*)(wsb + 40ll * 1024 * 1024);     // 8 MB (overlays x1, dead until step 4)
    unsigned short* vfrag   = (unsigned short*)(wsb + 48ll * 1024 * 1024);     // 8 MB (overlays x1, dead until step 4)
    unsigned short* wqkvT   = (unsigned short*)(wsb + 56ll * 1024 * 1024);     // 6 MB
    unsigned short* woutT   = (unsigned short*)(wsb + 62ll * 1024 * 1024);     // 2 MB
    unsigned short* wff1T   = (unsigned short*)(wsb + 64ll * 1024 * 1024);     // 8 MB
    unsigned short* wff2T   = (unsigned short*)(wsb + 72ll * 1024 * 1024);     // 8 MB
    unsigned short* ff1_bf  = (unsigned short*)(wsb + 8ll  * 1024 * 1024);     // 32 MB, overlays dead qkv+attn

    transpose_cast_kernel<<<dim3(48, 16), 256, 0, stream>>>(w_qkv, wqkvT, 1024, 3072);
    transpose_cast_kernel<<<dim3(16, 16), 256, 0, stream>>>(w_out, woutT, 1024, 1024);
    transpose_cast_kernel<<<dim3(64, 16), 256, 0, stream>>>(w_ff1, wff1T, 1024, 4096);
    transpose_cast_kernel<<<dim3(16, 64), 256, 0, stream>>>(w_ff2, wff2T, 4096, 1024);

    // 1. LN1 -> bf16
    ln_kernel<<<ROWS, 256, 0, stream>>>(x, ln1_g, ln1_b, h_bf);
    // 2. qkv = h @ w_qkv + b  -> bf16   (768 blocks: nbx=24, 4 row-panels/XCD)
    gemm_kernel<0><<<768, 256, 0, stream>>>(h_bf, wqkvT, b_qkv, nullptr, qkv_bf, ROWS, 3072, 1024, 24, 4);
    // 2b. K/V fragment-major pre-pass
    kvfrag_kernel<<<dim3(32, 32), 256, 0, stream>>>(qkv_bf, kfrag, vfrag);
    // 3. causal flash attention -> bf16 (swapped QK^T, in-lane softmax)
    attn_kernel<<<4096, 64, 0, stream>>>(qkv_bf, kfrag, vfrag, attn_bf);
    // 4. x1 = x + attn @ w_out + b  -> f32   (512 blocks: nbx=8, 8 row-panels/XCD)
    gemm64_kernel<1><<<512, 256, 0, stream>>>(attn_bf, woutT, b_out, x, x1, ROWS, 1024, 1024, 8, 8);
    // 5. LN2 -> bf16
    ln_kernel<<<ROWS, 256, 0, stream>>>(x1, ln2_g, ln2_b, h_bf);
    // 6. ff1 = gelu(h @ w_ff1 + b)  -> bf16   (1024 blocks: nbx=32, 4 row-panels/XCD)
    gemm_kernel<2><<<1024, 256, 0, stream>>>(h_bf, wff1T, b_ff1, nullptr, ff1_bf, ROWS, 4096, 1024, 32, 4);
    // 7. out = x1 + ff1 @ w_ff2 + b  -> f32   (512 blocks: nbx=8, 8 row-panels/XCD)
    gemm64_kernel<1><<<512, 256, 0, stream>>>(ff1_bf, wff2T, b_ff2, x1, (float*)out, ROWS, 1024, 4096, 8, 8);
}

// Round 16
// 239.989 us; speedup vs baseline: 1.6104x; 1.0086x over previous
//
#include <hip/hip_runtime.h>
#include <hip/hip_bf16.h>
#include <math.h>

#define TSEQ 2048
#define BATCH 2
#define CDIM 1024
#define NH 16
#define HD 64
#define DFF 4096
#define ROWS (BATCH*TSEQ)   // 4096

typedef __attribute__((ext_vector_type(4))) float f32x4;
typedef __attribute__((ext_vector_type(8))) short bf16x8;   // 8 bf16 in 4 VGPRs
typedef __attribute__((ext_vector_type(4))) unsigned short u16x4;

__device__ __forceinline__ void gload_lds16(const void* g, void* l) {
    void* gv = const_cast<void*>(g);
    __builtin_amdgcn_global_load_lds((__attribute__((address_space(1))) void*)gv,
                                     (__attribute__((address_space(3))) void*)l, 16, 0, 0);
}

__device__ __forceinline__ unsigned short f2bf(float f) {
    unsigned int u = __float_as_uint(f);
    return (unsigned short)((u + 0x7FFFu + ((u >> 16) & 1u)) >> 16);
}
__device__ __forceinline__ float bf2f(unsigned short u) {
    return __uint_as_float((unsigned int)u << 16);
}
// packed f32x2 -> bf16x2 (low half = first arg); no builtin on gfx950 (T12)
__device__ __forceinline__ unsigned int cvt_pk_bf16(float lo, float hi) {
    unsigned int r;
    asm("v_cvt_pk_bf16_f32 %0, %1, %2" : "=v"(r) : "v"(lo), "v"(hi));
    return r;
}
// tanh-form GELU: v * sigmoid(1.59577*(v + 0.044715 v^3)); |err vs exact| < ~3e-4
__device__ __forceinline__ float fast_gelu(float v) {
    float u = fmaf(0.044715f * v * v, v, v);
    float e = __expf(-1.5957691216057308f * u);
    return v * __builtin_amdgcn_rcpf(1.0f + e);
}

// ------------------------------- LayerNorm -> bf16 --------------------------------
__global__ __launch_bounds__(256) void ln_kernel(const float* __restrict__ x,
                                                 const float* __restrict__ g,
                                                 const float* __restrict__ b,
                                                 unsigned short* __restrict__ out) {
    int row = blockIdx.x;
    int tid = threadIdx.x;
    const float* xr = x + (size_t)row * CDIM;
    float4 v = *(const float4*)(xr + tid * 4);
    float s  = v.x + v.y + v.z + v.w;
    float s2 = v.x*v.x + v.y*v.y + v.z*v.z + v.w*v.w;
    #pragma unroll
    for (int off = 32; off >= 1; off >>= 1) {
        s  += __shfl_down(s, off);
        s2 += __shfl_down(s2, off);
    }
    __shared__ float red[8];
    int wid = tid >> 6, lane = tid & 63;
    if (lane == 0) { red[wid] = s; red[wid + 4] = s2; }
    __syncthreads();
    float ts  = red[0] + red[1] + red[2] + red[3];
    float ts2 = red[4] + red[5] + red[6] + red[7];
    float mu  = ts * (1.0f / CDIM);
    float var = ts2 * (1.0f / CDIM) - mu * mu;
    float rstd = rsqrtf(var + 1e-5f);
    float4 gv = *(const float4*)(g + tid * 4);
    float4 bv = *(const float4*)(b + tid * 4);
    unsigned short o4[4];
    o4[0] = f2bf((v.x - mu) * rstd * gv.x + bv.x);
    o4[1] = f2bf((v.y - mu) * rstd * gv.y + bv.y);
    o4[2] = f2bf((v.z - mu) * rstd * gv.z + bv.z);
    o4[3] = f2bf((v.w - mu) * rstd * gv.w + bv.w);
    *(u16x4*)(out + (size_t)row * CDIM + tid * 4) = *(u16x4*)o4;
}

// --------------------- transpose + cast: W[K][N] f32 -> Wt[N][K] bf16 ---------------
__global__ __launch_bounds__(256) void transpose_cast_kernel(const float* __restrict__ W,
                                                             unsigned short* __restrict__ Wt,
                                                             int K, int N) {
    __shared__ float T[64][65];
    int tid = threadIdx.x;
    int n0 = blockIdx.x * 64, k0 = blockIdx.y * 64;
    int kr = tid >> 4;
    int nc = (tid & 15) * 4;
    #pragma unroll
    for (int i = 0; i < 4; ++i) {
        float4 v = *(const float4*)&W[(size_t)(k0 + kr + i*16) * N + (n0 + nc)];
        T[kr + i*16][nc + 0] = v.x;
        T[kr + i*16][nc + 1] = v.y;
        T[kr + i*16][nc + 2] = v.z;
        T[kr + i*16][nc + 3] = v.w;
    }
    __syncthreads();
    int n  = tid >> 2;
    int kb = (tid & 3) * 16;
    unsigned short tmp[16];
    #pragma unroll
    for (int i = 0; i < 16; ++i) tmp[i] = f2bf(T[kb + i][n]);
    unsigned short* dst = Wt + (size_t)(n0 + n) * K + (k0 + kb);
    *(int4*)dst       = *(int4*)&tmp[0];
    *(int4*)(dst + 8) = *(int4*)&tmp[8];
}

// ---- K/V fragment-major pre-pass (see R8 notes) -----------------------------------
__global__ __launch_bounds__(256) void kvfrag_kernel(const unsigned short* __restrict__ qkv,
                                                     unsigned short* __restrict__ kfrag,
                                                     unsigned short* __restrict__ vfrag) {
    __shared__ unsigned short Kt[64][72];
    __shared__ unsigned short Vt[64][72];
    const int tid = threadIdx.x;
    const int j  = blockIdx.x;
    const int bh = blockIdx.y;
    const int b = bh >> 4, h = bh & 15;
    {
        const int r  = tid >> 2;
        const int c0 = (tid & 3) * 16;
        const unsigned short* src = qkv + ((size_t)(b * TSEQ + j * 64 + r)) * 3072 + 1024 + h * 64 + c0;
        bf16x8 k0 = *(const bf16x8*)src;
        bf16x8 k1 = *(const bf16x8*)(src + 8);
        bf16x8 v0 = *(const bf16x8*)(src + 1024);
        bf16x8 v1 = *(const bf16x8*)(src + 1032);
        *(bf16x8*)&Kt[r][c0]     = k0;
        *(bf16x8*)&Kt[r][c0 + 8] = k1;
        *(bf16x8*)&Vt[r][c0]     = v0;
        *(bf16x8*)&Vt[r][c0 + 8] = v1;
    }
    __syncthreads();
    const int l  = tid & 63;
    const int qd = tid >> 6;
    const size_t tbase = ((size_t)(bh * 32 + j)) * 8 * 512;
    #pragma unroll
    for (int pass = 0; pass < 2; ++pass) {
        const int kc = qd + pass * 4;
        const int sb = kc >> 1, g = kc & 1;
        bf16x8 kv = *(const bf16x8*)&Kt[sb * 16 + (l & 15)][g * 32 + (l >> 4) * 8];
        *(bf16x8*)(kfrag + tbase + kc * 512 + l * 8) = kv;

        const int vc = qd + pass * 4;
        const int kb = vc >> 2, db = vc & 3;
        unsigned short tmp[8];
        #pragma unroll
        for (int i = 0; i < 8; ++i)
            tmp[i] = Vt[kb * 32 + (l >> 4) * 8 + i][db * 16 + (l & 15)];
        *(bf16x8*)(vfrag + tbase + vc * 512 + l * 8) = *(bf16x8*)tmp;
    }
}

// ---- MFMA GEMM (TN) 128x128 tile, BK=32 stages, 3-DEEP counted-vmcnt pipeline -----
// LDS 48 KB (3 x (8A + 8B)) -> 3 blocks/CU. Per stage: 4 gload_lds (2A + 2B chunks).
// Bank derivation (64B rows): bank = (16*row + 4*chunk) mod 32 -> XOR chunk with
// (row>>1)&3 so the 4 same-parity rows per bankset window use 4 distinct banksets
// -> exactly 2 lanes/bankset = free. Both sides swizzled (stage source + read).
template<int EPI>
__global__ __launch_bounds__(256) void gemm_kernel(const unsigned short* __restrict__ A,
                                                   const unsigned short* __restrict__ Bt,
                                                   const float* __restrict__ bias,
                                                   const float* __restrict__ res,
                                                   void* __restrict__ Cout,
                                                   int M, int N, int K, int nbx, int rpx) {
    __shared__ __align__(16) unsigned short As[3 * 4096];   // 3 x 8 KB
    __shared__ __align__(16) unsigned short Bs[3 * 4096];   // 3 x 8 KB
    const int tid = threadIdx.x;
    const int l   = tid & 63;
    const int w   = tid >> 6;
    const int wr  = (w >> 1) * 64;
    const int wc  = (w & 1) * 64;
    const int lin = blockIdx.x;
    const int xcd = lin & 7;
    const int idx = lin >> 3;
    const long brow = (long)(xcd * rpx + idx / nbx) * 128;
    const long bcol = (long)(idx % nbx) * 128;

    // staging: thread covers rows r=tid>>2 and r+64, LDS pos tid&3, global chunk XOR'd
    const int srow = tid >> 2;                                  // 0..63
    const int schk = ((tid & 3) ^ ((srow >> 1) & 3)) * 8;       // global elem offset
    const unsigned short* gA = A  + (size_t)(brow + srow) * K + schk;
    const unsigned short* gB = Bt + (size_t)(bcol + srow) * K + schk;

    f32x4 acc[4][4];
    #pragma unroll
    for (int m = 0; m < 4; ++m)
        #pragma unroll
        for (int n = 0; n < 4; ++n) acc[m][n] = (f32x4){0.f, 0.f, 0.f, 0.f};

    // 4 loads per stage: rows [0,64) and [64,128) of A and B
    #define STAGE128(buf, koff_)                                                       \
        do {                                                                           \
            unsigned short* lA_ = As + (buf) * 4096 + tid * 8;                         \
            unsigned short* lB_ = Bs + (buf) * 4096 + tid * 8;                         \
            gload_lds16(gA + (koff_), lA_);                                            \
            gload_lds16(gA + (size_t)64 * K + (koff_), lA_ + 2048);                    \
            gload_lds16(gB + (koff_), lB_);                                            \
            gload_lds16(gB + (size_t)64 * K + (koff_), lB_ + 2048);                    \
        } while (0)

    // prologue: tiles 0 and 1 in flight (8 loads)
    STAGE128(0, 0);
    STAGE128(1, 32);

    int cur = 0;
    for (int k0 = 0; k0 < K; k0 += 32) {
        if (k0 + 32 < K) asm volatile("s_waitcnt vmcnt(4)" ::: "memory");
        else             asm volatile("s_waitcnt vmcnt(0)" ::: "memory");
        __builtin_amdgcn_s_barrier();
        asm volatile("" ::: "memory");   // no LDS read hoists above the barrier

        const unsigned short* cA = As + cur * 4096 + (wr >> 6) * 2048;
        const unsigned short* cB = Bs + cur * 4096 + (wc >> 6) * 2048;
        const int koff = ((l >> 4) ^ (((l & 15) >> 1) & 3)) * 8;
        bf16x8 af[4], bf[4];
        #pragma unroll
        for (int m = 0; m < 4; ++m)
            af[m] = *(const bf16x8*)&cA[(m * 16 + (l & 15)) * 32 + koff];
        #pragma unroll
        for (int n = 0; n < 4; ++n)
            bf[n] = *(const bf16x8*)&cB[(n * 16 + (l & 15)) * 32 + koff];
        __builtin_amdgcn_s_setprio(1);
        #pragma unroll
        for (int m = 0; m < 4; ++m)
            #pragma unroll
            for (int n = 0; n < 4; ++n)
                acc[m][n] = __builtin_amdgcn_mfma_f32_16x16x32_bf16(af[m], bf[n], acc[m][n], 0, 0, 0);
        __builtin_amdgcn_s_setprio(0);

        // stage tile t+2 (after barrier(t) -> WAR-safe vs compute(t-1) readers)
        if (k0 + 64 < K) {
            int nxt = cur + 2; if (nxt >= 3) nxt -= 3;
            STAGE128(nxt, k0 + 64);
        }
        cur = cur + 1; if (cur == 3) cur = 0;
    }
    #undef STAGE128

    #pragma unroll
    for (int m = 0; m < 4; ++m) {
        const int rown = wr + m * 16 + (l >> 4) * 4;
        #pragma unroll
        for (int n = 0; n < 4; ++n) {
            const long col = bcol + wc + n * 16 + (l & 15);
            const float bb = bias[col];
            #pragma unroll
            for (int r = 0; r < 4; ++r) {
                const long row = brow + rown + r;
                float v = acc[m][n][r] + bb;
                if (EPI == 1) {
                    v += res[row * N + col];
                    ((float*)Cout)[row * N + col] = v;
                } else if (EPI == 2) {
                    ((unsigned short*)Cout)[row * N + col] = f2bf(fast_gelu(v));
                } else {
                    ((unsigned short*)Cout)[row * N + col] = f2bf(v);
                }
            }
        }
    }
}

// ------ MFMA GEMM (TN) 64x128 tile, BK=64, XOR swizzle, XCD-banded, 3-DEEP PIPELINE
template<int EPI>
__global__ __launch_bounds__(256) void gemm64_kernel(const unsigned short* __restrict__ A,
                                                     const unsigned short* __restrict__ Bt,
                                                     const float* __restrict__ bias,
                                                     const float* __restrict__ res,
                                                     void* __restrict__ Cout,
                                                     int M, int N, int K, int nbx, int rpx) {
    __shared__ __align__(16) unsigned short As[3 * 64 * 64];    // 3 x 8 KB
    __shared__ __align__(16) unsigned short Bs[3 * 128 * 64];   // 3 x 16 KB
    const int tid = threadIdx.x;
    const int l   = tid & 63;
    const int w   = tid >> 6;
    const int wr  = (w >> 1) * 32;
    const int wc  = (w & 1) * 64;
    const int lin = blockIdx.x;
    const int xcd = lin & 7;
    const int idx = lin >> 3;
    const long brow = (long)(xcd * rpx + idx / nbx) * 64;
    const long bcol = (long)(idx % nbx) * 128;

    const int srow = tid >> 3;                                  // 0..31
    const int schk = ((tid & 7) ^ (srow & 7)) * 8;
    const unsigned short* gA = A  + (size_t)(brow + srow) * K + schk;
    const unsigned short* gB = Bt + (size_t)(bcol + srow) * K + schk;

    f32x4 acc[2][4];
    #pragma unroll
    for (int m = 0; m < 2; ++m)
        #pragma unroll
        for (int n = 0; n < 4; ++n) acc[m][n] = (f32x4){0.f, 0.f, 0.f, 0.f};

    #define STAGE64(buf, koff_)                                                        \
        do {                                                                           \
            unsigned short* lA_ = As + (buf) * 4096 + tid * 8;                         \
            unsigned short* lB_ = Bs + (buf) * 8192 + tid * 8;                         \
            _Pragma("unroll")                                                          \
            for (int p = 0; p < 2; ++p)                                                \
                gload_lds16(gA + (size_t)(32 * p) * K + (koff_), lA_ + p * 2048);      \
            _Pragma("unroll")                                                          \
            for (int p = 0; p < 4; ++p)                                                \
                gload_lds16(gB + (size_t)(32 * p) * K + (koff_), lB_ + p * 2048);      \
        } while (0)

    STAGE64(0, 0);
    STAGE64(1, 64);

    int cur = 0;
    for (int k0 = 0; k0 < K; k0 += 64) {
        if (k0 + 64 < K) asm volatile("s_waitcnt vmcnt(6)" ::: "memory");
        else             asm volatile("s_waitcnt vmcnt(0)" ::: "memory");
        __builtin_amdgcn_s_barrier();
        asm volatile("" ::: "memory");

        const unsigned short* cA = As + cur * 4096;
        const unsigned short* cB = Bs + cur * 8192;
        #pragma unroll
        for (int gg = 0; gg < 2; ++gg) {
            const int koff = ((gg * 4 + (l >> 4)) ^ (l & 7)) * 8;
            bf16x8 af[2], bf[4];
            #pragma unroll
            for (int m = 0; m < 2; ++m)
                af[m] = *(const bf16x8*)&cA[(wr + m * 16 + (l & 15)) * 64 + koff];
            #pragma unroll
            for (int n = 0; n < 4; ++n)
                bf[n] = *(const bf16x8*)&cB[(wc + n * 16 + (l & 15)) * 64 + koff];
            __builtin_amdgcn_s_setprio(1);
            #pragma unroll
            for (int m = 0; m < 2; ++m)
                #pragma unroll
                for (int n = 0; n < 4; ++n)
                    acc[m][n] = __builtin_amdgcn_mfma_f32_16x16x32_bf16(af[m], bf[n], acc[m][n], 0, 0, 0);
            __builtin_amdgcn_s_setprio(0);
        }

        if (k0 + 128 < K) {
            int nxt = cur + 2; if (nxt >= 3) nxt -= 3;
            STAGE64(nxt, k0 + 128);
        }
        cur = cur + 1; if (cur == 3) cur = 0;
    }
    #undef STAGE64

    #pragma unroll
    for (int m = 0; m < 2; ++m) {
        const int rown = wr + m * 16 + (l >> 4) * 4;
        #pragma unroll
        for (int n = 0; n < 4; ++n) {
            const long col = bcol + wc + n * 16 + (l & 15);
            const float bb = bias[col];
            #pragma unroll
            for (int r = 0; r < 4; ++r) {
                const long row = brow + rown + r;
                float v = acc[m][n][r] + bb;
                if (EPI == 1) {
                    v += res[row * N + col];
                    ((float*)Cout)[row * N + col] = v;
                } else if (EPI == 2) {
                    ((unsigned short*)Cout)[row * N + col] = f2bf(fast_gelu(v));
                } else {
                    ((unsigned short*)Cout)[row * N + col] = f2bf(v);
                }
            }
        }
    }
}

// ------------- MFMA causal flash attention (swapped QK^T, in-lane softmax) ----------
#define QSCALE 0.18033688011112042f   // 0.125 * log2(e)
__global__ __launch_bounds__(64) void attn_kernel(const unsigned short* __restrict__ qkv,
                                                  const unsigned short* __restrict__ kfrag,
                                                  const unsigned short* __restrict__ vfrag,
                                                  unsigned short* __restrict__ out) {
    __shared__ __align__(16) unsigned short Ps[16 * 128];   // [q][s], 16B-chunk swizzled

    const int l    = threadIdx.x;
    const int q    = l & 15;                   // lane's softmax row
    const int g    = l >> 4;                   // lane group 0..3
    const int lin  = blockIdx.x;
    const int xcd  = lin & 7;
    const int rest = lin >> 3;
    const int h    = xcd + 8 * (rest & 1);
    const int b    = (rest >> 1) & 1;
    const int strip = 127 - (rest >> 2);
    const int jmax  = strip >> 2;
    const size_t rowbase = (size_t)b * TSEQ;
    const int bh = b * NH + h;
    const int qglob = strip * 16 + q;

    const unsigned short* kfb = kfrag + (size_t)bh * 32 * 8 * 512;
    const unsigned short* vfb = vfrag + (size_t)bh * 32 * 8 * 512;

    bf16x8 aq0, aq1;
    {
        const unsigned short* qp = qkv + (rowbase + qglob) * 3072 + h * 64 + g * 8;
        bf16x8 t0 = *(const bf16x8*)qp;
        bf16x8 t1 = *(const bf16x8*)(qp + 32);
        #pragma unroll
        for (int i = 0; i < 8; ++i) {
            aq0[i] = (short)f2bf(bf2f((unsigned short)t0[i]) * QSCALE);
            aq1[i] = (short)f2bf(bf2f((unsigned short)t1[i]) * QSCALE);
        }
    }

    float mrow = -INFINITY, lrow = 0.f;
    f32x4 o[4];
    #pragma unroll
    for (int d = 0; d < 4; ++d) o[d] = (f32x4){0.f, 0.f, 0.f, 0.f};

    for (int j = 0; j + 1 <= jmax; j += 2) {
        const bool diag2 = (j + 1 == jmax);

        bf16x8 kf[16];
        #pragma unroll
        for (int t = 0; t < 2; ++t)
            #pragma unroll
            for (int sb = 0; sb < 4; ++sb) {
                const unsigned short* kp = kfb + (size_t)((j + t) * 8 + sb * 2) * 512 + l * 8;
                kf[t * 8 + sb * 2]     = *(const bf16x8*)kp;
                kf[t * 8 + sb * 2 + 1] = *(const bf16x8*)(kp + 512);
            }

        f32x4 sf[8];
        __builtin_amdgcn_s_setprio(1);
        #pragma unroll
        for (int t = 0; t < 2; ++t)
            #pragma unroll
            for (int sb = 0; sb < 4; ++sb) {
                f32x4 acc = (f32x4){0.f, 0.f, 0.f, 0.f};
                acc = __builtin_amdgcn_mfma_f32_16x16x32_bf16(kf[t*8 + sb*2],     aq0, acc, 0, 0, 0);
                acc = __builtin_amdgcn_mfma_f32_16x16x32_bf16(kf[t*8 + sb*2 + 1], aq1, acc, 0, 0, 0);
                sf[t*4 + sb] = acc;
            }
        __builtin_amdgcn_s_setprio(0);

        bf16x8 vf[16];
        #pragma unroll
        for (int kb = 0; kb < 4; ++kb)
            #pragma unroll
            for (int db = 0; db < 4; ++db)
                vf[kb * 4 + db] = *(const bf16x8*)(vfb + (size_t)((j + (kb >> 1)) * 8 + (kb & 1) * 4 + db) * 512 + l * 8);

        if (diag2) {
            #pragma unroll
            for (int sb = 0; sb < 4; ++sb) {
                const int sg = (j + 1) * 64 + sb * 16 + 4 * g;
                #pragma unroll
                for (int r = 0; r < 4; ++r)
                    if (sg + r > qglob) sf[4 + sb][r] = -INFINITY;
            }
        }

        f32x4 mv = sf[0];
        #pragma unroll
        for (int i = 1; i < 8; ++i)
            #pragma unroll
            for (int r = 0; r < 4; ++r) mv[r] = fmaxf(mv[r], sf[i][r]);
        float mloc = fmaxf(fmaxf(mv[0], mv[1]), fmaxf(mv[2], mv[3]));
        mloc = fmaxf(mloc, __shfl_xor(mloc, 16));
        mloc = fmaxf(mloc, __shfl_xor(mloc, 32));
        const float mn = fmaxf(mrow, mloc);
        const float alpha = exp2f(mrow - mn);
        mrow = mn;

        float psum = 0.f;
        #pragma unroll
        for (int i = 0; i < 8; ++i) {
            const int t = i >> 2, sb = i & 3;
            float p0 = exp2f(sf[i][0] - mn);
            float p1 = exp2f(sf[i][1] - mn);
            float p2 = exp2f(sf[i][2] - mn);
            float p3 = exp2f(sf[i][3] - mn);
            psum += (p0 + p1) + (p2 + p3);
            unsigned int pk0 = cvt_pk_bf16(p0, p1);
            unsigned int pk1 = cvt_pk_bf16(p2, p3);
            const int c16 = (t * 8 + sb * 2 + (g >> 1)) ^ (q & 7);
            *(uint2*)((char*)Ps + q * 256 + c16 * 16 + (g & 1) * 8) = make_uint2(pk0, pk1);
        }
        psum += __shfl_xor(psum, 16);
        psum += __shfl_xor(psum, 32);
        lrow = lrow * alpha + psum;

        float al[4];
        #pragma unroll
        for (int r = 0; r < 4; ++r) al[r] = __shfl(alpha, g * 4 + r);
        #pragma unroll
        for (int d = 0; d < 4; ++d)
            #pragma unroll
            for (int r = 0; r < 4; ++r) o[d][r] *= al[r];

        __builtin_amdgcn_s_setprio(1);
        #pragma unroll
        for (int kb = 0; kb < 4; ++kb) {
            const int c16 = (kb * 4 + g) ^ (q & 7);
            bf16x8 pa = *(const bf16x8*)((const char*)Ps + q * 256 + c16 * 16);
            #pragma unroll
            for (int db = 0; db < 4; ++db)
                o[db] = __builtin_amdgcn_mfma_f32_16x16x32_bf16(pa, vf[kb * 4 + db], o[db], 0, 0, 0);
        }
        __builtin_amdgcn_s_setprio(0);
    }

    if ((jmax & 1) == 0) {
        const int j = jmax;
        bf16x8 kf[8];
        #pragma unroll
        for (int sb = 0; sb < 4; ++sb) {
            const unsigned short* kp = kfb + (size_t)(j * 8 + sb * 2) * 512 + l * 8;
            kf[sb * 2]     = *(const bf16x8*)kp;
            kf[sb * 2 + 1] = *(const bf16x8*)(kp + 512);
        }
        f32x4 sf[4];
        __builtin_amdgcn_s_setprio(1);
        #pragma unroll
        for (int sb = 0; sb < 4; ++sb) {
            f32x4 acc = (f32x4){0.f, 0.f, 0.f, 0.f};
            acc = __builtin_amdgcn_mfma_f32_16x16x32_bf16(kf[sb*2],     aq0, acc, 0, 0, 0);
            acc = __builtin_amdgcn_mfma_f32_16x16x32_bf16(kf[sb*2 + 1], aq1, acc, 0, 0, 0);
            sf[sb] = acc;
        }
        __builtin_amdgcn_s_setprio(0);

        bf16x8 vf[8];
        #pragma unroll
        for (int kb = 0; kb < 2; ++kb)
            #pragma unroll
            for (int db = 0; db < 4; ++db)
                vf[kb * 4 + db] = *(const bf16x8*)(vfb + (size_t)(j * 8 + kb * 4 + db) * 512 + l * 8);

        #pragma unroll
        for (int sb = 0; sb < 4; ++sb) {
            const int sg = j * 64 + sb * 16 + 4 * g;
            #pragma unroll
            for (int r = 0; r < 4; ++r)
                if (sg + r > qglob) sf[sb][r] = -INFINITY;
        }

        f32x4 mv = sf[0];
        #pragma unroll
        for (int i = 1; i < 4; ++i)
            #pragma unroll
            for (int r = 0; r < 4; ++r) mv[r] = fmaxf(mv[r], sf[i][r]);
        float mloc = fmaxf(fmaxf(mv[0], mv[1]), fmaxf(mv[2], mv[3]));
        mloc = fmaxf(mloc, __shfl_xor(mloc, 16));
        mloc = fmaxf(mloc, __shfl_xor(mloc, 32));
        const float mn = fmaxf(mrow, mloc);
        const float alpha = exp2f(mrow - mn);
        mrow = mn;

        float psum = 0.f;
        #pragma unroll
        for (int sb = 0; sb < 4; ++sb) {
            float p0 = exp2f(sf[sb][0] - mn);
            float p1 = exp2f(sf[sb][1] - mn);
            float p2 = exp2f(sf[sb][2] - mn);
            float p3 = exp2f(sf[sb][3] - mn);
            psum += (p0 + p1) + (p2 + p3);
            unsigned int pk0 = cvt_pk_bf16(p0, p1);
            unsigned int pk1 = cvt_pk_bf16(p2, p3);
            const int c16 = (sb * 2 + (g >> 1)) ^ (q & 7);
            *(uint2*)((char*)Ps + q * 256 + c16 * 16 + (g & 1) * 8) = make_uint2(pk0, pk1);
        }
        psum += __shfl_xor(psum, 16);
        psum += __shfl_xor(psum, 32);
        lrow = lrow * alpha + psum;

        float al[4];
        #pragma unroll
        for (int r = 0; r < 4; ++r) al[r] = __shfl(alpha, g * 4 + r);
        #pragma unroll
        for (int d = 0; d < 4; ++d)
            #pragma unroll
            for (int r = 0; r < 4; ++r) o[d][r] *= al[r];

        __builtin_amdgcn_s_setprio(1);
        #pragma unroll
        for (int kb = 0; kb < 2; ++kb) {
            const int c16 = (kb * 4 + g) ^ (q & 7);
            bf16x8 pa = *(const bf16x8*)((const char*)Ps + q * 256 + c16 * 16);
            #pragma unroll
            for (int db = 0; db < 4; ++db)
                o[db] = __builtin_amdgcn_mfma_f32_16x16x32_bf16(pa, vf[kb * 4 + db], o[db], 0, 0, 0);
        }
        __builtin_amdgcn_s_setprio(0);
    }

    // epilogue: O rows = g*4+r, cols = q + db*16
    float linv[4];
    #pragma unroll
    for (int r = 0; r < 4; ++r) linv[r] = 1.0f / __shfl(lrow, g * 4 + r);
    #pragma unroll
    for (int r = 0; r < 4; ++r) {
        const size_t rb = (rowbase + strip * 16 + g * 4 + r) * (size_t)CDIM + h * 64 + q;
        #pragma unroll
        for (int d = 0; d < 4; ++d)
            out[rb + d * 16] = f2bf(o[d][r] * linv[r]);
    }
}

extern "C" void kernel_launch(void* const* d_in, const int* in_sizes, int n_in,
                              void* d_out, int out_size, void* d_ws, size_t ws_size,
                              hipStream_t stream) {
    const float* x     = (const float*)d_in[0];
    const float* ln1_g = (const float*)d_in[1];
    const float* ln1_b = (const float*)d_in[2];
    const float* w_qkv = (const float*)d_in[3];
    const float* b_qkv = (const float*)d_in[4];
    const float* w_out = (const float*)d_in[5];
    const float* b_out = (const float*)d_in[6];
    const float* ln2_g = (const float*)d_in[7];
    const float* ln2_b = (const float*)d_in[8];
    const float* w_ff1 = (const float*)d_in[9];
    const float* b_ff1 = (const float*)d_in[10];
    const float* w_ff2 = (const float*)d_in[11];
    const float* b_ff2 = (const float*)d_in[12];
    float* out = (float*)d_out;

    char* wsb = (char*)d_ws;
    unsigned short* h_bf    = (unsigned short*)(wsb);                          // 8 MB
    unsigned short* qkv_bf  = (unsigned short*)(wsb + 8ll  * 1024 * 1024);     // 24 MB
    unsigned short* attn_bf = (unsigned short*)(wsb + 32ll * 1024 * 1024);     // 8 MB
    float*          x1      = (float*)         (wsb + 40ll * 1024 * 1024);     // 16 MB
    unsigned short* kfrag   = (unsigned short*)(wsb + 40ll * 1024 * 1024);     // 8 MB (overlays x1, dead until step 4)
    unsigned short* vfrag   = (unsigned short*)(wsb + 48ll * 1024 * 1024);     // 8 MB (overlays x1, dead until step 4)
    unsigned short* wqkvT   = (unsigned short*)(wsb + 56ll * 1024 * 1024);     // 6 MB
    unsigned short* woutT   = (unsigned short*)(wsb + 62ll * 1024 * 1024);     // 2 MB
    unsigned short* wff1T   = (unsigned short*)(wsb + 64ll * 1024 * 1024);     // 8 MB
    unsigned short* wff2T   = (unsigned short*)(wsb + 72ll * 1024 * 1024);     // 8 MB
    unsigned short* ff1_bf  = (unsigned short*)(wsb + 8ll  * 1024 * 1024);     // 32 MB, overlays dead qkv+attn

    transpose_cast_kernel<<<dim3(48, 16), 256, 0, stream>>>(w_qkv, wqkvT, 1024, 3072);
    transpose_cast_kernel<<<dim3(16, 16), 256, 0, stream>>>(w_out, woutT, 1024, 1024);
    transpose_cast_kernel<<<dim3(64, 16), 256, 0, stream>>>(w_ff1, wff1T, 1024, 4096);
    transpose_cast_kernel<<<dim3(16, 64), 256, 0, stream>>>(w_ff2, wff2T, 4096, 1024);

    // 1. LN1 -> bf16
    ln_kernel<<<ROWS, 256, 0, stream>>>(x, ln1_g, ln1_b, h_bf);
    // 2. qkv = h @ w_qkv + b  -> bf16   (768 blocks: nbx=24, 4 row-panels/XCD)
    gemm_kernel<0><<<768, 256, 0, stream>>>(h_bf, wqkvT, b_qkv, nullptr, qkv_bf, ROWS, 3072, 1024, 24, 4);
    // 2b. K/V fragment-major pre-pass
    kvfrag_kernel<<<dim3(32, 32), 256, 0, stream>>>(qkv_bf, kfrag, vfrag);
    // 3. causal flash attention -> bf16 (swapped QK^T, in-lane softmax)
    attn_kernel<<<4096, 64, 0, stream>>>(qkv_bf, kfrag, vfrag, attn_bf);
    // 4. x1 = x + attn @ w_out + b  -> f32   (512 blocks: nbx=8, 8 row-panels/XCD)
    gemm64_kernel<1><<<512, 256, 0, stream>>>(attn_bf, woutT, b_out, x, x1, ROWS, 1024, 1024, 8, 8);
    // 5. LN2 -> bf16
    ln_kernel<<<ROWS, 256, 0, stream>>>(x1, ln2_g, ln2_b, h_bf);
    // 6. ff1 = gelu(h @ w_ff1 + b)  -> bf16   (1024 blocks: nbx=32, 4 row-panels/XCD)
    gemm_kernel<2><<<1024, 256, 0, stream>>>(h_bf, wff1T, b_ff1, nullptr, ff1_bf, ROWS, 4096, 1024, 32, 4);
    // 7. out = x1 + ff1 @ w_ff2 + b  -> f32   (512 blocks: nbx=8, 8 row-panels/XCD)
    gemm64_kernel<1><<<512, 256, 0, stream>>>(ff1_bf, wff2T, b_ff2, x1, (float*)out, ROWS, 1024, 4096, 8, 8);
}